// Round 1
// baseline (2689.381 us; speedup 1.0000x reference)
//
#include <hip/hip_runtime.h>

// ---------------------------------------------------------------------------
// TransformerBlock: B=2,S=2048,D=768,H=12,DH=64,DFF=3072, causal attn, 2x LN
// Round 0: correctness-first. bf16 MFMA GEMMs (m97-style 128x128x32 tile,
// global_load_lds width=16), fp32 vector flash attention, fused resid+LN.
// ---------------------------------------------------------------------------

typedef __attribute__((ext_vector_type(8))) short  short8;   // 8 x bf16 (4 VGPR)
typedef __attribute__((ext_vector_type(4))) float  floatx4;  // 4 x f32 acc

__device__ __forceinline__ float b2f(unsigned short u) {
    return __uint_as_float(((unsigned)u) << 16);
}
__device__ __forceinline__ unsigned short f2b(float f) {  // RNE
    unsigned x = __float_as_uint(f);
    return (unsigned short)((x + 0x7fffu + ((x >> 16) & 1u)) >> 16);
}
__device__ __forceinline__ void async_cp16(const void* g, void* l) {
    __builtin_amdgcn_global_load_lds((const __attribute__((address_space(1))) void*)g,
                                     (__attribute__((address_space(3))) void*)l,
                                     16, 0, 0);
}
__device__ __forceinline__ void unpack8(uint4 u, float* dst) {
    dst[0] = b2f((unsigned short)(u.x & 0xffffu)); dst[1] = b2f((unsigned short)(u.x >> 16));
    dst[2] = b2f((unsigned short)(u.y & 0xffffu)); dst[3] = b2f((unsigned short)(u.y >> 16));
    dst[4] = b2f((unsigned short)(u.z & 0xffffu)); dst[5] = b2f((unsigned short)(u.z >> 16));
    dst[6] = b2f((unsigned short)(u.w & 0xffffu)); dst[7] = b2f((unsigned short)(u.w >> 16));
}

// ---------------- fp32 -> bf16 elementwise (x), 4-wide ----------------------
__global__ __launch_bounds__(256) void cvt_f32_bf16(const float* __restrict__ x,
                                                    unsigned short* __restrict__ y,
                                                    int n4) {
    int i = blockIdx.x * 256 + threadIdx.x;
    if (i < n4) {
        float4 v = ((const float4*)x)[i];
        ushort4 u;
        u.x = f2b(v.x); u.y = f2b(v.y); u.z = f2b(v.z); u.w = f2b(v.w);
        ((ushort4*)y)[i] = u;
    }
}

// ---------------- W[K][N] f32 -> Wt[N][K] bf16 ------------------------------
__global__ __launch_bounds__(256) void transpose_to_bf16(const float* __restrict__ W,
                                                         unsigned short* __restrict__ Wt,
                                                         int K, int N) {
    __shared__ float tile[32][33];
    int n0 = blockIdx.x * 32, k0 = blockIdx.y * 32;
    int tx = threadIdx.x, ty = threadIdx.y;  // (32,8)
    for (int i = ty; i < 32; i += 8)
        tile[i][tx] = W[(size_t)(k0 + i) * N + n0 + tx];
    __syncthreads();
    for (int i = ty; i < 32; i += 8)
        Wt[(size_t)(n0 + i) * K + k0 + tx] = f2b(tile[tx][i]);
}

// ---------------- bf16 MFMA GEMM: C[M][N] = A[M][K] @ Bt[N][K]^T ------------
// 128x128x32 tile, 256 threads (4 waves 2x2, each 64x64 via 4x4 mfma 16x16x32)
__global__ __launch_bounds__(256) void gemm_bf16(
    const unsigned short* __restrict__ A,   // [M][K] bf16
    const unsigned short* __restrict__ Bt,  // [N][K] bf16
    const float* __restrict__ bias,         // [N] or null
    float* __restrict__ outF,               // [M][N] or null
    unsigned short* __restrict__ outB,      // [M][N] or null
    int M, int N, int K, int relu)
{
    __shared__ unsigned short As[128][32];
    __shared__ unsigned short Bs[128][32];
    const int tid  = threadIdx.x;
    const int m0   = blockIdx.y * 128;
    const int n0   = blockIdx.x * 128;
    const int lane = tid & 63;
    const int wave = tid >> 6;
    const int wm   = (wave >> 1) * 64;
    const int wn   = (wave & 1) * 64;
    const int fr   = lane & 15;   // row within 16x16 fragment
    const int fq   = lane >> 4;   // quad (k-group / acc row group)

    floatx4 acc[4][4];
    for (int i = 0; i < 4; i++)
        for (int j = 0; j < 4; j++)
            for (int e = 0; e < 4; e++) acc[i][j][e] = 0.f;

    for (int kk = 0; kk < K; kk += 32) {
        __syncthreads();  // previous iter's LDS reads done
        #pragma unroll
        for (int r = 0; r < 2; ++r) {
            int c    = r * 256 + tid;      // 16B-chunk id; lane-contiguous in LDS
            int row  = c >> 2;
            int colb = (c & 3) * 8;
            async_cp16(A  + (size_t)(m0 + row) * K + kk + colb, &As[row][colb]);
            async_cp16(Bt + (size_t)(n0 + row) * K + kk + colb, &Bs[row][colb]);
        }
        __syncthreads();  // drains vmcnt (compiler emits vmcnt(0) before barrier)

        short8 a[4], b[4];
        #pragma unroll
        for (int t = 0; t < 4; t++) a[t] = *(const short8*)&As[wm + t * 16 + fr][fq * 8];
        #pragma unroll
        for (int t = 0; t < 4; t++) b[t] = *(const short8*)&Bs[wn + t * 16 + fr][fq * 8];
        #pragma unroll
        for (int i = 0; i < 4; i++)
            #pragma unroll
            for (int j = 0; j < 4; j++)
                acc[i][j] = __builtin_amdgcn_mfma_f32_16x16x32_bf16(a[i], b[j], acc[i][j], 0, 0, 0);
    }

    // epilogue: C/D layout col = lane&15, row = (lane>>4)*4 + reg
    #pragma unroll
    for (int j = 0; j < 4; j++) {
        int col  = n0 + wn + j * 16 + fr;
        float bv = bias ? bias[col] : 0.f;
        #pragma unroll
        for (int i = 0; i < 4; i++) {
            int rbase = m0 + wm + i * 16 + fq * 4;
            #pragma unroll
            for (int e = 0; e < 4; e++) {
                float v = acc[i][j][e] + bv;
                if (relu) v = fmaxf(v, 0.f);
                size_t idx = (size_t)(rbase + e) * N + col;
                if (outF) outF[idx] = v;
                if (outB) outB[idx] = f2b(v);
            }
        }
    }
}

// ---------------- causal flash attention (fp32 vector) ----------------------
// qkv: [B*S][2304] bf16 (q|k|v chunks of 768); ctx out: [B*S][768] bf16
// grid (S/64, B*H), 64 threads; thread t owns q-row qblk*64+t.
__global__ __launch_bounds__(64) void attn_causal(const unsigned short* __restrict__ qkv,
                                                  unsigned short* __restrict__ ctx) {
    const int t    = threadIdx.x;
    const int qblk = blockIdx.x;
    const int bh   = blockIdx.y;
    const int b    = bh / 12, h = bh % 12;
    const int qa   = qblk * 64 + t;
    const unsigned short* base = qkv + (size_t)b * 2048 * 2304;

    float q[64];
    {
        const unsigned short* qr = base + (size_t)qa * 2304 + h * 64;
        #pragma unroll
        for (int c = 0; c < 8; ++c) {
            uint4 u = *(const uint4*)(qr + c * 8);
            unpack8(u, &q[c * 8]);
        }
    }
    float m = -1e30f, l = 0.f;
    float o[64];
    #pragma unroll
    for (int d = 0; d < 64; d++) o[d] = 0.f;

    __shared__ float Ks[32][64];
    __shared__ float Vs[32][64];
    const int kv_end = qblk * 64 + 64;

    for (int kt = 0; kt < kv_end; kt += 32) {
        __syncthreads();
        #pragma unroll
        for (int r = 0; r < 4; ++r) {           // 256 chunks of 8 bf16, 4/thread
            int c = r * 64 + t;
            int row = c >> 3, d0 = (c & 7) * 8;
            const unsigned short* kp = base + (size_t)(kt + row) * 2304 + 768  + h * 64 + d0;
            const unsigned short* vp = base + (size_t)(kt + row) * 2304 + 1536 + h * 64 + d0;
            uint4 ku = *(const uint4*)kp;
            uint4 vu = *(const uint4*)vp;
            unpack8(ku, &Ks[row][d0]);
            unpack8(vu, &Vs[row][d0]);
        }
        __syncthreads();

        int jmax = qa - kt + 1;
        if (jmax > 32) jmax = 32;
        for (int j = 0; j < jmax; ++j) {
            float s = 0.f;
            #pragma unroll
            for (int d = 0; d < 64; d++) s = fmaf(q[d], Ks[j][d], s);
            s *= 0.125f;  // 1/sqrt(64)
            float mn    = fmaxf(m, s);
            float alpha = __expf(m - mn);
            float p     = __expf(s - mn);
            l = l * alpha + p;
            #pragma unroll
            for (int d = 0; d < 64; d++) o[d] = o[d] * alpha + p * Vs[j][d];
            m = mn;
        }
    }
    float inv = 1.f / l;
    unsigned short* orow = ctx + (size_t)(b * 2048 + qa) * 768 + h * 64;
    #pragma unroll
    for (int c = 0; c < 8; ++c) {
        uint4 u;
        u.x = (unsigned)f2b(o[c*8+0]*inv) | ((unsigned)f2b(o[c*8+1]*inv) << 16);
        u.y = (unsigned)f2b(o[c*8+2]*inv) | ((unsigned)f2b(o[c*8+3]*inv) << 16);
        u.z = (unsigned)f2b(o[c*8+4]*inv) | ((unsigned)f2b(o[c*8+5]*inv) << 16);
        u.w = (unsigned)f2b(o[c*8+6]*inv) | ((unsigned)f2b(o[c*8+7]*inv) << 16);
        *(uint4*)(orow + c * 8) = u;
    }
}

// ---------------- fused residual + LayerNorm --------------------------------
// y = g * ((x+r) - mean)/sqrt(var+eps) + be ; one block per row of 768
__global__ __launch_bounds__(256) void resid_ln(const float* __restrict__ X,
                                                const float* __restrict__ R,
                                                const float* __restrict__ gain,
                                                const float* __restrict__ beta,
                                                float* __restrict__ outF,
                                                unsigned short* __restrict__ outB) {
    const int row = blockIdx.x;
    const int t   = threadIdx.x;
    const size_t off = (size_t)row * 768;
    float v0 = X[off + t]       + R[off + t];
    float v1 = X[off + t + 256] + R[off + t + 256];
    float v2 = X[off + t + 512] + R[off + t + 512];
    float s  = v0 + v1 + v2;
    float s2 = v0 * v0 + v1 * v1 + v2 * v2;
    #pragma unroll
    for (int o2 = 32; o2 > 0; o2 >>= 1) {
        s  += __shfl_down(s,  o2);
        s2 += __shfl_down(s2, o2);
    }
    __shared__ float rs[4], rq[4];
    if ((t & 63) == 0) { rs[t >> 6] = s; rq[t >> 6] = s2; }
    __syncthreads();
    float S    = rs[0] + rs[1] + rs[2] + rs[3];
    float S2   = rq[0] + rq[1] + rq[2] + rq[3];
    float mean = S * (1.0f / 768.0f);
    float var  = S2 * (1.0f / 768.0f) - mean * mean;
    float inv  = rsqrtf(var + 1e-5f);
    #pragma unroll
    for (int i = 0; i < 3; i++) {
        int c   = t + i * 256;
        float v = (i == 0 ? v0 : (i == 1 ? v1 : v2));
        float y = gain[c] * (v - mean) * inv + beta[c];
        if (outF) outF[off + c] = y;
        if (outB) outB[off + c] = f2b(y);
    }
}

// ---------------------------------------------------------------------------
extern "C" void kernel_launch(void* const* d_in, const int* in_sizes, int n_in,
                              void* d_out, int out_size, void* d_ws, size_t ws_size,
                              hipStream_t stream) {
    const float* x    = (const float*)d_in[0];
    const float* Wqkv = (const float*)d_in[1];
    const float* Wout = (const float*)d_in[2];
    const float* bout = (const float*)d_in[3];
    const float* W1   = (const float*)d_in[4];
    const float* b1   = (const float*)d_in[5];
    const float* W2   = (const float*)d_in[6];
    const float* b2   = (const float*)d_in[7];
    const float* g1   = (const float*)d_in[8];
    const float* be1  = (const float*)d_in[9];
    const float* g2   = (const float*)d_in[10];
    const float* be2  = (const float*)d_in[11];
    float* out = (float*)d_out;

    // workspace layout (bytes), liveness-aliased; total 83,361,792 B
    char* ws = (char*)d_ws;
    unsigned short* xb     = (unsigned short*)(ws + 0);         // 6,291,456
    unsigned short* wqkvT  = (unsigned short*)(ws + 6291456);   // 3,538,944
    unsigned short* woutT  = (unsigned short*)(ws + 9830400);   // 1,179,648
    unsigned short* w1T    = (unsigned short*)(ws + 11010048);  // 4,718,592
    unsigned short* w2T    = (unsigned short*)(ws + 15728640);  // 4,718,592
    unsigned short* qkv    = (unsigned short*)(ws + 20447232);  // 18,874,368 (dead after attn)
    unsigned short* ctxb   = (unsigned short*)(ws + 39321600);  // 6,291,456  (dead after out-proj)
    float*          attn_o = (float*)(ws + 20447232);           // alias qkv
    float*          h      = (float*)(ws + 45613056);           // 12,582,912
    unsigned short* hb     = (unsigned short*)(ws + 39321600);  // alias ctxb
    unsigned short* ffb    = (unsigned short*)(ws + 58195968);  // 25,165,824
    float*          ff2    = (float*)(ws + 20447232);           // alias attn_o

    // 1) casts + weight transposes
    cvt_f32_bf16<<<3072, 256, 0, stream>>>(x, xb, 786432);
    transpose_to_bf16<<<dim3(72, 24), dim3(32, 8), 0, stream>>>(Wqkv, wqkvT, 768, 2304);
    transpose_to_bf16<<<dim3(24, 24), dim3(32, 8), 0, stream>>>(Wout, woutT, 768, 768);
    transpose_to_bf16<<<dim3(96, 24), dim3(32, 8), 0, stream>>>(W1,   w1T,   768, 3072);
    transpose_to_bf16<<<dim3(24, 96), dim3(32, 8), 0, stream>>>(W2,   w2T,   3072, 768);

    // 2) QKV projection -> bf16
    gemm_bf16<<<dim3(18, 32), 256, 0, stream>>>(xb, wqkvT, nullptr, nullptr, qkv,
                                                4096, 2304, 768, 0);
    // 3) causal flash attention -> ctx bf16
    attn_causal<<<dim3(32, 24), 64, 0, stream>>>(qkv, ctxb);
    // 4) out projection (+bout) -> fp32
    gemm_bf16<<<dim3(6, 32), 256, 0, stream>>>(ctxb, woutT, bout, attn_o, nullptr,
                                               4096, 768, 768, 0);
    // 5) h = LN(x + attn_o) -> fp32 + bf16
    resid_ln<<<4096, 256, 0, stream>>>(x, attn_o, g1, be1, h, hb);
    // 6) ff = relu(h @ W1 + b1) -> bf16
    gemm_bf16<<<dim3(24, 32), 256, 0, stream>>>(hb, w1T, b1, nullptr, ffb,
                                                4096, 3072, 768, 1);
    // 7) ff2 = ff @ W2 + b2 -> fp32
    gemm_bf16<<<dim3(6, 32), 256, 0, stream>>>(ffb, w2T, b2, ff2, nullptr,
                                               4096, 768, 3072, 0);
    // 8) out = LN(h + ff2) -> fp32
    resid_ln<<<4096, 256, 0, stream>>>(h, ff2, g2, be2, out, nullptr);
}

// Round 2
// 427.221 us; speedup vs baseline: 6.2951x; 6.2951x over previous
//
#include <hip/hip_runtime.h>

// ---------------------------------------------------------------------------
// TransformerBlock: B=2,S=2048,D=768,H=12,DH=64,DFF=3072, causal attn, 2x LN
// Round 1: MFMA flash attention (was fp32-vector, 2430us @ 0% MfmaUtil).
// GEMMs unchanged (m97-style 128x128x32 bf16 MFMA tile).
// ---------------------------------------------------------------------------

typedef __attribute__((ext_vector_type(8))) short  short8;   // 8 x bf16 (4 VGPR)
typedef __attribute__((ext_vector_type(4))) float  floatx4;  // 4 x f32 acc

__device__ __forceinline__ float b2f(unsigned short u) {
    return __uint_as_float(((unsigned)u) << 16);
}
__device__ __forceinline__ unsigned short f2b(float f) {  // RNE
    unsigned x = __float_as_uint(f);
    return (unsigned short)((x + 0x7fffu + ((x >> 16) & 1u)) >> 16);
}
__device__ __forceinline__ void async_cp16(const void* g, void* l) {
    __builtin_amdgcn_global_load_lds((const __attribute__((address_space(1))) void*)g,
                                     (__attribute__((address_space(3))) void*)l,
                                     16, 0, 0);
}

// ---------------- fp32 -> bf16 elementwise (x), 4-wide ----------------------
__global__ __launch_bounds__(256) void cvt_f32_bf16(const float* __restrict__ x,
                                                    unsigned short* __restrict__ y,
                                                    int n4) {
    int i = blockIdx.x * 256 + threadIdx.x;
    if (i < n4) {
        float4 v = ((const float4*)x)[i];
        ushort4 u;
        u.x = f2b(v.x); u.y = f2b(v.y); u.z = f2b(v.z); u.w = f2b(v.w);
        ((ushort4*)y)[i] = u;
    }
}

// ---------------- W[K][N] f32 -> Wt[N][K] bf16 ------------------------------
__global__ __launch_bounds__(256) void transpose_to_bf16(const float* __restrict__ W,
                                                         unsigned short* __restrict__ Wt,
                                                         int K, int N) {
    __shared__ float tile[32][33];
    int n0 = blockIdx.x * 32, k0 = blockIdx.y * 32;
    int tx = threadIdx.x, ty = threadIdx.y;  // (32,8)
    for (int i = ty; i < 32; i += 8)
        tile[i][tx] = W[(size_t)(k0 + i) * N + n0 + tx];
    __syncthreads();
    for (int i = ty; i < 32; i += 8)
        Wt[(size_t)(n0 + i) * K + k0 + tx] = f2b(tile[tx][i]);
}

// ---------------- bf16 MFMA GEMM: C[M][N] = A[M][K] @ Bt[N][K]^T ------------
// 128x128x32 tile, 256 threads (4 waves 2x2, each 64x64 via 4x4 mfma 16x16x32)
__global__ __launch_bounds__(256) void gemm_bf16(
    const unsigned short* __restrict__ A,   // [M][K] bf16
    const unsigned short* __restrict__ Bt,  // [N][K] bf16
    const float* __restrict__ bias,         // [N] or null
    float* __restrict__ outF,               // [M][N] or null
    unsigned short* __restrict__ outB,      // [M][N] or null
    int M, int N, int K, int relu)
{
    __shared__ unsigned short As[128][32];
    __shared__ unsigned short Bs[128][32];
    const int tid  = threadIdx.x;
    const int m0   = blockIdx.y * 128;
    const int n0   = blockIdx.x * 128;
    const int lane = tid & 63;
    const int wave = tid >> 6;
    const int wm   = (wave >> 1) * 64;
    const int wn   = (wave & 1) * 64;
    const int fr   = lane & 15;   // row within 16x16 fragment
    const int fq   = lane >> 4;   // quad (k-group / acc row group)

    floatx4 acc[4][4];
    for (int i = 0; i < 4; i++)
        for (int j = 0; j < 4; j++)
            for (int e = 0; e < 4; e++) acc[i][j][e] = 0.f;

    for (int kk = 0; kk < K; kk += 32) {
        __syncthreads();  // previous iter's LDS reads done
        #pragma unroll
        for (int r = 0; r < 2; ++r) {
            int c    = r * 256 + tid;      // 16B-chunk id; lane-contiguous in LDS
            int row  = c >> 2;
            int colb = (c & 3) * 8;
            async_cp16(A  + (size_t)(m0 + row) * K + kk + colb, &As[row][colb]);
            async_cp16(Bt + (size_t)(n0 + row) * K + kk + colb, &Bs[row][colb]);
        }
        __syncthreads();  // drains vmcnt (compiler emits vmcnt(0) before barrier)

        short8 a[4], b[4];
        #pragma unroll
        for (int t = 0; t < 4; t++) a[t] = *(const short8*)&As[wm + t * 16 + fr][fq * 8];
        #pragma unroll
        for (int t = 0; t < 4; t++) b[t] = *(const short8*)&Bs[wn + t * 16 + fr][fq * 8];
        #pragma unroll
        for (int i = 0; i < 4; i++)
            #pragma unroll
            for (int j = 0; j < 4; j++)
                acc[i][j] = __builtin_amdgcn_mfma_f32_16x16x32_bf16(a[i], b[j], acc[i][j], 0, 0, 0);
    }

    // epilogue: C/D layout col = lane&15, row = (lane>>4)*4 + reg
    #pragma unroll
    for (int j = 0; j < 4; j++) {
        int col  = n0 + wn + j * 16 + fr;
        float bv = bias ? bias[col] : 0.f;
        #pragma unroll
        for (int i = 0; i < 4; i++) {
            int rbase = m0 + wm + i * 16 + fq * 4;
            #pragma unroll
            for (int e = 0; e < 4; e++) {
                float v = acc[i][j][e] + bv;
                if (relu) v = fmaxf(v, 0.f);
                size_t idx = (size_t)(rbase + e) * N + col;
                if (outF) outF[idx] = v;
                if (outB) outB[idx] = f2b(v);
            }
        }
    }
}

// ---------------- MFMA causal flash attention -------------------------------
// qkv: [B*S][2304] bf16 (q|k|v chunks of 768); ctx out: [B*S][768] bf16
// grid (S/64, B*H), 256 threads = 4 waves; wave w owns q-rows [w*16, w*16+16).
// Per kv-tile of 64: QK^T (mfma, K stored [kv][d] = Bt form directly),
// online softmax in C-layout regs, P->LDS->A-layout, PV (mfma, V transposed
// in LDS to [d][kv] = Bt form).
__global__ __launch_bounds__(256) void attn_mfma(const unsigned short* __restrict__ qkv,
                                                 unsigned short* __restrict__ ctx) {
    __shared__ unsigned short Ks[64][72];   // [kv][d]   pad->stride 144B (16B-aligned, 2-way banks)
    __shared__ unsigned short Vt[64][72];   // [d][kv]
    __shared__ unsigned short Ps[64][72];   // [q][kv]
    const int tid  = threadIdx.x;
    const int lane = tid & 63;
    const int wave = tid >> 6;
    const int fr   = lane & 15;
    const int fq   = lane >> 4;
    const int wm   = wave * 16;
    const int qblk = blockIdx.x;
    const int q0   = qblk * 64;
    const int bh   = blockIdx.y;
    const int b    = bh / 12, h = bh % 12;
    const unsigned short* base = qkv + (size_t)b * 2048 * 2304;

    // Q fragments (A-operand): rows q0+wm+fr, k-chunks 0-31 / 32-63
    short8 qf[2];
    {
        const unsigned short* qr = base + (size_t)(q0 + wm + fr) * 2304 + h * 64;
        qf[0] = *(const short8*)(qr + fq * 8);
        qf[1] = *(const short8*)(qr + 32 + fq * 8);
    }

    floatx4 o[4];
    #pragma unroll
    for (int nt = 0; nt < 4; nt++)
        #pragma unroll
        for (int e = 0; e < 4; e++) o[nt][e] = 0.f;
    float m_e[4] = {-1e30f, -1e30f, -1e30f, -1e30f};
    float l_e[4] = {0.f, 0.f, 0.f, 0.f};

    for (int kt = 0; kt <= qblk; ++kt) {
        __syncthreads();  // previous tile's Ks/Vt reads done
        // stage K (row-major) and V (transposed) cooperatively
        #pragma unroll
        for (int r = 0; r < 2; ++r) {
            int c = r * 256 + tid;
            // K: 512 chunks of 8 bf16, lane-major along d for coalescing
            int krow = c >> 3, kc8 = (c & 7) * 8;
            uint4 ku = *(const uint4*)(base + (size_t)(kt * 64 + krow) * 2304 + 768 + h * 64 + kc8);
            *(uint4*)&Ks[krow][kc8] = ku;
            // V: lane-major along kv so transposed b16 writes spread banks (2-way)
            int vkv = c & 63, vd0 = (c >> 6) * 8;
            uint4 vu = *(const uint4*)(base + (size_t)(kt * 64 + vkv) * 2304 + 1536 + h * 64 + vd0);
            unsigned short tmp[8];
            *(uint4*)tmp = vu;
            #pragma unroll
            for (int i = 0; i < 8; ++i) Vt[vd0 + i][vkv] = tmp[i];
        }
        __syncthreads();

        // S = Q K^T for this wave's 16 rows x 64 kv cols
        floatx4 s[4];
        #pragma unroll
        for (int nt = 0; nt < 4; nt++)
            #pragma unroll
            for (int e = 0; e < 4; e++) s[nt][e] = 0.f;
        #pragma unroll
        for (int kc = 0; kc < 2; ++kc)
            #pragma unroll
            for (int nt = 0; nt < 4; ++nt) {
                short8 kf = *(const short8*)&Ks[nt * 16 + fr][kc * 32 + fq * 8];
                s[nt] = __builtin_amdgcn_mfma_f32_16x16x32_bf16(qf[kc], kf, s[nt], 0, 0, 0);
            }

        // online softmax; C-layout: row = fq*4+e, col = nt*16+fr
        const bool diag = (kt == qblk);
        float p[4][4];
        #pragma unroll
        for (int e = 0; e < 4; ++e) {
            const int qrow = q0 + wm + fq * 4 + e;
            float mx = -1e30f;
            #pragma unroll
            for (int nt = 0; nt < 4; ++nt) {
                float v = s[nt][e] * 0.125f;  // 1/sqrt(64)
                if (diag && (kt * 64 + nt * 16 + fr) > qrow) v = -1e30f;
                s[nt][e] = v;
                mx = fmaxf(mx, v);
            }
            mx = fmaxf(mx, __shfl_xor(mx, 1));
            mx = fmaxf(mx, __shfl_xor(mx, 2));
            mx = fmaxf(mx, __shfl_xor(mx, 4));
            mx = fmaxf(mx, __shfl_xor(mx, 8));
            float mn = fmaxf(m_e[e], mx);
            float al = __expf(m_e[e] - mn);
            float rs = 0.f;
            #pragma unroll
            for (int nt = 0; nt < 4; ++nt) {
                float pv = __expf(s[nt][e] - mn);
                p[nt][e] = pv;
                rs += pv;
            }
            rs += __shfl_xor(rs, 1);
            rs += __shfl_xor(rs, 2);
            rs += __shfl_xor(rs, 4);
            rs += __shfl_xor(rs, 8);
            l_e[e] = l_e[e] * al + rs;
            m_e[e] = mn;
            #pragma unroll
            for (int nt = 0; nt < 4; ++nt) o[nt][e] *= al;
        }

        // P: C-layout regs -> LDS (own 16 rows only; same-wave RAW, no barrier)
        #pragma unroll
        for (int nt = 0; nt < 4; ++nt)
            #pragma unroll
            for (int e = 0; e < 4; ++e)
                Ps[wm + fq * 4 + e][nt * 16 + fr] = f2b(p[nt][e]);
        __asm__ volatile("s_waitcnt lgkmcnt(0)" ::: "memory");

        // P back in A-layout; PV accumulate into O (C-layout)
        short8 pf[2];
        pf[0] = *(const short8*)&Ps[wm + fr][fq * 8];
        pf[1] = *(const short8*)&Ps[wm + fr][32 + fq * 8];
        #pragma unroll
        for (int kc = 0; kc < 2; ++kc)
            #pragma unroll
            for (int nt = 0; nt < 4; ++nt) {
                short8 vf = *(const short8*)&Vt[nt * 16 + fr][kc * 32 + fq * 8];
                o[nt] = __builtin_amdgcn_mfma_f32_16x16x32_bf16(pf[kc], vf, o[nt], 0, 0, 0);
            }
    }

    // epilogue: normalize and store bf16 ctx
    #pragma unroll
    for (int e = 0; e < 4; ++e) {
        float inv = 1.f / l_e[e];
        unsigned short* orow = ctx + (size_t)(b * 2048 + q0 + wm + fq * 4 + e) * 768 + h * 64;
        #pragma unroll
        for (int nt = 0; nt < 4; ++nt)
            orow[nt * 16 + fr] = f2b(o[nt][e] * inv);
    }
}

// ---------------- fused residual + LayerNorm --------------------------------
// y = g * ((x+r) - mean)/sqrt(var+eps) + be ; one block per row of 768
__global__ __launch_bounds__(256) void resid_ln(const float* __restrict__ X,
                                                const float* __restrict__ R,
                                                const float* __restrict__ gain,
                                                const float* __restrict__ beta,
                                                float* __restrict__ outF,
                                                unsigned short* __restrict__ outB) {
    const int row = blockIdx.x;
    const int t   = threadIdx.x;
    const size_t off = (size_t)row * 768;
    float v0 = X[off + t]       + R[off + t];
    float v1 = X[off + t + 256] + R[off + t + 256];
    float v2 = X[off + t + 512] + R[off + t + 512];
    float s  = v0 + v1 + v2;
    float s2 = v0 * v0 + v1 * v1 + v2 * v2;
    #pragma unroll
    for (int o2 = 32; o2 > 0; o2 >>= 1) {
        s  += __shfl_down(s,  o2);
        s2 += __shfl_down(s2, o2);
    }
    __shared__ float rs[4], rq[4];
    if ((t & 63) == 0) { rs[t >> 6] = s; rq[t >> 6] = s2; }
    __syncthreads();
    float S    = rs[0] + rs[1] + rs[2] + rs[3];
    float S2   = rq[0] + rq[1] + rq[2] + rq[3];
    float mean = S * (1.0f / 768.0f);
    float var  = S2 * (1.0f / 768.0f) - mean * mean;
    float inv  = rsqrtf(var + 1e-5f);
    #pragma unroll
    for (int i = 0; i < 3; i++) {
        int c   = t + i * 256;
        float v = (i == 0 ? v0 : (i == 1 ? v1 : v2));
        float y = gain[c] * (v - mean) * inv + beta[c];
        if (outF) outF[off + c] = y;
        if (outB) outB[off + c] = f2b(y);
    }
}

// ---------------------------------------------------------------------------
extern "C" void kernel_launch(void* const* d_in, const int* in_sizes, int n_in,
                              void* d_out, int out_size, void* d_ws, size_t ws_size,
                              hipStream_t stream) {
    const float* x    = (const float*)d_in[0];
    const float* Wqkv = (const float*)d_in[1];
    const float* Wout = (const float*)d_in[2];
    const float* bout = (const float*)d_in[3];
    const float* W1   = (const float*)d_in[4];
    const float* b1   = (const float*)d_in[5];
    const float* W2   = (const float*)d_in[6];
    const float* b2   = (const float*)d_in[7];
    const float* g1   = (const float*)d_in[8];
    const float* be1  = (const float*)d_in[9];
    const float* g2   = (const float*)d_in[10];
    const float* be2  = (const float*)d_in[11];
    float* out = (float*)d_out;

    // workspace layout (bytes), liveness-aliased; total 83,361,792 B
    char* ws = (char*)d_ws;
    unsigned short* xb     = (unsigned short*)(ws + 0);         // 6,291,456
    unsigned short* wqkvT  = (unsigned short*)(ws + 6291456);   // 3,538,944
    unsigned short* woutT  = (unsigned short*)(ws + 9830400);   // 1,179,648
    unsigned short* w1T    = (unsigned short*)(ws + 11010048);  // 4,718,592
    unsigned short* w2T    = (unsigned short*)(ws + 15728640);  // 4,718,592
    unsigned short* qkv    = (unsigned short*)(ws + 20447232);  // 18,874,368 (dead after attn)
    unsigned short* ctxb   = (unsigned short*)(ws + 39321600);  // 6,291,456  (dead after out-proj)
    float*          attn_o = (float*)(ws + 20447232);           // alias qkv
    float*          h      = (float*)(ws + 45613056);           // 12,582,912
    unsigned short* hb     = (unsigned short*)(ws + 39321600);  // alias ctxb
    unsigned short* ffb    = (unsigned short*)(ws + 58195968);  // 25,165,824
    float*          ff2    = (float*)(ws + 20447232);           // alias attn_o

    // 1) casts + weight transposes
    cvt_f32_bf16<<<3072, 256, 0, stream>>>(x, xb, 786432);
    transpose_to_bf16<<<dim3(72, 24), dim3(32, 8), 0, stream>>>(Wqkv, wqkvT, 768, 2304);
    transpose_to_bf16<<<dim3(24, 24), dim3(32, 8), 0, stream>>>(Wout, woutT, 768, 768);
    transpose_to_bf16<<<dim3(96, 24), dim3(32, 8), 0, stream>>>(W1,   w1T,   768, 3072);
    transpose_to_bf16<<<dim3(24, 96), dim3(32, 8), 0, stream>>>(W2,   w2T,   3072, 768);

    // 2) QKV projection -> bf16
    gemm_bf16<<<dim3(18, 32), 256, 0, stream>>>(xb, wqkvT, nullptr, nullptr, qkv,
                                                4096, 2304, 768, 0);
    // 3) MFMA causal flash attention -> ctx bf16
    attn_mfma<<<dim3(32, 24), 256, 0, stream>>>(qkv, ctxb);
    // 4) out projection (+bout) -> fp32
    gemm_bf16<<<dim3(6, 32), 256, 0, stream>>>(ctxb, woutT, bout, attn_o, nullptr,
                                               4096, 768, 768, 0);
    // 5) h = LN(x + attn_o) -> fp32 + bf16
    resid_ln<<<4096, 256, 0, stream>>>(x, attn_o, g1, be1, h, hb);
    // 6) ff = relu(h @ W1 + b1) -> bf16
    gemm_bf16<<<dim3(24, 32), 256, 0, stream>>>(hb, w1T, b1, nullptr, ffb,
                                                4096, 3072, 768, 1);
    // 7) ff2 = ff @ W2 + b2 -> fp32
    gemm_bf16<<<dim3(6, 32), 256, 0, stream>>>(ffb, w2T, b2, ff2, nullptr,
                                               4096, 768, 3072, 0);
    // 8) out = LN(h + ff2) -> fp32
    resid_ln<<<4096, 256, 0, stream>>>(h, ff2, g2, be2, out, nullptr);
}

// Round 3
// 410.107 us; speedup vs baseline: 6.5578x; 1.0417x over previous
//
#include <hip/hip_runtime.h>

// ---------------------------------------------------------------------------
// TransformerBlock: B=2,S=2048,D=768,H=12,DH=64,DFF=3072, causal attn, 2x LN
// Round 2: attention v2 — split Q/K/V [bh][s][64] layout (GEMM scatter
// epilogue), double-buffered single-barrier kv pipeline, q-tile 128,
// longest-first dispatch. Fused prepass (cvt + 4 weight transposes).
// ---------------------------------------------------------------------------

typedef __attribute__((ext_vector_type(8))) short  short8;   // 8 x bf16 (4 VGPR)
typedef __attribute__((ext_vector_type(4))) float  floatx4;  // 4 x f32 acc

__device__ __forceinline__ float b2f(unsigned short u) {
    return __uint_as_float(((unsigned)u) << 16);
}
__device__ __forceinline__ unsigned short f2b(float f) {  // RNE
    unsigned x = __float_as_uint(f);
    return (unsigned short)((x + 0x7fffu + ((x >> 16) & 1u)) >> 16);
}
__device__ __forceinline__ void async_cp16(const void* g, void* l) {
    __builtin_amdgcn_global_load_lds((const __attribute__((address_space(1))) void*)g,
                                     (__attribute__((address_space(3))) void*)l,
                                     16, 0, 0);
}

// ---------------- fused prepass: x->bf16 + 4 weight transposes --------------
// blocks [0,1728): Wqkv 768x2304 ; [1728,2304): Wout 768x768 ;
// [2304,4608): W1 768x3072 ; [4608,6912): W2 3072x768 ; [6912,9984): cvt x
__global__ __launch_bounds__(256) void prep_all(
    const float* __restrict__ x,    unsigned short* __restrict__ xb,
    const float* __restrict__ Wqkv, unsigned short* __restrict__ wqkvT,
    const float* __restrict__ Wout, unsigned short* __restrict__ woutT,
    const float* __restrict__ W1,   unsigned short* __restrict__ w1T,
    const float* __restrict__ W2,   unsigned short* __restrict__ w2T)
{
    __shared__ float tile[32][33];
    int idx = blockIdx.x;
    int tx = threadIdx.x & 31, ty = threadIdx.x >> 5;  // (32,8) from flat 256
    if (idx >= 6912) {  // cvt x: fp32 -> bf16, 4-wide
        int i = (idx - 6912) * 256 + threadIdx.x;  // < 786432
        float4 v = ((const float4*)x)[i];
        ushort4 u;
        u.x = f2b(v.x); u.y = f2b(v.y); u.z = f2b(v.z); u.w = f2b(v.w);
        ((ushort4*)xb)[i] = u;
        return;
    }
    const float* W; unsigned short* Wt; int K, N, bx, by;
    if (idx < 1728)      { W = Wqkv; Wt = wqkvT; K = 768;  N = 2304; bx = idx % 72;          by = idx / 72; }
    else if (idx < 2304) { W = Wout; Wt = woutT; K = 768;  N = 768;  bx = (idx-1728) % 24;   by = (idx-1728) / 24; }
    else if (idx < 4608) { W = W1;   Wt = w1T;   K = 768;  N = 3072; bx = (idx-2304) % 96;   by = (idx-2304) / 96; }
    else                 { W = W2;   Wt = w2T;   K = 3072; N = 768;  bx = (idx-4608) % 24;   by = (idx-4608) / 24; }
    int n0 = bx * 32, k0 = by * 32;
    for (int i = ty; i < 32; i += 8)
        tile[i][tx] = W[(size_t)(k0 + i) * N + n0 + tx];
    __syncthreads();
    for (int i = ty; i < 32; i += 8)
        Wt[(size_t)(n0 + i) * K + k0 + tx] = f2b(tile[tx][i]);
}

// ---------------- bf16 MFMA GEMM: C[M][N] = A[M][K] @ Bt[N][K]^T ------------
// 128x128x32 tile, 256 threads (4 waves 2x2, each 64x64 via 4x4 mfma 16x16x32)
// mode 0: row-major outF/outB.  mode 1: qkv scatter -> outB is Q|K|V, each
// [24][2048][64] bf16 (contig blocks of 3,145,728 elems).
__global__ __launch_bounds__(256) void gemm_bf16(
    const unsigned short* __restrict__ A,   // [M][K] bf16
    const unsigned short* __restrict__ Bt,  // [N][K] bf16
    const float* __restrict__ bias,         // [N] or null
    float* __restrict__ outF,               // [M][N] or null
    unsigned short* __restrict__ outB,      // [M][N] or null
    int M, int N, int K, int relu, int mode)
{
    __shared__ unsigned short As[128][32];
    __shared__ unsigned short Bs[128][32];
    const int tid  = threadIdx.x;
    const int m0   = blockIdx.y * 128;
    const int n0   = blockIdx.x * 128;
    const int lane = tid & 63;
    const int wave = tid >> 6;
    const int wm   = (wave >> 1) * 64;
    const int wn   = (wave & 1) * 64;
    const int fr   = lane & 15;   // row within 16x16 fragment
    const int fq   = lane >> 4;   // quad (k-group / acc row group)

    floatx4 acc[4][4];
    for (int i = 0; i < 4; i++)
        for (int j = 0; j < 4; j++)
            for (int e = 0; e < 4; e++) acc[i][j][e] = 0.f;

    for (int kk = 0; kk < K; kk += 32) {
        __syncthreads();  // previous iter's LDS reads done
        #pragma unroll
        for (int r = 0; r < 2; ++r) {
            int c    = r * 256 + tid;      // 16B-chunk id; lane-contiguous in LDS
            int row  = c >> 2;
            int colb = (c & 3) * 8;
            async_cp16(A  + (size_t)(m0 + row) * K + kk + colb, &As[row][colb]);
            async_cp16(Bt + (size_t)(n0 + row) * K + kk + colb, &Bs[row][colb]);
        }
        __syncthreads();  // drains vmcnt (compiler emits vmcnt(0) before barrier)

        short8 a[4], b[4];
        #pragma unroll
        for (int t = 0; t < 4; t++) a[t] = *(const short8*)&As[wm + t * 16 + fr][fq * 8];
        #pragma unroll
        for (int t = 0; t < 4; t++) b[t] = *(const short8*)&Bs[wn + t * 16 + fr][fq * 8];
        #pragma unroll
        for (int i = 0; i < 4; i++)
            #pragma unroll
            for (int j = 0; j < 4; j++)
                acc[i][j] = __builtin_amdgcn_mfma_f32_16x16x32_bf16(a[i], b[j], acc[i][j], 0, 0, 0);
    }

    // epilogue: C/D layout col = lane&15, row = (lane>>4)*4 + reg
    if (mode == 1) {
        #pragma unroll
        for (int j = 0; j < 4; j++) {
            int col   = n0 + wn + j * 16 + fr;
            int which = (col >= 1536) ? 2 : (col >= 768 ? 1 : 0);
            int rem   = col - which * 768;
            int hh    = rem >> 6, d = rem & 63;
            #pragma unroll
            for (int i = 0; i < 4; i++) {
                int rbase = m0 + wm + i * 16 + fq * 4;
                #pragma unroll
                for (int e = 0; e < 4; e++) {
                    int row = rbase + e;
                    int b_  = row >> 11, srow = row & 2047;
                    size_t idx = (size_t)which * 3145728 +
                                 ((size_t)(b_ * 12 + hh) * 2048 + srow) * 64 + d;
                    outB[idx] = f2b(acc[i][j][e]);
                }
            }
        }
        return;
    }
    #pragma unroll
    for (int j = 0; j < 4; j++) {
        int col  = n0 + wn + j * 16 + fr;
        float bv = bias ? bias[col] : 0.f;
        #pragma unroll
        for (int i = 0; i < 4; i++) {
            int rbase = m0 + wm + i * 16 + fq * 4;
            #pragma unroll
            for (int e = 0; e < 4; e++) {
                float v = acc[i][j][e] + bv;
                if (relu) v = fmaxf(v, 0.f);
                size_t idx = (size_t)(rbase + e) * N + col;
                if (outF) outF[idx] = v;
                if (outB) outB[idx] = f2b(v);
            }
        }
    }
}

// ---------------- MFMA causal flash attention v2 ----------------------------
// Q/K/V: [bh][2048][64] bf16. ctx out: [b][s][768] bf16.
// grid (24 bh, 16), 256 thr = 4 waves; qb = 15-blockIdx.y (longest first);
// q-tile 128 (wave owns 32 rows = 2 row-frags), kv-tile 64, double-buffered
// K/V staging with one barrier per tile; global loads for tile k+1 issued
// before compute of tile k.
__global__ __launch_bounds__(256) void attn_mfma2(const unsigned short* __restrict__ Qg,
                                                  const unsigned short* __restrict__ Kg,
                                                  const unsigned short* __restrict__ Vg,
                                                  unsigned short* __restrict__ ctx) {
    __shared__ unsigned short Ks[2][64][72];   // [buf][kv][d], stride pad 72
    __shared__ unsigned short Vt[2][64][72];   // [buf][d][kv]
    __shared__ unsigned short Ps[128][72];     // [q][kv]
    const int tid  = threadIdx.x;
    const int lane = tid & 63;
    const int wave = tid >> 6;
    const int fr   = lane & 15;
    const int fq   = lane >> 4;
    const int wm   = wave * 32;
    const int bh   = blockIdx.x;
    const int qb   = 15 - blockIdx.y;          // longest blocks dispatched first
    const int q0   = qb * 128;
    const int b    = bh / 12, h = bh % 12;
    const unsigned short* Qb = Qg + (size_t)bh * 2048 * 64;
    const unsigned short* Kb = Kg + (size_t)bh * 2048 * 64;
    const unsigned short* Vb = Vg + (size_t)bh * 2048 * 64;

    // Q fragments: rf in {0,1} -> rows q0+wm+rf*16+fr; kc chunk of 32
    short8 qf[2][2];
    #pragma unroll
    for (int rf = 0; rf < 2; ++rf) {
        const unsigned short* qr = Qb + (size_t)(q0 + wm + rf * 16 + fr) * 64;
        qf[rf][0] = *(const short8*)(qr + fq * 8);
        qf[rf][1] = *(const short8*)(qr + 32 + fq * 8);
    }

    floatx4 o[2][4];
    float m_s[2][4], l_s[2][4];
    #pragma unroll
    for (int rf = 0; rf < 2; ++rf)
        #pragma unroll
        for (int nt = 0; nt < 4; ++nt)
            #pragma unroll
            for (int e = 0; e < 4; ++e) o[rf][nt][e] = 0.f;
    #pragma unroll
    for (int rf = 0; rf < 2; ++rf)
        #pragma unroll
        for (int e = 0; e < 4; ++e) { m_s[rf][e] = -1e30f; l_s[rf][e] = 0.f; }

    const int ntiles = 2 * qb + 2;
    const int c0 = tid, c1 = tid + 256;
    // chunk mapping: K: row=c>>3, d8=(c&7)*8 ; V: kv=c&63, d0=(c>>6)*8
    uint4 kr0, kr1, vr0, vr1;

#define LOADT(KT)                                                              \
    {                                                                          \
        int base = (KT) * 64;                                                  \
        kr0 = *(const uint4*)(Kb + (size_t)(base + (c0 >> 3)) * 64 + (c0 & 7) * 8); \
        kr1 = *(const uint4*)(Kb + (size_t)(base + (c1 >> 3)) * 64 + (c1 & 7) * 8); \
        vr0 = *(const uint4*)(Vb + (size_t)(base + (c0 & 63)) * 64 + (c0 >> 6) * 8); \
        vr1 = *(const uint4*)(Vb + (size_t)(base + (c1 & 63)) * 64 + (c1 >> 6) * 8); \
    }
#define WRITET(BUF)                                                            \
    {                                                                          \
        *(uint4*)&Ks[BUF][c0 >> 3][(c0 & 7) * 8] = kr0;                        \
        *(uint4*)&Ks[BUF][c1 >> 3][(c1 & 7) * 8] = kr1;                        \
        unsigned short t0[8]; *(uint4*)t0 = vr0;                               \
        _Pragma("unroll") for (int i_ = 0; i_ < 8; ++i_)                       \
            Vt[BUF][(c0 >> 6) * 8 + i_][c0 & 63] = t0[i_];                     \
        unsigned short t1[8]; *(uint4*)t1 = vr1;                               \
        _Pragma("unroll") for (int i_ = 0; i_ < 8; ++i_)                       \
            Vt[BUF][(c1 >> 6) * 8 + i_][c1 & 63] = t1[i_];                     \
    }

    LOADT(0);
    WRITET(0);
    __syncthreads();

    for (int kt = 0; kt < ntiles; ++kt) {
        const int  cur  = kt & 1;
        const bool more = (kt + 1 < ntiles);
        if (more) LOADT(kt + 1);   // global loads in flight under compute

        // K fragments (shared by both row-frags)
        short8 kf[2][4];
        #pragma unroll
        for (int kc = 0; kc < 2; ++kc)
            #pragma unroll
            for (int nt = 0; nt < 4; ++nt)
                kf[kc][nt] = *(const short8*)&Ks[cur][nt * 16 + fr][kc * 32 + fq * 8];

        // S = Q K^T  (2 row-frags x 4 col-frags)
        floatx4 s[2][4];
        #pragma unroll
        for (int rf = 0; rf < 2; ++rf)
            #pragma unroll
            for (int nt = 0; nt < 4; ++nt)
                #pragma unroll
                for (int e = 0; e < 4; ++e) s[rf][nt][e] = 0.f;
        #pragma unroll
        for (int rf = 0; rf < 2; ++rf)
            #pragma unroll
            for (int kc = 0; kc < 2; ++kc)
                #pragma unroll
                for (int nt = 0; nt < 4; ++nt)
                    s[rf][nt] = __builtin_amdgcn_mfma_f32_16x16x32_bf16(qf[rf][kc], kf[kc][nt], s[rf][nt], 0, 0, 0);

        // online softmax; C-layout: row = fq*4+e, col = nt*16+fr
        const bool need_mask = (kt * 64 + 63) > (q0 + wm);
        #pragma unroll
        for (int rf = 0; rf < 2; ++rf)
            #pragma unroll
            for (int e = 0; e < 4; ++e) {
                const int qrow = q0 + wm + rf * 16 + fq * 4 + e;
                float mx = -1e30f;
                #pragma unroll
                for (int nt = 0; nt < 4; ++nt) {
                    float v = s[rf][nt][e] * 0.125f;  // 1/sqrt(64)
                    if (need_mask && (kt * 64 + nt * 16 + fr) > qrow) v = -1e30f;
                    s[rf][nt][e] = v;
                    mx = fmaxf(mx, v);
                }
                mx = fmaxf(mx, __shfl_xor(mx, 1));
                mx = fmaxf(mx, __shfl_xor(mx, 2));
                mx = fmaxf(mx, __shfl_xor(mx, 4));
                mx = fmaxf(mx, __shfl_xor(mx, 8));
                float mn = fmaxf(m_s[rf][e], mx);
                float al = __expf(m_s[rf][e] - mn);
                float rs = 0.f;
                #pragma unroll
                for (int nt = 0; nt < 4; ++nt) {
                    float pv = __expf(s[rf][nt][e] - mn);
                    s[rf][nt][e] = pv;
                    rs += pv;
                }
                rs += __shfl_xor(rs, 1);
                rs += __shfl_xor(rs, 2);
                rs += __shfl_xor(rs, 4);
                rs += __shfl_xor(rs, 8);
                l_s[rf][e] = l_s[rf][e] * al + rs;
                m_s[rf][e] = mn;
                #pragma unroll
                for (int nt = 0; nt < 4; ++nt) {
                    o[rf][nt][e] *= al;
                    Ps[wm + rf * 16 + fq * 4 + e][nt * 16 + fr] = f2b(s[rf][nt][e]);
                }
            }
        __asm__ volatile("s_waitcnt lgkmcnt(0)" ::: "memory");  // own-wave P RAW

        // P (A-layout) @ V^T (B-layout) -> O
        short8 pf[2][2], vf[2][4];
        #pragma unroll
        for (int rf = 0; rf < 2; ++rf)
            #pragma unroll
            for (int kc = 0; kc < 2; ++kc)
                pf[rf][kc] = *(const short8*)&Ps[wm + rf * 16 + fr][kc * 32 + fq * 8];
        #pragma unroll
        for (int kc = 0; kc < 2; ++kc)
            #pragma unroll
            for (int nt = 0; nt < 4; ++nt)
                vf[kc][nt] = *(const short8*)&Vt[cur][nt * 16 + fr][kc * 32 + fq * 8];
        #pragma unroll
        for (int rf = 0; rf < 2; ++rf)
            #pragma unroll
            for (int kc = 0; kc < 2; ++kc)
                #pragma unroll
                for (int nt = 0; nt < 4; ++nt)
                    o[rf][nt] = __builtin_amdgcn_mfma_f32_16x16x32_bf16(pf[rf][kc], vf[kc][nt], o[rf][nt], 0, 0, 0);

        if (more) {
            WRITET(cur ^ 1);     // disjoint buffer: no barrier before writes
            __syncthreads();     // publish tile kt+1 before next iteration
        }
    }
#undef LOADT
#undef WRITET

    // epilogue: normalize, store ctx [b][s][768]
    #pragma unroll
    for (int rf = 0; rf < 2; ++rf)
        #pragma unroll
        for (int e = 0; e < 4; ++e) {
            float inv = 1.f / l_s[rf][e];
            int row = q0 + wm + rf * 16 + fq * 4 + e;
            unsigned short* orow = ctx + ((size_t)(b * 2048 + row)) * 768 + h * 64;
            #pragma unroll
            for (int nt = 0; nt < 4; ++nt)
                orow[nt * 16 + fr] = f2b(o[rf][nt][e] * inv);
        }
}

// ---------------- fused residual + LayerNorm --------------------------------
__global__ __launch_bounds__(256) void resid_ln(const float* __restrict__ X,
                                                const float* __restrict__ R,
                                                const float* __restrict__ gain,
                                                const float* __restrict__ beta,
                                                float* __restrict__ outF,
                                                unsigned short* __restrict__ outB) {
    const int row = blockIdx.x;
    const int t   = threadIdx.x;
    const size_t off = (size_t)row * 768;
    float v0 = X[off + t]       + R[off + t];
    float v1 = X[off + t + 256] + R[off + t + 256];
    float v2 = X[off + t + 512] + R[off + t + 512];
    float s  = v0 + v1 + v2;
    float s2 = v0 * v0 + v1 * v1 + v2 * v2;
    #pragma unroll
    for (int o2 = 32; o2 > 0; o2 >>= 1) {
        s  += __shfl_down(s,  o2);
        s2 += __shfl_down(s2, o2);
    }
    __shared__ float rs[4], rq[4];
    if ((t & 63) == 0) { rs[t >> 6] = s; rq[t >> 6] = s2; }
    __syncthreads();
    float S    = rs[0] + rs[1] + rs[2] + rs[3];
    float S2   = rq[0] + rq[1] + rq[2] + rq[3];
    float mean = S * (1.0f / 768.0f);
    float var  = S2 * (1.0f / 768.0f) - mean * mean;
    float inv  = rsqrtf(var + 1e-5f);
    #pragma unroll
    for (int i = 0; i < 3; i++) {
        int c   = t + i * 256;
        float v = (i == 0 ? v0 : (i == 1 ? v1 : v2));
        float y = gain[c] * (v - mean) * inv + beta[c];
        if (outF) outF[off + c] = y;
        if (outB) outB[off + c] = f2b(y);
    }
}

// ---------------------------------------------------------------------------
extern "C" void kernel_launch(void* const* d_in, const int* in_sizes, int n_in,
                              void* d_out, int out_size, void* d_ws, size_t ws_size,
                              hipStream_t stream) {
    const float* x    = (const float*)d_in[0];
    const float* Wqkv = (const float*)d_in[1];
    const float* Wout = (const float*)d_in[2];
    const float* bout = (const float*)d_in[3];
    const float* W1   = (const float*)d_in[4];
    const float* b1   = (const float*)d_in[5];
    const float* W2   = (const float*)d_in[6];
    const float* b2   = (const float*)d_in[7];
    const float* g1   = (const float*)d_in[8];
    const float* be1  = (const float*)d_in[9];
    const float* g2   = (const float*)d_in[10];
    const float* be2  = (const float*)d_in[11];
    float* out = (float*)d_out;

    // workspace layout (bytes), liveness-aliased
    char* ws = (char*)d_ws;
    unsigned short* xb     = (unsigned short*)(ws + 0);         // 6,291,456
    unsigned short* wqkvT  = (unsigned short*)(ws + 6291456);   // 3,538,944
    unsigned short* woutT  = (unsigned short*)(ws + 9830400);   // 1,179,648
    unsigned short* w1T    = (unsigned short*)(ws + 11010048);  // 4,718,592
    unsigned short* w2T    = (unsigned short*)(ws + 15728640);  // 4,718,592
    unsigned short* qkvG   = (unsigned short*)(ws + 20447232);  // Q|K|V 3x6,291,456
    unsigned short* Qg     = qkvG;
    unsigned short* Kg     = qkvG + 3145728;
    unsigned short* Vg     = qkvG + 6291456;
    unsigned short* ctxb   = (unsigned short*)(ws + 39321600);  // 6,291,456
    float*          attn_o = (float*)(ws + 20447232);           // alias qkvG
    float*          h      = (float*)(ws + 45613056);           // 12,582,912
    unsigned short* hb     = (unsigned short*)(ws + 39321600);  // alias ctxb
    unsigned short* ffb    = (unsigned short*)(ws + 58195968);  // 25,165,824
    float*          ff2    = (float*)(ws + 20447232);           // alias qkvG

    // 1) fused prepass: cvt x + all weight transposes
    prep_all<<<9984, 256, 0, stream>>>(x, xb, Wqkv, wqkvT, Wout, woutT, W1, w1T, W2, w2T);

    // 2) QKV projection -> Q/K/V [bh][s][64] bf16 (scatter epilogue)
    gemm_bf16<<<dim3(18, 32), 256, 0, stream>>>(xb, wqkvT, nullptr, nullptr, qkvG,
                                                4096, 2304, 768, 0, 1);
    // 3) MFMA causal flash attention -> ctx bf16
    attn_mfma2<<<dim3(24, 16), 256, 0, stream>>>(Qg, Kg, Vg, ctxb);
    // 4) out projection (+bout) -> fp32
    gemm_bf16<<<dim3(6, 32), 256, 0, stream>>>(ctxb, woutT, bout, attn_o, nullptr,
                                               4096, 768, 768, 0, 0);
    // 5) h = LN(x + attn_o) -> fp32 + bf16
    resid_ln<<<4096, 256, 0, stream>>>(x, attn_o, g1, be1, h, hb);
    // 6) ff = relu(h @ W1 + b1) -> bf16
    gemm_bf16<<<dim3(24, 32), 256, 0, stream>>>(hb, w1T, b1, nullptr, ffb,
                                                4096, 3072, 768, 1, 0);
    // 7) ff2 = ff @ W2 + b2 -> fp32
    gemm_bf16<<<dim3(6, 32), 256, 0, stream>>>(ffb, w2T, b2, ff2, nullptr,
                                               4096, 768, 3072, 0, 0);
    // 8) out = LN(h + ff2) -> fp32
    resid_ln<<<4096, 256, 0, stream>>>(h, ff2, g2, be2, out, nullptr);
}

// Round 4
// 385.709 us; speedup vs baseline: 6.9726x; 1.0633x over previous
//
#include <hip/hip_runtime.h>

// ---------------------------------------------------------------------------
// TransformerBlock: B=2,S=2048,D=768,H=12,DH=64,DFF=3072, causal attn, 2x LN
// Round 3: flash-decoding kv-split attention. Each (bh, q128-block) kv-range
// split into 256-wide chunks -> 1728 balanced blocks writing partial (O,m,l);
// combine kernel merges. Fixes the 9% occupancy / triangular-makespan limit
// of round 2 (MfmaUtil 5%, VALU 25%, nothing saturated).
// ---------------------------------------------------------------------------

typedef __attribute__((ext_vector_type(8))) short  short8;   // 8 x bf16 (4 VGPR)
typedef __attribute__((ext_vector_type(4))) float  floatx4;  // 4 x f32 acc

__device__ __forceinline__ float b2f(unsigned short u) {
    return __uint_as_float(((unsigned)u) << 16);
}
__device__ __forceinline__ unsigned short f2b(float f) {  // RNE
    unsigned x = __float_as_uint(f);
    return (unsigned short)((x + 0x7fffu + ((x >> 16) & 1u)) >> 16);
}
__device__ __forceinline__ void async_cp16(const void* g, void* l) {
    __builtin_amdgcn_global_load_lds((const __attribute__((address_space(1))) void*)g,
                                     (__attribute__((address_space(3))) void*)l,
                                     16, 0, 0);
}
// chunk-slot prefix: ofs(qb) = sum_{j<qb} ceil((j+1)/2)
__device__ __forceinline__ int chunk_ofs(int qb) {
    int t = qb >> 1;
    return (qb & 1) ? (t + 1) * (t + 1) : t * (t + 1);
}

// ---------------- fused prepass: x->bf16 + 4 weight transposes --------------
__global__ __launch_bounds__(256) void prep_all(
    const float* __restrict__ x,    unsigned short* __restrict__ xb,
    const float* __restrict__ Wqkv, unsigned short* __restrict__ wqkvT,
    const float* __restrict__ Wout, unsigned short* __restrict__ woutT,
    const float* __restrict__ W1,   unsigned short* __restrict__ w1T,
    const float* __restrict__ W2,   unsigned short* __restrict__ w2T)
{
    __shared__ float tile[32][33];
    int idx = blockIdx.x;
    int tx = threadIdx.x & 31, ty = threadIdx.x >> 5;  // (32,8) from flat 256
    if (idx >= 6912) {  // cvt x: fp32 -> bf16, 4-wide
        int i = (idx - 6912) * 256 + threadIdx.x;  // < 786432
        float4 v = ((const float4*)x)[i];
        ushort4 u;
        u.x = f2b(v.x); u.y = f2b(v.y); u.z = f2b(v.z); u.w = f2b(v.w);
        ((ushort4*)xb)[i] = u;
        return;
    }
    const float* W; unsigned short* Wt; int K, N, bx, by;
    if (idx < 1728)      { W = Wqkv; Wt = wqkvT; K = 768;  N = 2304; bx = idx % 72;          by = idx / 72; }
    else if (idx < 2304) { W = Wout; Wt = woutT; K = 768;  N = 768;  bx = (idx-1728) % 24;   by = (idx-1728) / 24; }
    else if (idx < 4608) { W = W1;   Wt = w1T;   K = 768;  N = 3072; bx = (idx-2304) % 96;   by = (idx-2304) / 96; }
    else                 { W = W2;   Wt = w2T;   K = 3072; N = 768;  bx = (idx-4608) % 24;   by = (idx-4608) / 24; }
    int n0 = bx * 32, k0 = by * 32;
    for (int i = ty; i < 32; i += 8)
        tile[i][tx] = W[(size_t)(k0 + i) * N + n0 + tx];
    __syncthreads();
    for (int i = ty; i < 32; i += 8)
        Wt[(size_t)(n0 + i) * K + k0 + tx] = f2b(tile[tx][i]);
}

// ---------------- bf16 MFMA GEMM: C[M][N] = A[M][K] @ Bt[N][K]^T ------------
__global__ __launch_bounds__(256) void gemm_bf16(
    const unsigned short* __restrict__ A,   // [M][K] bf16
    const unsigned short* __restrict__ Bt,  // [N][K] bf16
    const float* __restrict__ bias,         // [N] or null
    float* __restrict__ outF,               // [M][N] or null
    unsigned short* __restrict__ outB,      // [M][N] or null
    int M, int N, int K, int relu, int mode)
{
    __shared__ unsigned short As[128][32];
    __shared__ unsigned short Bs[128][32];
    const int tid  = threadIdx.x;
    const int m0   = blockIdx.y * 128;
    const int n0   = blockIdx.x * 128;
    const int lane = tid & 63;
    const int wave = tid >> 6;
    const int wm   = (wave >> 1) * 64;
    const int wn   = (wave & 1) * 64;
    const int fr   = lane & 15;   // row within 16x16 fragment
    const int fq   = lane >> 4;   // quad (k-group / acc row group)

    floatx4 acc[4][4];
    for (int i = 0; i < 4; i++)
        for (int j = 0; j < 4; j++)
            for (int e = 0; e < 4; e++) acc[i][j][e] = 0.f;

    for (int kk = 0; kk < K; kk += 32) {
        __syncthreads();
        #pragma unroll
        for (int r = 0; r < 2; ++r) {
            int c    = r * 256 + tid;
            int row  = c >> 2;
            int colb = (c & 3) * 8;
            async_cp16(A  + (size_t)(m0 + row) * K + kk + colb, &As[row][colb]);
            async_cp16(Bt + (size_t)(n0 + row) * K + kk + colb, &Bs[row][colb]);
        }
        __syncthreads();

        short8 a[4], b[4];
        #pragma unroll
        for (int t = 0; t < 4; t++) a[t] = *(const short8*)&As[wm + t * 16 + fr][fq * 8];
        #pragma unroll
        for (int t = 0; t < 4; t++) b[t] = *(const short8*)&Bs[wn + t * 16 + fr][fq * 8];
        #pragma unroll
        for (int i = 0; i < 4; i++)
            #pragma unroll
            for (int j = 0; j < 4; j++)
                acc[i][j] = __builtin_amdgcn_mfma_f32_16x16x32_bf16(a[i], b[j], acc[i][j], 0, 0, 0);
    }

    if (mode == 1) {  // qkv scatter: outB = Q|K|V, each [24][2048][64]
        #pragma unroll
        for (int j = 0; j < 4; j++) {
            int col   = n0 + wn + j * 16 + fr;
            int which = (col >= 1536) ? 2 : (col >= 768 ? 1 : 0);
            int rem   = col - which * 768;
            int hh    = rem >> 6, d = rem & 63;
            #pragma unroll
            for (int i = 0; i < 4; i++) {
                int rbase = m0 + wm + i * 16 + fq * 4;
                #pragma unroll
                for (int e = 0; e < 4; e++) {
                    int row = rbase + e;
                    int b_  = row >> 11, srow = row & 2047;
                    size_t idx = (size_t)which * 3145728 +
                                 ((size_t)(b_ * 12 + hh) * 2048 + srow) * 64 + d;
                    outB[idx] = f2b(acc[i][j][e]);
                }
            }
        }
        return;
    }
    #pragma unroll
    for (int j = 0; j < 4; j++) {
        int col  = n0 + wn + j * 16 + fr;
        float bv = bias ? bias[col] : 0.f;
        #pragma unroll
        for (int i = 0; i < 4; i++) {
            int rbase = m0 + wm + i * 16 + fq * 4;
            #pragma unroll
            for (int e = 0; e < 4; e++) {
                float v = acc[i][j][e] + bv;
                if (relu) v = fmaxf(v, 0.f);
                size_t idx = (size_t)(rbase + e) * N + col;
                if (outF) outF[idx] = v;
                if (outB) outB[idx] = f2b(v);
            }
        }
    }
}

// ---------------- attention partial (kv-split flash) ------------------------
// grid (72, 24): x = chunk slot r within bh, y = bh. 256 thr = 4 waves.
// slot r -> (qb, c): qb s.t. ofs(qb) <= r < ofs(qb+1), c = r - ofs(qb).
// Block computes q-rows [qb*128, qb*128+128) against kv tiles
// [4c, min(4c+4, 2qb+2)) of 64, writes unnormalized partial O (bf16) + m,l.
__global__ __launch_bounds__(256) void attn_part(const unsigned short* __restrict__ Qg,
                                                 const unsigned short* __restrict__ Kg,
                                                 const unsigned short* __restrict__ Vg,
                                                 unsigned short* __restrict__ pO,
                                                 float* __restrict__ pM,
                                                 float* __restrict__ pL) {
    __shared__ unsigned short Ks[2][64][72];
    __shared__ unsigned short Vt[2][64][72];
    __shared__ unsigned short Ps[128][72];
    const int tid  = threadIdx.x;
    const int lane = tid & 63;
    const int wave = tid >> 6;
    const int fr   = lane & 15;
    const int fq   = lane >> 4;
    const int wm   = wave * 32;
    const int r    = blockIdx.x;
    const int bh   = blockIdx.y;
    int qb = 0;
    for (int q_ = 15; q_ >= 0; --q_) if (r >= chunk_ofs(q_)) { qb = q_; break; }
    const int c     = r - chunk_ofs(qb);
    const int q0    = qb * 128;
    const int tile0 = 4 * c;
    const int ntk   = min(4, 2 * (qb + 1) - 4 * c);
    const int slot  = bh * 72 + r;
    const unsigned short* Qb = Qg + (size_t)bh * 2048 * 64;
    const unsigned short* Kb = Kg + (size_t)bh * 2048 * 64;
    const unsigned short* Vb = Vg + (size_t)bh * 2048 * 64;

    short8 qf[2][2];
    #pragma unroll
    for (int rf = 0; rf < 2; ++rf) {
        const unsigned short* qr = Qb + (size_t)(q0 + wm + rf * 16 + fr) * 64;
        qf[rf][0] = *(const short8*)(qr + fq * 8);
        qf[rf][1] = *(const short8*)(qr + 32 + fq * 8);
    }

    floatx4 o[2][4];
    float m_s[2][4], l_s[2][4];
    #pragma unroll
    for (int rf = 0; rf < 2; ++rf)
        #pragma unroll
        for (int nt = 0; nt < 4; ++nt)
            #pragma unroll
            for (int e = 0; e < 4; ++e) o[rf][nt][e] = 0.f;
    #pragma unroll
    for (int rf = 0; rf < 2; ++rf)
        #pragma unroll
        for (int e = 0; e < 4; ++e) { m_s[rf][e] = -1e30f; l_s[rf][e] = 0.f; }

    const int c0 = tid, c1 = tid + 256;
    uint4 kr0, kr1, vr0, vr1;

#define LOADT(TG)                                                              \
    {                                                                          \
        int base = (TG) * 64;                                                  \
        kr0 = *(const uint4*)(Kb + (size_t)(base + (c0 >> 3)) * 64 + (c0 & 7) * 8); \
        kr1 = *(const uint4*)(Kb + (size_t)(base + (c1 >> 3)) * 64 + (c1 & 7) * 8); \
        vr0 = *(const uint4*)(Vb + (size_t)(base + (c0 & 63)) * 64 + (c0 >> 6) * 8); \
        vr1 = *(const uint4*)(Vb + (size_t)(base + (c1 & 63)) * 64 + (c1 >> 6) * 8); \
    }
#define WRITET(BUF)                                                            \
    {                                                                          \
        *(uint4*)&Ks[BUF][c0 >> 3][(c0 & 7) * 8] = kr0;                        \
        *(uint4*)&Ks[BUF][c1 >> 3][(c1 & 7) * 8] = kr1;                        \
        unsigned short t0[8]; *(uint4*)t0 = vr0;                               \
        _Pragma("unroll") for (int i_ = 0; i_ < 8; ++i_)                       \
            Vt[BUF][(c0 >> 6) * 8 + i_][c0 & 63] = t0[i_];                     \
        unsigned short t1[8]; *(uint4*)t1 = vr1;                               \
        _Pragma("unroll") for (int i_ = 0; i_ < 8; ++i_)                       \
            Vt[BUF][(c1 >> 6) * 8 + i_][c1 & 63] = t1[i_];                     \
    }

    LOADT(tile0);
    WRITET(0);
    __syncthreads();

    for (int kt = 0; kt < ntk; ++kt) {
        const int  tg   = tile0 + kt;
        const int  cur  = kt & 1;
        const bool more = (kt + 1 < ntk);
        if (more) LOADT(tg + 1);

        short8 kf[2][4];
        #pragma unroll
        for (int kc = 0; kc < 2; ++kc)
            #pragma unroll
            for (int nt = 0; nt < 4; ++nt)
                kf[kc][nt] = *(const short8*)&Ks[cur][nt * 16 + fr][kc * 32 + fq * 8];

        floatx4 s[2][4];
        #pragma unroll
        for (int rf = 0; rf < 2; ++rf)
            #pragma unroll
            for (int nt = 0; nt < 4; ++nt)
                #pragma unroll
                for (int e = 0; e < 4; ++e) s[rf][nt][e] = 0.f;
        #pragma unroll
        for (int rf = 0; rf < 2; ++rf)
            #pragma unroll
            for (int kc = 0; kc < 2; ++kc)
                #pragma unroll
                for (int nt = 0; nt < 4; ++nt)
                    s[rf][nt] = __builtin_amdgcn_mfma_f32_16x16x32_bf16(qf[rf][kc], kf[kc][nt], s[rf][nt], 0, 0, 0);

        const bool need_mask = (tg * 64 + 63) > (q0 + wm);
        #pragma unroll
        for (int rf = 0; rf < 2; ++rf)
            #pragma unroll
            for (int e = 0; e < 4; ++e) {
                const int qrow = q0 + wm + rf * 16 + fq * 4 + e;
                float mx = -1e30f;
                #pragma unroll
                for (int nt = 0; nt < 4; ++nt) {
                    float v = s[rf][nt][e] * 0.125f;  // 1/sqrt(64)
                    if (need_mask && (tg * 64 + nt * 16 + fr) > qrow) v = -1e30f;
                    s[rf][nt][e] = v;
                    mx = fmaxf(mx, v);
                }
                mx = fmaxf(mx, __shfl_xor(mx, 1));
                mx = fmaxf(mx, __shfl_xor(mx, 2));
                mx = fmaxf(mx, __shfl_xor(mx, 4));
                mx = fmaxf(mx, __shfl_xor(mx, 8));
                float mn = fmaxf(m_s[rf][e], mx);  // finite after tile 0: chunk
                float al = __expf(m_s[rf][e] - mn); // start 256c <= qrow always
                float rs = 0.f;
                #pragma unroll
                for (int nt = 0; nt < 4; ++nt) {
                    float pv = __expf(s[rf][nt][e] - mn);
                    s[rf][nt][e] = pv;
                    rs += pv;
                }
                rs += __shfl_xor(rs, 1);
                rs += __shfl_xor(rs, 2);
                rs += __shfl_xor(rs, 4);
                rs += __shfl_xor(rs, 8);
                l_s[rf][e] = l_s[rf][e] * al + rs;
                m_s[rf][e] = mn;
                #pragma unroll
                for (int nt = 0; nt < 4; ++nt) {
                    o[rf][nt][e] *= al;
                    Ps[wm + rf * 16 + fq * 4 + e][nt * 16 + fr] = f2b(s[rf][nt][e]);
                }
            }
        __asm__ volatile("s_waitcnt lgkmcnt(0)" ::: "memory");

        short8 pf[2][2], vf[2][4];
        #pragma unroll
        for (int rf = 0; rf < 2; ++rf)
            #pragma unroll
            for (int kc = 0; kc < 2; ++kc)
                pf[rf][kc] = *(const short8*)&Ps[wm + rf * 16 + fr][kc * 32 + fq * 8];
        #pragma unroll
        for (int kc = 0; kc < 2; ++kc)
            #pragma unroll
            for (int nt = 0; nt < 4; ++nt)
                vf[kc][nt] = *(const short8*)&Vt[cur][nt * 16 + fr][kc * 32 + fq * 8];
        #pragma unroll
        for (int rf = 0; rf < 2; ++rf)
            #pragma unroll
            for (int kc = 0; kc < 2; ++kc)
                #pragma unroll
                for (int nt = 0; nt < 4; ++nt)
                    o[rf][nt] = __builtin_amdgcn_mfma_f32_16x16x32_bf16(pf[rf][kc], vf[kc][nt], o[rf][nt], 0, 0, 0);

        if (more) {
            WRITET(cur ^ 1);
            __syncthreads();
        }
    }
#undef LOADT
#undef WRITET

    // epilogue: unnormalized partial O + per-row m,l
    #pragma unroll
    for (int rf = 0; rf < 2; ++rf)
        #pragma unroll
        for (int e = 0; e < 4; ++e) {
            int row = wm + rf * 16 + fq * 4 + e;
            unsigned short* orow = pO + ((size_t)slot * 128 + row) * 64;
            #pragma unroll
            for (int nt = 0; nt < 4; ++nt)
                orow[nt * 16 + fr] = f2b(o[rf][nt][e]);
            if (fr == 0) {
                pM[(size_t)slot * 128 + row] = m_s[rf][e];
                pL[(size_t)slot * 128 + row] = l_s[rf][e];
            }
        }
}

// ---------------- attention combine -----------------------------------------
// grid (16, 24): x = qb, y = bh. 256 thr; 2 threads per q-row, 32 cols each.
__global__ __launch_bounds__(256) void attn_combine(const unsigned short* __restrict__ pO,
                                                    const float* __restrict__ pM,
                                                    const float* __restrict__ pL,
                                                    unsigned short* __restrict__ ctx) {
    const int qb  = blockIdx.x;
    const int bh  = blockIdx.y;
    const int b   = bh / 12, h = bh % 12;
    const int nch = (qb + 2) >> 1;
    const int slot0 = bh * 72 + chunk_ofs(qb);
    const int tid = threadIdx.x;
    const int row = tid >> 1;
    const int col0 = (tid & 1) * 32;

    float mv[8], lv[8];
    float M = -1e30f;
    for (int i = 0; i < nch; ++i) {
        mv[i] = pM[(size_t)(slot0 + i) * 128 + row];
        lv[i] = pL[(size_t)(slot0 + i) * 128 + row];
        M = fmaxf(M, mv[i]);
    }
    float L = 0.f;
    for (int i = 0; i < nch; ++i) L += lv[i] * __expf(mv[i] - M);

    float acc[32];
    #pragma unroll
    for (int j = 0; j < 32; ++j) acc[j] = 0.f;
    for (int i = 0; i < nch; ++i) {
        float sc = __expf(mv[i] - M);
        const unsigned short* p = pO + ((size_t)(slot0 + i) * 128 + row) * 64 + col0;
        #pragma unroll
        for (int v4 = 0; v4 < 4; ++v4) {
            uint4 u = *(const uint4*)(p + v4 * 8);
            unsigned short t[8]; *(uint4*)t = u;
            #pragma unroll
            for (int j = 0; j < 8; ++j) acc[v4 * 8 + j] += sc * b2f(t[j]);
        }
    }
    float inv = 1.f / L;
    unsigned short* orow = ctx + ((size_t)(b * 2048 + qb * 128 + row)) * 768 + h * 64 + col0;
    #pragma unroll
    for (int v4 = 0; v4 < 4; ++v4) {
        uint4 u;
        unsigned short t[8];
        #pragma unroll
        for (int j = 0; j < 8; ++j) t[j] = f2b(acc[v4 * 8 + j] * inv);
        u = *(uint4*)t;
        *(uint4*)(orow + v4 * 8) = u;
    }
}

// ---------------- fused residual + LayerNorm --------------------------------
__global__ __launch_bounds__(256) void resid_ln(const float* __restrict__ X,
                                                const float* __restrict__ R,
                                                const float* __restrict__ gain,
                                                const float* __restrict__ beta,
                                                float* __restrict__ outF,
                                                unsigned short* __restrict__ outB) {
    const int row = blockIdx.x;
    const int t   = threadIdx.x;
    const size_t off = (size_t)row * 768;
    float v0 = X[off + t]       + R[off + t];
    float v1 = X[off + t + 256] + R[off + t + 256];
    float v2 = X[off + t + 512] + R[off + t + 512];
    float s  = v0 + v1 + v2;
    float s2 = v0 * v0 + v1 * v1 + v2 * v2;
    #pragma unroll
    for (int o2 = 32; o2 > 0; o2 >>= 1) {
        s  += __shfl_down(s,  o2);
        s2 += __shfl_down(s2, o2);
    }
    __shared__ float rs[4], rq[4];
    if ((t & 63) == 0) { rs[t >> 6] = s; rq[t >> 6] = s2; }
    __syncthreads();
    float S    = rs[0] + rs[1] + rs[2] + rs[3];
    float S2   = rq[0] + rq[1] + rq[2] + rq[3];
    float mean = S * (1.0f / 768.0f);
    float var  = S2 * (1.0f / 768.0f) - mean * mean;
    float inv  = rsqrtf(var + 1e-5f);
    #pragma unroll
    for (int i = 0; i < 3; i++) {
        int c   = t + i * 256;
        float v = (i == 0 ? v0 : (i == 1 ? v1 : v2));
        float y = gain[c] * (v - mean) * inv + beta[c];
        if (outF) outF[off + c] = y;
        if (outB) outB[off + c] = f2b(y);
    }
}

// ---------------------------------------------------------------------------
extern "C" void kernel_launch(void* const* d_in, const int* in_sizes, int n_in,
                              void* d_out, int out_size, void* d_ws, size_t ws_size,
                              hipStream_t stream) {
    const float* x    = (const float*)d_in[0];
    const float* Wqkv = (const float*)d_in[1];
    const float* Wout = (const float*)d_in[2];
    const float* bout = (const float*)d_in[3];
    const float* W1   = (const float*)d_in[4];
    const float* b1   = (const float*)d_in[5];
    const float* W2   = (const float*)d_in[6];
    const float* b2   = (const float*)d_in[7];
    const float* g1   = (const float*)d_in[8];
    const float* be1  = (const float*)d_in[9];
    const float* g2   = (const float*)d_in[10];
    const float* be2  = (const float*)d_in[11];
    float* out = (float*)d_out;

    // workspace layout (bytes), liveness-aliased; peak 83,361,792
    char* ws = (char*)d_ws;
    unsigned short* xb     = (unsigned short*)(ws + 0);         // 6,291,456
    unsigned short* wqkvT  = (unsigned short*)(ws + 6291456);   // 3,538,944
    unsigned short* woutT  = (unsigned short*)(ws + 9830400);   // 1,179,648
    unsigned short* w1T    = (unsigned short*)(ws + 11010048);  // 4,718,592
    unsigned short* w2T    = (unsigned short*)(ws + 15728640);  // 4,718,592
    unsigned short* qkvG   = (unsigned short*)(ws + 20447232);  // Q|K|V 3x6,291,456
    unsigned short* Qg     = qkvG;
    unsigned short* Kg     = qkvG + 3145728;
    unsigned short* Vg     = qkvG + 6291456;
    unsigned short* ctxb   = (unsigned short*)(ws + 39321600);  // 6,291,456
    // attention partials (dead outside attn_part..attn_combine):
    unsigned short* pO     = (unsigned short*)(ws + 45613056);  // 28,311,552
    float*          pM     = (float*)(ws + 73924608);           // 884,736
    float*          pL     = (float*)(ws + 74809344);           // 884,736
    float*          attn_o = (float*)(ws + 20447232);           // alias qkvG
    float*          h      = (float*)(ws + 45613056);           // 12,582,912 (alias pO)
    unsigned short* hb     = (unsigned short*)(ws + 39321600);  // alias ctxb
    unsigned short* ffb    = (unsigned short*)(ws + 58195968);  // 25,165,824
    float*          ff2    = (float*)(ws + 20447232);           // alias qkvG

    // 1) fused prepass: cvt x + all weight transposes
    prep_all<<<9984, 256, 0, stream>>>(x, xb, Wqkv, wqkvT, Wout, woutT, W1, w1T, W2, w2T);

    // 2) QKV projection -> Q/K/V [bh][s][64] bf16 (scatter epilogue)
    gemm_bf16<<<dim3(18, 32), 256, 0, stream>>>(xb, wqkvT, nullptr, nullptr, qkvG,
                                                4096, 2304, 768, 0, 1);
    // 3) kv-split flash attention partials + combine -> ctx bf16
    attn_part<<<dim3(72, 24), 256, 0, stream>>>(Qg, Kg, Vg, pO, pM, pL);
    attn_combine<<<dim3(16, 24), 256, 0, stream>>>(pO, pM, pL, ctxb);
    // 4) out projection (+bout) -> fp32
    gemm_bf16<<<dim3(6, 32), 256, 0, stream>>>(ctxb, woutT, bout, attn_o, nullptr,
                                               4096, 768, 768, 0, 0);
    // 5) h = LN(x + attn_o) -> fp32 + bf16
    resid_ln<<<4096, 256, 0, stream>>>(x, attn_o, g1, be1, h, hb);
    // 6) ff = relu(h @ W1 + b1) -> bf16
    gemm_bf16<<<dim3(24, 32), 256, 0, stream>>>(hb, w1T, b1, nullptr, ffb,
                                                4096, 3072, 768, 1, 0);
    // 7) ff2 = ff @ W2 + b2 -> fp32
    gemm_bf16<<<dim3(6, 32), 256, 0, stream>>>(ffb, w2T, b2, ff2, nullptr,
                                               4096, 768, 3072, 0, 0);
    // 8) out = LN(h + ff2) -> fp32
    resid_ln<<<4096, 256, 0, stream>>>(h, ff2, g2, be2, out, nullptr);
}

// Round 5
// 362.591 us; speedup vs baseline: 7.4171x; 1.0638x over previous
//
#include <hip/hip_runtime.h>

// ---------------------------------------------------------------------------
// TransformerBlock: B=2,S=2048,D=768,H=12,DH=64,DFF=3072, causal attn, 2x LN
// Round 4: split-K for the two under-subscribed GEMMs (Wout K=768 -> 3 slabs,
// W2 K=3072 -> 2 slabs; 192 blocks -> 576/384), fp32 partials reduced inside
// resid_ln2 (bias folded there). Attention unchanged from round 3.
// ---------------------------------------------------------------------------

typedef __attribute__((ext_vector_type(8))) short  short8;   // 8 x bf16 (4 VGPR)
typedef __attribute__((ext_vector_type(4))) float  floatx4;  // 4 x f32 acc

__device__ __forceinline__ float b2f(unsigned short u) {
    return __uint_as_float(((unsigned)u) << 16);
}
__device__ __forceinline__ unsigned short f2b(float f) {  // RNE
    unsigned x = __float_as_uint(f);
    return (unsigned short)((x + 0x7fffu + ((x >> 16) & 1u)) >> 16);
}
__device__ __forceinline__ void async_cp16(const void* g, void* l) {
    __builtin_amdgcn_global_load_lds((const __attribute__((address_space(1))) void*)g,
                                     (__attribute__((address_space(3))) void*)l,
                                     16, 0, 0);
}
__device__ __forceinline__ int chunk_ofs(int qb) {
    int t = qb >> 1;
    return (qb & 1) ? (t + 1) * (t + 1) : t * (t + 1);
}

// ---------------- fused prepass: x->bf16 + 4 weight transposes --------------
__global__ __launch_bounds__(256) void prep_all(
    const float* __restrict__ x,    unsigned short* __restrict__ xb,
    const float* __restrict__ Wqkv, unsigned short* __restrict__ wqkvT,
    const float* __restrict__ Wout, unsigned short* __restrict__ woutT,
    const float* __restrict__ W1,   unsigned short* __restrict__ w1T,
    const float* __restrict__ W2,   unsigned short* __restrict__ w2T)
{
    __shared__ float tile[32][33];
    int idx = blockIdx.x;
    int tx = threadIdx.x & 31, ty = threadIdx.x >> 5;
    if (idx >= 6912) {  // cvt x
        int i = (idx - 6912) * 256 + threadIdx.x;
        float4 v = ((const float4*)x)[i];
        ushort4 u;
        u.x = f2b(v.x); u.y = f2b(v.y); u.z = f2b(v.z); u.w = f2b(v.w);
        ((ushort4*)xb)[i] = u;
        return;
    }
    const float* W; unsigned short* Wt; int K, N, bx, by;
    if (idx < 1728)      { W = Wqkv; Wt = wqkvT; K = 768;  N = 2304; bx = idx % 72;        by = idx / 72; }
    else if (idx < 2304) { W = Wout; Wt = woutT; K = 768;  N = 768;  bx = (idx-1728) % 24; by = (idx-1728) / 24; }
    else if (idx < 4608) { W = W1;   Wt = w1T;   K = 768;  N = 3072; bx = (idx-2304) % 96; by = (idx-2304) / 96; }
    else                 { W = W2;   Wt = w2T;   K = 3072; N = 768;  bx = (idx-4608) % 24; by = (idx-4608) / 24; }
    int n0 = bx * 32, k0 = by * 32;
    for (int i = ty; i < 32; i += 8)
        tile[i][tx] = W[(size_t)(k0 + i) * N + n0 + tx];
    __syncthreads();
    for (int i = ty; i < 32; i += 8)
        Wt[(size_t)(n0 + i) * K + k0 + tx] = f2b(tile[tx][i]);
}

// ---------------- bf16 MFMA GEMM ---------------------------------------------
// mode 0: row-major outF/outB (+bias, relu)
// mode 1: qkv scatter -> outB = Q|K|V each [24][2048][64]
// mode 2: split-K fp32 partial -> outF + blockIdx.z*M*N
__global__ __launch_bounds__(256) void gemm_bf16(
    const unsigned short* __restrict__ A,
    const unsigned short* __restrict__ Bt,
    const float* __restrict__ bias,
    float* __restrict__ outF,
    unsigned short* __restrict__ outB,
    int M, int N, int K, int relu, int mode, int kslab)
{
    __shared__ unsigned short As[128][32];
    __shared__ unsigned short Bs[128][32];
    const int tid  = threadIdx.x;
    const int m0   = blockIdx.y * 128;
    const int n0   = blockIdx.x * 128;
    const int kz   = blockIdx.z;
    const int kbeg = kz * kslab;
    const int kend = kbeg + kslab;
    const int lane = tid & 63;
    const int wave = tid >> 6;
    const int wm   = (wave >> 1) * 64;
    const int wn   = (wave & 1) * 64;
    const int fr   = lane & 15;
    const int fq   = lane >> 4;

    floatx4 acc[4][4];
    for (int i = 0; i < 4; i++)
        for (int j = 0; j < 4; j++)
            for (int e = 0; e < 4; e++) acc[i][j][e] = 0.f;

    for (int kk = kbeg; kk < kend; kk += 32) {
        __syncthreads();
        #pragma unroll
        for (int r = 0; r < 2; ++r) {
            int c    = r * 256 + tid;
            int row  = c >> 2;
            int colb = (c & 3) * 8;
            async_cp16(A  + (size_t)(m0 + row) * K + kk + colb, &As[row][colb]);
            async_cp16(Bt + (size_t)(n0 + row) * K + kk + colb, &Bs[row][colb]);
        }
        __syncthreads();

        short8 a[4], b[4];
        #pragma unroll
        for (int t = 0; t < 4; t++) a[t] = *(const short8*)&As[wm + t * 16 + fr][fq * 8];
        #pragma unroll
        for (int t = 0; t < 4; t++) b[t] = *(const short8*)&Bs[wn + t * 16 + fr][fq * 8];
        #pragma unroll
        for (int i = 0; i < 4; i++)
            #pragma unroll
            for (int j = 0; j < 4; j++)
                acc[i][j] = __builtin_amdgcn_mfma_f32_16x16x32_bf16(a[i], b[j], acc[i][j], 0, 0, 0);
    }

    if (mode == 2) {
        float* dst = outF + (size_t)kz * M * N;
        #pragma unroll
        for (int j = 0; j < 4; j++) {
            int col = n0 + wn + j * 16 + fr;
            #pragma unroll
            for (int i = 0; i < 4; i++) {
                int rbase = m0 + wm + i * 16 + fq * 4;
                #pragma unroll
                for (int e = 0; e < 4; e++)
                    dst[(size_t)(rbase + e) * N + col] = acc[i][j][e];
            }
        }
        return;
    }
    if (mode == 1) {
        #pragma unroll
        for (int j = 0; j < 4; j++) {
            int col   = n0 + wn + j * 16 + fr;
            int which = (col >= 1536) ? 2 : (col >= 768 ? 1 : 0);
            int rem   = col - which * 768;
            int hh    = rem >> 6, d = rem & 63;
            #pragma unroll
            for (int i = 0; i < 4; i++) {
                int rbase = m0 + wm + i * 16 + fq * 4;
                #pragma unroll
                for (int e = 0; e < 4; e++) {
                    int row = rbase + e;
                    int b_  = row >> 11, srow = row & 2047;
                    size_t idx = (size_t)which * 3145728 +
                                 ((size_t)(b_ * 12 + hh) * 2048 + srow) * 64 + d;
                    outB[idx] = f2b(acc[i][j][e]);
                }
            }
        }
        return;
    }
    #pragma unroll
    for (int j = 0; j < 4; j++) {
        int col  = n0 + wn + j * 16 + fr;
        float bv = bias ? bias[col] : 0.f;
        #pragma unroll
        for (int i = 0; i < 4; i++) {
            int rbase = m0 + wm + i * 16 + fq * 4;
            #pragma unroll
            for (int e = 0; e < 4; e++) {
                float v = acc[i][j][e] + bv;
                if (relu) v = fmaxf(v, 0.f);
                size_t idx = (size_t)(rbase + e) * N + col;
                if (outF) outF[idx] = v;
                if (outB) outB[idx] = f2b(v);
            }
        }
    }
}

// ---------------- attention partial (kv-split flash) ------------------------
__global__ __launch_bounds__(256) void attn_part(const unsigned short* __restrict__ Qg,
                                                 const unsigned short* __restrict__ Kg,
                                                 const unsigned short* __restrict__ Vg,
                                                 unsigned short* __restrict__ pO,
                                                 float* __restrict__ pM,
                                                 float* __restrict__ pL) {
    __shared__ unsigned short Ks[2][64][72];
    __shared__ unsigned short Vt[2][64][72];
    __shared__ unsigned short Ps[128][72];
    const int tid  = threadIdx.x;
    const int lane = tid & 63;
    const int wave = tid >> 6;
    const int fr   = lane & 15;
    const int fq   = lane >> 4;
    const int wm   = wave * 32;
    const int r    = blockIdx.x;
    const int bh   = blockIdx.y;
    int qb = 0;
    for (int q_ = 15; q_ >= 0; --q_) if (r >= chunk_ofs(q_)) { qb = q_; break; }
    const int c     = r - chunk_ofs(qb);
    const int q0    = qb * 128;
    const int tile0 = 4 * c;
    const int ntk   = min(4, 2 * (qb + 1) - 4 * c);
    const int slot  = bh * 72 + r;
    const unsigned short* Qb = Qg + (size_t)bh * 2048 * 64;
    const unsigned short* Kb = Kg + (size_t)bh * 2048 * 64;
    const unsigned short* Vb = Vg + (size_t)bh * 2048 * 64;

    short8 qf[2][2];
    #pragma unroll
    for (int rf = 0; rf < 2; ++rf) {
        const unsigned short* qr = Qb + (size_t)(q0 + wm + rf * 16 + fr) * 64;
        qf[rf][0] = *(const short8*)(qr + fq * 8);
        qf[rf][1] = *(const short8*)(qr + 32 + fq * 8);
    }

    floatx4 o[2][4];
    float m_s[2][4], l_s[2][4];
    #pragma unroll
    for (int rf = 0; rf < 2; ++rf)
        #pragma unroll
        for (int nt = 0; nt < 4; ++nt)
            #pragma unroll
            for (int e = 0; e < 4; ++e) o[rf][nt][e] = 0.f;
    #pragma unroll
    for (int rf = 0; rf < 2; ++rf)
        #pragma unroll
        for (int e = 0; e < 4; ++e) { m_s[rf][e] = -1e30f; l_s[rf][e] = 0.f; }

    const int c0 = tid, c1 = tid + 256;
    uint4 kr0, kr1, vr0, vr1;

#define LOADT(TG)                                                              \
    {                                                                          \
        int base = (TG) * 64;                                                  \
        kr0 = *(const uint4*)(Kb + (size_t)(base + (c0 >> 3)) * 64 + (c0 & 7) * 8); \
        kr1 = *(const uint4*)(Kb + (size_t)(base + (c1 >> 3)) * 64 + (c1 & 7) * 8); \
        vr0 = *(const uint4*)(Vb + (size_t)(base + (c0 & 63)) * 64 + (c0 >> 6) * 8); \
        vr1 = *(const uint4*)(Vb + (size_t)(base + (c1 & 63)) * 64 + (c1 >> 6) * 8); \
    }
#define WRITET(BUF)                                                            \
    {                                                                          \
        *(uint4*)&Ks[BUF][c0 >> 3][(c0 & 7) * 8] = kr0;                        \
        *(uint4*)&Ks[BUF][c1 >> 3][(c1 & 7) * 8] = kr1;                        \
        unsigned short t0[8]; *(uint4*)t0 = vr0;                               \
        _Pragma("unroll") for (int i_ = 0; i_ < 8; ++i_)                       \
            Vt[BUF][(c0 >> 6) * 8 + i_][c0 & 63] = t0[i_];                     \
        unsigned short t1[8]; *(uint4*)t1 = vr1;                               \
        _Pragma("unroll") for (int i_ = 0; i_ < 8; ++i_)                       \
            Vt[BUF][(c1 >> 6) * 8 + i_][c1 & 63] = t1[i_];                     \
    }

    LOADT(tile0);
    WRITET(0);
    __syncthreads();

    for (int kt = 0; kt < ntk; ++kt) {
        const int  tg   = tile0 + kt;
        const int  cur  = kt & 1;
        const bool more = (kt + 1 < ntk);
        if (more) LOADT(tg + 1);

        short8 kf[2][4];
        #pragma unroll
        for (int kc = 0; kc < 2; ++kc)
            #pragma unroll
            for (int nt = 0; nt < 4; ++nt)
                kf[kc][nt] = *(const short8*)&Ks[cur][nt * 16 + fr][kc * 32 + fq * 8];

        floatx4 s[2][4];
        #pragma unroll
        for (int rf = 0; rf < 2; ++rf)
            #pragma unroll
            for (int nt = 0; nt < 4; ++nt)
                #pragma unroll
                for (int e = 0; e < 4; ++e) s[rf][nt][e] = 0.f;
        #pragma unroll
        for (int rf = 0; rf < 2; ++rf)
            #pragma unroll
            for (int kc = 0; kc < 2; ++kc)
                #pragma unroll
                for (int nt = 0; nt < 4; ++nt)
                    s[rf][nt] = __builtin_amdgcn_mfma_f32_16x16x32_bf16(qf[rf][kc], kf[kc][nt], s[rf][nt], 0, 0, 0);

        const bool need_mask = (tg * 64 + 63) > (q0 + wm);
        #pragma unroll
        for (int rf = 0; rf < 2; ++rf)
            #pragma unroll
            for (int e = 0; e < 4; ++e) {
                const int qrow = q0 + wm + rf * 16 + fq * 4 + e;
                float mx = -1e30f;
                #pragma unroll
                for (int nt = 0; nt < 4; ++nt) {
                    float v = s[rf][nt][e] * 0.125f;
                    if (need_mask && (tg * 64 + nt * 16 + fr) > qrow) v = -1e30f;
                    s[rf][nt][e] = v;
                    mx = fmaxf(mx, v);
                }
                mx = fmaxf(mx, __shfl_xor(mx, 1));
                mx = fmaxf(mx, __shfl_xor(mx, 2));
                mx = fmaxf(mx, __shfl_xor(mx, 4));
                mx = fmaxf(mx, __shfl_xor(mx, 8));
                float mn = fmaxf(m_s[rf][e], mx);
                float al = __expf(m_s[rf][e] - mn);
                float rs = 0.f;
                #pragma unroll
                for (int nt = 0; nt < 4; ++nt) {
                    float pv = __expf(s[rf][nt][e] - mn);
                    s[rf][nt][e] = pv;
                    rs += pv;
                }
                rs += __shfl_xor(rs, 1);
                rs += __shfl_xor(rs, 2);
                rs += __shfl_xor(rs, 4);
                rs += __shfl_xor(rs, 8);
                l_s[rf][e] = l_s[rf][e] * al + rs;
                m_s[rf][e] = mn;
                #pragma unroll
                for (int nt = 0; nt < 4; ++nt) {
                    o[rf][nt][e] *= al;
                    Ps[wm + rf * 16 + fq * 4 + e][nt * 16 + fr] = f2b(s[rf][nt][e]);
                }
            }
        __asm__ volatile("s_waitcnt lgkmcnt(0)" ::: "memory");

        short8 pf[2][2], vf[2][4];
        #pragma unroll
        for (int rf = 0; rf < 2; ++rf)
            #pragma unroll
            for (int kc = 0; kc < 2; ++kc)
                pf[rf][kc] = *(const short8*)&Ps[wm + rf * 16 + fr][kc * 32 + fq * 8];
        #pragma unroll
        for (int kc = 0; kc < 2; ++kc)
            #pragma unroll
            for (int nt = 0; nt < 4; ++nt)
                vf[kc][nt] = *(const short8*)&Vt[cur][nt * 16 + fr][kc * 32 + fq * 8];
        #pragma unroll
        for (int rf = 0; rf < 2; ++rf)
            #pragma unroll
            for (int kc = 0; kc < 2; ++kc)
                #pragma unroll
                for (int nt = 0; nt < 4; ++nt)
                    o[rf][nt] = __builtin_amdgcn_mfma_f32_16x16x32_bf16(pf[rf][kc], vf[kc][nt], o[rf][nt], 0, 0, 0);

        if (more) {
            WRITET(cur ^ 1);
            __syncthreads();
        }
    }
#undef LOADT
#undef WRITET

    #pragma unroll
    for (int rf = 0; rf < 2; ++rf)
        #pragma unroll
        for (int e = 0; e < 4; ++e) {
            int row = wm + rf * 16 + fq * 4 + e;
            unsigned short* orow = pO + ((size_t)slot * 128 + row) * 64;
            #pragma unroll
            for (int nt = 0; nt < 4; ++nt)
                orow[nt * 16 + fr] = f2b(o[rf][nt][e]);
            if (fr == 0) {
                pM[(size_t)slot * 128 + row] = m_s[rf][e];
                pL[(size_t)slot * 128 + row] = l_s[rf][e];
            }
        }
}

// ---------------- attention combine -----------------------------------------
__global__ __launch_bounds__(256) void attn_combine(const unsigned short* __restrict__ pO,
                                                    const float* __restrict__ pM,
                                                    const float* __restrict__ pL,
                                                    unsigned short* __restrict__ ctx) {
    const int qb  = blockIdx.x;
    const int bh  = blockIdx.y;
    const int b   = bh / 12, h = bh % 12;
    const int nch = (qb + 2) >> 1;
    const int slot0 = bh * 72 + chunk_ofs(qb);
    const int tid = threadIdx.x;
    const int row = tid >> 1;
    const int col0 = (tid & 1) * 32;

    float mv[8], lv[8];
    float M = -1e30f;
    for (int i = 0; i < nch; ++i) {
        mv[i] = pM[(size_t)(slot0 + i) * 128 + row];
        lv[i] = pL[(size_t)(slot0 + i) * 128 + row];
        M = fmaxf(M, mv[i]);
    }
    float L = 0.f;
    for (int i = 0; i < nch; ++i) L += lv[i] * __expf(mv[i] - M);

    float acc[32];
    #pragma unroll
    for (int j = 0; j < 32; ++j) acc[j] = 0.f;
    for (int i = 0; i < nch; ++i) {
        float sc = __expf(mv[i] - M);
        const unsigned short* p = pO + ((size_t)(slot0 + i) * 128 + row) * 64 + col0;
        #pragma unroll
        for (int v4 = 0; v4 < 4; ++v4) {
            uint4 u = *(const uint4*)(p + v4 * 8);
            unsigned short t[8]; *(uint4*)t = u;
            #pragma unroll
            for (int j = 0; j < 8; ++j) acc[v4 * 8 + j] += sc * b2f(t[j]);
        }
    }
    float inv = 1.f / L;
    unsigned short* orow = ctx + ((size_t)(b * 2048 + qb * 128 + row)) * 768 + h * 64 + col0;
    #pragma unroll
    for (int v4 = 0; v4 < 4; ++v4) {
        unsigned short t[8];
        #pragma unroll
        for (int j = 0; j < 8; ++j) t[j] = f2b(acc[v4 * 8 + j] * inv);
        *(uint4*)(orow + v4 * 8) = *(uint4*)t;
    }
}

// ---------------- fused split-K reduce + bias + residual + LayerNorm --------
// P = base of nsplit contiguous fp32 [4096][768] partials.
__global__ __launch_bounds__(256) void resid_ln2(const float* __restrict__ X,
                                                 const float* __restrict__ P,
                                                 int nsplit,
                                                 const float* __restrict__ bv,
                                                 const float* __restrict__ gain,
                                                 const float* __restrict__ beta,
                                                 float* __restrict__ outF,
                                                 unsigned short* __restrict__ outB) {
    const int row = blockIdx.x;
    const int t   = threadIdx.x;
    const size_t off = (size_t)row * 768;
    float v[3];
    #pragma unroll
    for (int i = 0; i < 3; i++) {
        size_t c = off + t + i * 256;
        float r = X[c] + bv[t + i * 256];
        for (int p = 0; p < nsplit; ++p) r += P[(size_t)p * 3145728 + c];
        v[i] = r;
    }
    float s  = v[0] + v[1] + v[2];
    float s2 = v[0] * v[0] + v[1] * v[1] + v[2] * v[2];
    #pragma unroll
    for (int o2 = 32; o2 > 0; o2 >>= 1) {
        s  += __shfl_down(s,  o2);
        s2 += __shfl_down(s2, o2);
    }
    __shared__ float rs[4], rq[4];
    if ((t & 63) == 0) { rs[t >> 6] = s; rq[t >> 6] = s2; }
    __syncthreads();
    float S    = rs[0] + rs[1] + rs[2] + rs[3];
    float S2   = rq[0] + rq[1] + rq[2] + rq[3];
    float mean = S * (1.0f / 768.0f);
    float var  = S2 * (1.0f / 768.0f) - mean * mean;
    float inv  = rsqrtf(var + 1e-5f);
    #pragma unroll
    for (int i = 0; i < 3; i++) {
        int c   = t + i * 256;
        float y = gain[c] * (v[i] - mean) * inv + beta[c];
        if (outF) outF[off + c] = y;
        if (outB) outB[off + c] = f2b(y);
    }
}

// ---------------------------------------------------------------------------
extern "C" void kernel_launch(void* const* d_in, const int* in_sizes, int n_in,
                              void* d_out, int out_size, void* d_ws, size_t ws_size,
                              hipStream_t stream) {
    const float* x    = (const float*)d_in[0];
    const float* Wqkv = (const float*)d_in[1];
    const float* Wout = (const float*)d_in[2];
    const float* bout = (const float*)d_in[3];
    const float* W1   = (const float*)d_in[4];
    const float* b1   = (const float*)d_in[5];
    const float* W2   = (const float*)d_in[6];
    const float* b2   = (const float*)d_in[7];
    const float* g1   = (const float*)d_in[8];
    const float* be1  = (const float*)d_in[9];
    const float* g2   = (const float*)d_in[10];
    const float* be2  = (const float*)d_in[11];
    float* out = (float*)d_out;

    // workspace layout (bytes), liveness-aliased; peak 83,361,792
    // timeline: prep -> QKV -> attn_part -> combine -> Wout(x3) -> LN1 ->
    //           W1 -> W2(x2) -> LN2
    char* ws = (char*)d_ws;
    unsigned short* wqkvT  = (unsigned short*)(ws + 0);         // 3.5M  ->QKV
    unsigned short* woutT  = (unsigned short*)(ws + 3538944);   // 1.2M  ->Wout
    unsigned short* w1T    = (unsigned short*)(ws + 4718592);   // 4.7M  ->W1
    unsigned short* w2T    = (unsigned short*)(ws + 9437184);   // 4.7M  ->W2
    unsigned short* xb     = (unsigned short*)(ws + 14155776);  // 6.3M  ->QKV
    unsigned short* qkvG   = (unsigned short*)(ws + 20447232);  // 18.9M ->attn_part
    unsigned short* Qg     = qkvG;
    unsigned short* Kg     = qkvG + 3145728;
    unsigned short* Vg     = qkvG + 6291456;
    unsigned short* pO     = (unsigned short*)(ws + 39321600);  // 28.3M ->combine
    float*          pM     = (float*)(ws + 67633152);           // 0.9M  ->combine
    float*          pL     = (float*)(ws + 68517888);           // 0.9M  ->combine
    unsigned short* ctxb   = (unsigned short*)(ws + 14155776);  // 6.3M  combine->Wout (xb dead)
    float*          WoutP  = (float*)(ws + 39321600);           // 3x12.6M=37.7M Wout->LN1 (pO/pM/pL dead); ends 77,070,336
    float*          h      = (float*)(ws + 20447232);           // 12.6M LN1->LN2 (qkvG dead); ends 33,030,144
    unsigned short* hb     = (unsigned short*)(ws + 77070336);  // 6.3M  LN1->W1; ends 83,361,792
    unsigned short* ffb    = (unsigned short*)(ws + 39321600);  // 25.2M W1->W2 (WoutP dead); ends 64,487,424
    float*          W2P    = (float*)(ws + 64487424);           // 2x12.6M=25.2M W2->LN2; ends 77,070,336

    // 1) fused prepass
    prep_all<<<9984, 256, 0, stream>>>(x, xb, Wqkv, wqkvT, Wout, woutT, W1, w1T, W2, w2T);
    // 2) QKV projection -> Q/K/V [bh][s][64] bf16
    gemm_bf16<<<dim3(18, 32), 256, 0, stream>>>(xb, wqkvT, nullptr, nullptr, qkvG,
                                                4096, 2304, 768, 0, 1, 768);
    // 3) kv-split flash attention + combine -> ctx bf16
    attn_part<<<dim3(72, 24), 256, 0, stream>>>(Qg, Kg, Vg, pO, pM, pL);
    attn_combine<<<dim3(16, 24), 256, 0, stream>>>(pO, pM, pL, ctxb);
    // 4) out projection, split-K=3 -> fp32 partials
    gemm_bf16<<<dim3(6, 32, 3), 256, 0, stream>>>(ctxb, woutT, nullptr, WoutP, nullptr,
                                                  4096, 768, 768, 0, 2, 256);
    // 5) h = LN(x + sum(WoutP) + bout) -> fp32 + bf16
    resid_ln2<<<4096, 256, 0, stream>>>(x, WoutP, 3, bout, g1, be1, h, hb);
    // 6) ff = relu(h @ W1 + b1) -> bf16
    gemm_bf16<<<dim3(24, 32), 256, 0, stream>>>(hb, w1T, b1, nullptr, ffb,
                                                4096, 3072, 768, 1, 0, 768);
    // 7) ff2 partials = ff @ W2 (split-K=2)
    gemm_bf16<<<dim3(6, 32, 2), 256, 0, stream>>>(ffb, w2T, nullptr, W2P, nullptr,
                                                  4096, 768, 3072, 0, 2, 1536);
    // 8) out = LN(h + sum(W2P) + b2) -> fp32
    resid_ln2<<<4096, 256, 0, stream>>>(h, W2P, 2, b2, g2, be2, out, nullptr);
}

// Round 6
// 342.235 us; speedup vs baseline: 7.8583x; 1.0595x over previous
//
#include <hip/hip_runtime.h>

// ---------------------------------------------------------------------------
// TransformerBlock: B=2,S=2048,D=768,H=12,DH=64,DFF=3072, causal attn, 2x LN
// Round 5: fixed-base softmax in attn_part (p = 2^(s'-C), C=24; exact after
// combine) -- removes max-tracking shfls, alpha-rescale, pM. Q pre-scaled by
// 0.125*log2e in QKV scatter. Split-K GEMMs + kv-split flash unchanged.
// ---------------------------------------------------------------------------

typedef __attribute__((ext_vector_type(8))) short  short8;   // 8 x bf16 (4 VGPR)
typedef __attribute__((ext_vector_type(4))) float  floatx4;  // 4 x f32 acc

#define QSC 0.18033688f   // 0.125 * log2(e): folded into Q at scatter
#define C2  24.0f         // fixed base-2 softmax offset

__device__ __forceinline__ float b2f(unsigned short u) {
    return __uint_as_float(((unsigned)u) << 16);
}
__device__ __forceinline__ unsigned short f2b(float f) {  // RNE
    unsigned x = __float_as_uint(f);
    return (unsigned short)((x + 0x7fffu + ((x >> 16) & 1u)) >> 16);
}
__device__ __forceinline__ void async_cp16(const void* g, void* l) {
    __builtin_amdgcn_global_load_lds((const __attribute__((address_space(1))) void*)g,
                                     (__attribute__((address_space(3))) void*)l,
                                     16, 0, 0);
}
__device__ __forceinline__ int chunk_ofs(int qb) {
    int t = qb >> 1;
    return (qb & 1) ? (t + 1) * (t + 1) : t * (t + 1);
}

// ---------------- fused prepass: x->bf16 + 4 weight transposes --------------
__global__ __launch_bounds__(256) void prep_all(
    const float* __restrict__ x,    unsigned short* __restrict__ xb,
    const float* __restrict__ Wqkv, unsigned short* __restrict__ wqkvT,
    const float* __restrict__ Wout, unsigned short* __restrict__ woutT,
    const float* __restrict__ W1,   unsigned short* __restrict__ w1T,
    const float* __restrict__ W2,   unsigned short* __restrict__ w2T)
{
    __shared__ float tile[32][33];
    int idx = blockIdx.x;
    int tx = threadIdx.x & 31, ty = threadIdx.x >> 5;
    if (idx >= 6912) {  // cvt x
        int i = (idx - 6912) * 256 + threadIdx.x;
        float4 v = ((const float4*)x)[i];
        ushort4 u;
        u.x = f2b(v.x); u.y = f2b(v.y); u.z = f2b(v.z); u.w = f2b(v.w);
        ((ushort4*)xb)[i] = u;
        return;
    }
    const float* W; unsigned short* Wt; int K, N, bx, by;
    if (idx < 1728)      { W = Wqkv; Wt = wqkvT; K = 768;  N = 2304; bx = idx % 72;        by = idx / 72; }
    else if (idx < 2304) { W = Wout; Wt = woutT; K = 768;  N = 768;  bx = (idx-1728) % 24; by = (idx-1728) / 24; }
    else if (idx < 4608) { W = W1;   Wt = w1T;   K = 768;  N = 3072; bx = (idx-2304) % 96; by = (idx-2304) / 96; }
    else                 { W = W2;   Wt = w2T;   K = 3072; N = 768;  bx = (idx-4608) % 24; by = (idx-4608) / 24; }
    int n0 = bx * 32, k0 = by * 32;
    for (int i = ty; i < 32; i += 8)
        tile[i][tx] = W[(size_t)(k0 + i) * N + n0 + tx];
    __syncthreads();
    for (int i = ty; i < 32; i += 8)
        Wt[(size_t)(n0 + i) * K + k0 + tx] = f2b(tile[tx][i]);
}

// ---------------- bf16 MFMA GEMM ---------------------------------------------
// mode 0: row-major outF/outB (+bias, relu)
// mode 1: qkv scatter -> outB = Q|K|V each [24][2048][64]; Q scaled by QSC
// mode 2: split-K fp32 partial -> outF + blockIdx.z*M*N
__global__ __launch_bounds__(256) void gemm_bf16(
    const unsigned short* __restrict__ A,
    const unsigned short* __restrict__ Bt,
    const float* __restrict__ bias,
    float* __restrict__ outF,
    unsigned short* __restrict__ outB,
    int M, int N, int K, int relu, int mode, int kslab)
{
    __shared__ unsigned short As[128][32];
    __shared__ unsigned short Bs[128][32];
    const int tid  = threadIdx.x;
    const int m0   = blockIdx.y * 128;
    const int n0   = blockIdx.x * 128;
    const int kz   = blockIdx.z;
    const int kbeg = kz * kslab;
    const int kend = kbeg + kslab;
    const int lane = tid & 63;
    const int wave = tid >> 6;
    const int wm   = (wave >> 1) * 64;
    const int wn   = (wave & 1) * 64;
    const int fr   = lane & 15;
    const int fq   = lane >> 4;

    floatx4 acc[4][4];
    for (int i = 0; i < 4; i++)
        for (int j = 0; j < 4; j++)
            for (int e = 0; e < 4; e++) acc[i][j][e] = 0.f;

    for (int kk = kbeg; kk < kend; kk += 32) {
        __syncthreads();
        #pragma unroll
        for (int r = 0; r < 2; ++r) {
            int c    = r * 256 + tid;
            int row  = c >> 2;
            int colb = (c & 3) * 8;
            async_cp16(A  + (size_t)(m0 + row) * K + kk + colb, &As[row][colb]);
            async_cp16(Bt + (size_t)(n0 + row) * K + kk + colb, &Bs[row][colb]);
        }
        __syncthreads();

        short8 a[4], b[4];
        #pragma unroll
        for (int t = 0; t < 4; t++) a[t] = *(const short8*)&As[wm + t * 16 + fr][fq * 8];
        #pragma unroll
        for (int t = 0; t < 4; t++) b[t] = *(const short8*)&Bs[wn + t * 16 + fr][fq * 8];
        #pragma unroll
        for (int i = 0; i < 4; i++)
            #pragma unroll
            for (int j = 0; j < 4; j++)
                acc[i][j] = __builtin_amdgcn_mfma_f32_16x16x32_bf16(a[i], b[j], acc[i][j], 0, 0, 0);
    }

    if (mode == 2) {
        float* dst = outF + (size_t)kz * M * N;
        #pragma unroll
        for (int j = 0; j < 4; j++) {
            int col = n0 + wn + j * 16 + fr;
            #pragma unroll
            for (int i = 0; i < 4; i++) {
                int rbase = m0 + wm + i * 16 + fq * 4;
                #pragma unroll
                for (int e = 0; e < 4; e++)
                    dst[(size_t)(rbase + e) * N + col] = acc[i][j][e];
            }
        }
        return;
    }
    if (mode == 1) {
        #pragma unroll
        for (int j = 0; j < 4; j++) {
            int col   = n0 + wn + j * 16 + fr;
            int which = (col >= 1536) ? 2 : (col >= 768 ? 1 : 0);
            float sc  = (which == 0) ? QSC : 1.0f;   // fold 0.125*log2e into Q
            int rem   = col - which * 768;
            int hh    = rem >> 6, d = rem & 63;
            #pragma unroll
            for (int i = 0; i < 4; i++) {
                int rbase = m0 + wm + i * 16 + fq * 4;
                #pragma unroll
                for (int e = 0; e < 4; e++) {
                    int row = rbase + e;
                    int b_  = row >> 11, srow = row & 2047;
                    size_t idx = (size_t)which * 3145728 +
                                 ((size_t)(b_ * 12 + hh) * 2048 + srow) * 64 + d;
                    outB[idx] = f2b(acc[i][j][e] * sc);
                }
            }
        }
        return;
    }
    #pragma unroll
    for (int j = 0; j < 4; j++) {
        int col  = n0 + wn + j * 16 + fr;
        float bv = bias ? bias[col] : 0.f;
        #pragma unroll
        for (int i = 0; i < 4; i++) {
            int rbase = m0 + wm + i * 16 + fq * 4;
            #pragma unroll
            for (int e = 0; e < 4; e++) {
                float v = acc[i][j][e] + bv;
                if (relu) v = fmaxf(v, 0.f);
                size_t idx = (size_t)(rbase + e) * N + col;
                if (outF) outF[idx] = v;
                if (outB) outB[idx] = f2b(v);
            }
        }
    }
}

// ---------------- attention partial (kv-split, fixed-base softmax) ----------
// p = 2^(s' - C2) with s' = (q.k)*0.125*log2e (scale folded into Q).
// Exact softmax after combine: o/l ratio is scale-invariant. Masked -> p=0.
__global__ __launch_bounds__(256) void attn_part(const unsigned short* __restrict__ Qg,
                                                 const unsigned short* __restrict__ Kg,
                                                 const unsigned short* __restrict__ Vg,
                                                 unsigned short* __restrict__ pO,
                                                 float* __restrict__ pL) {
    __shared__ unsigned short Ks[2][64][72];
    __shared__ unsigned short Vt[2][64][72];
    __shared__ unsigned short Ps[128][72];
    const int tid  = threadIdx.x;
    const int lane = tid & 63;
    const int wave = tid >> 6;
    const int fr   = lane & 15;
    const int fq   = lane >> 4;
    const int wm   = wave * 32;
    const int r    = blockIdx.x;
    const int bh   = blockIdx.y;
    int qb = 0;
    for (int q_ = 15; q_ >= 0; --q_) if (r >= chunk_ofs(q_)) { qb = q_; break; }
    const int c     = r - chunk_ofs(qb);
    const int q0    = qb * 128;
    const int tile0 = 4 * c;
    const int ntk   = min(4, 2 * (qb + 1) - 4 * c);
    const int slot  = bh * 72 + r;
    const unsigned short* Qb = Qg + (size_t)bh * 2048 * 64;
    const unsigned short* Kb = Kg + (size_t)bh * 2048 * 64;
    const unsigned short* Vb = Vg + (size_t)bh * 2048 * 64;

    short8 qf[2][2];
    #pragma unroll
    for (int rf = 0; rf < 2; ++rf) {
        const unsigned short* qr = Qb + (size_t)(q0 + wm + rf * 16 + fr) * 64;
        qf[rf][0] = *(const short8*)(qr + fq * 8);
        qf[rf][1] = *(const short8*)(qr + 32 + fq * 8);
    }

    floatx4 o[2][4];
    float l_s[2][4];
    #pragma unroll
    for (int rf = 0; rf < 2; ++rf)
        #pragma unroll
        for (int nt = 0; nt < 4; ++nt)
            #pragma unroll
            for (int e = 0; e < 4; ++e) o[rf][nt][e] = 0.f;
    #pragma unroll
    for (int rf = 0; rf < 2; ++rf)
        #pragma unroll
        for (int e = 0; e < 4; ++e) l_s[rf][e] = 0.f;

    const int c0 = tid, c1 = tid + 256;
    uint4 kr0, kr1, vr0, vr1;

#define LOADT(TG)                                                              \
    {                                                                          \
        int base = (TG) * 64;                                                  \
        kr0 = *(const uint4*)(Kb + (size_t)(base + (c0 >> 3)) * 64 + (c0 & 7) * 8); \
        kr1 = *(const uint4*)(Kb + (size_t)(base + (c1 >> 3)) * 64 + (c1 & 7) * 8); \
        vr0 = *(const uint4*)(Vb + (size_t)(base + (c0 & 63)) * 64 + (c0 >> 6) * 8); \
        vr1 = *(const uint4*)(Vb + (size_t)(base + (c1 & 63)) * 64 + (c1 >> 6) * 8); \
    }
#define WRITET(BUF)                                                            \
    {                                                                          \
        *(uint4*)&Ks[BUF][c0 >> 3][(c0 & 7) * 8] = kr0;                        \
        *(uint4*)&Ks[BUF][c1 >> 3][(c1 & 7) * 8] = kr1;                        \
        unsigned short t0[8]; *(uint4*)t0 = vr0;                               \
        _Pragma("unroll") for (int i_ = 0; i_ < 8; ++i_)                       \
            Vt[BUF][(c0 >> 6) * 8 + i_][c0 & 63] = t0[i_];                     \
        unsigned short t1[8]; *(uint4*)t1 = vr1;                               \
        _Pragma("unroll") for (int i_ = 0; i_ < 8; ++i_)                       \
            Vt[BUF][(c1 >> 6) * 8 + i_][c1 & 63] = t1[i_];                     \
    }

    LOADT(tile0);
    WRITET(0);
    __syncthreads();

    for (int kt = 0; kt < ntk; ++kt) {
        const int  tg   = tile0 + kt;
        const int  cur  = kt & 1;
        const bool more = (kt + 1 < ntk);
        if (more) LOADT(tg + 1);

        short8 kf[2][4];
        #pragma unroll
        for (int kc = 0; kc < 2; ++kc)
            #pragma unroll
            for (int nt = 0; nt < 4; ++nt)
                kf[kc][nt] = *(const short8*)&Ks[cur][nt * 16 + fr][kc * 32 + fq * 8];

        floatx4 s[2][4];
        #pragma unroll
        for (int rf = 0; rf < 2; ++rf)
            #pragma unroll
            for (int nt = 0; nt < 4; ++nt)
                #pragma unroll
                for (int e = 0; e < 4; ++e) s[rf][nt][e] = 0.f;
        #pragma unroll
        for (int rf = 0; rf < 2; ++rf)
            #pragma unroll
            for (int kc = 0; kc < 2; ++kc)
                #pragma unroll
                for (int nt = 0; nt < 4; ++nt)
                    s[rf][nt] = __builtin_amdgcn_mfma_f32_16x16x32_bf16(qf[rf][kc], kf[kc][nt], s[rf][nt], 0, 0, 0);

        // fixed-base softmax: p = 2^(s-C2); masked -> 0. No max, no rescale.
        const bool need_mask = (tg * 64 + 63) > (q0 + wm);
        #pragma unroll
        for (int rf = 0; rf < 2; ++rf)
            #pragma unroll
            for (int e = 0; e < 4; ++e) {
                const int qrow = q0 + wm + rf * 16 + fq * 4 + e;
                float rs = 0.f;
                #pragma unroll
                for (int nt = 0; nt < 4; ++nt) {
                    float v = s[rf][nt][e] - C2;
                    if (need_mask && (tg * 64 + nt * 16 + fr) > qrow) v = -1e30f;
                    float pv = __builtin_amdgcn_exp2f(v);
                    rs += pv;
                    Ps[wm + rf * 16 + fq * 4 + e][nt * 16 + fr] =
                        (unsigned short)(__float_as_uint(pv) >> 16);  // trunc pack
                }
                rs += __shfl_xor(rs, 1);
                rs += __shfl_xor(rs, 2);
                rs += __shfl_xor(rs, 4);
                rs += __shfl_xor(rs, 8);
                l_s[rf][e] += rs;
            }
        __asm__ volatile("s_waitcnt lgkmcnt(0)" ::: "memory");  // own-wave P RAW

        short8 pf[2][2], vf[2][4];
        #pragma unroll
        for (int rf = 0; rf < 2; ++rf)
            #pragma unroll
            for (int kc = 0; kc < 2; ++kc)
                pf[rf][kc] = *(const short8*)&Ps[wm + rf * 16 + fr][kc * 32 + fq * 8];
        #pragma unroll
        for (int kc = 0; kc < 2; ++kc)
            #pragma unroll
            for (int nt = 0; nt < 4; ++nt)
                vf[kc][nt] = *(const short8*)&Vt[cur][nt * 16 + fr][kc * 32 + fq * 8];
        #pragma unroll
        for (int rf = 0; rf < 2; ++rf)
            #pragma unroll
            for (int kc = 0; kc < 2; ++kc)
                #pragma unroll
                for (int nt = 0; nt < 4; ++nt)
                    o[rf][nt] = __builtin_amdgcn_mfma_f32_16x16x32_bf16(pf[rf][kc], vf[kc][nt], o[rf][nt], 0, 0, 0);

        if (more) {
            WRITET(cur ^ 1);
            __syncthreads();
        }
    }
#undef LOADT
#undef WRITET

    #pragma unroll
    for (int rf = 0; rf < 2; ++rf)
        #pragma unroll
        for (int e = 0; e < 4; ++e) {
            int row = wm + rf * 16 + fq * 4 + e;
            unsigned short* orow = pO + ((size_t)slot * 128 + row) * 64;
            #pragma unroll
            for (int nt = 0; nt < 4; ++nt)
                orow[nt * 16 + fr] = f2b(o[rf][nt][e]);
            if (fr == 0)
                pL[(size_t)slot * 128 + row] = l_s[rf][e];
        }
}

// ---------------- attention combine (fixed base: plain sums) ----------------
__global__ __launch_bounds__(256) void attn_combine(const unsigned short* __restrict__ pO,
                                                    const float* __restrict__ pL,
                                                    unsigned short* __restrict__ ctx) {
    const int qb  = blockIdx.x;
    const int bh  = blockIdx.y;
    const int b   = bh / 12, h = bh % 12;
    const int nch = (qb + 2) >> 1;
    const int slot0 = bh * 72 + chunk_ofs(qb);
    const int tid = threadIdx.x;
    const int row = tid >> 1;
    const int col0 = (tid & 1) * 32;

    float L = 0.f;
    for (int i = 0; i < nch; ++i)
        L += pL[(size_t)(slot0 + i) * 128 + row];

    float acc[32];
    #pragma unroll
    for (int j = 0; j < 32; ++j) acc[j] = 0.f;
    for (int i = 0; i < nch; ++i) {
        const unsigned short* p = pO + ((size_t)(slot0 + i) * 128 + row) * 64 + col0;
        #pragma unroll
        for (int v4 = 0; v4 < 4; ++v4) {
            uint4 u = *(const uint4*)(p + v4 * 8);
            unsigned short t[8]; *(uint4*)t = u;
            #pragma unroll
            for (int j = 0; j < 8; ++j) acc[v4 * 8 + j] += b2f(t[j]);
        }
    }
    float inv = 1.f / L;
    unsigned short* orow = ctx + ((size_t)(b * 2048 + qb * 128 + row)) * 768 + h * 64 + col0;
    #pragma unroll
    for (int v4 = 0; v4 < 4; ++v4) {
        unsigned short t[8];
        #pragma unroll
        for (int j = 0; j < 8; ++j) t[j] = f2b(acc[v4 * 8 + j] * inv);
        *(uint4*)(orow + v4 * 8) = *(uint4*)t;
    }
}

// ---------------- fused split-K reduce + bias + residual + LayerNorm --------
__global__ __launch_bounds__(256) void resid_ln2(const float* __restrict__ X,
                                                 const float* __restrict__ P,
                                                 int nsplit,
                                                 const float* __restrict__ bv,
                                                 const float* __restrict__ gain,
                                                 const float* __restrict__ beta,
                                                 float* __restrict__ outF,
                                                 unsigned short* __restrict__ outB) {
    const int row = blockIdx.x;
    const int t   = threadIdx.x;
    const size_t off = (size_t)row * 768;
    float v[3];
    #pragma unroll
    for (int i = 0; i < 3; i++) {
        size_t c = off + t + i * 256;
        float r = X[c] + bv[t + i * 256];
        for (int p = 0; p < nsplit; ++p) r += P[(size_t)p * 3145728 + c];
        v[i] = r;
    }
    float s  = v[0] + v[1] + v[2];
    float s2 = v[0] * v[0] + v[1] * v[1] + v[2] * v[2];
    #pragma unroll
    for (int o2 = 32; o2 > 0; o2 >>= 1) {
        s  += __shfl_down(s,  o2);
        s2 += __shfl_down(s2, o2);
    }
    __shared__ float rs[4], rq[4];
    if ((t & 63) == 0) { rs[t >> 6] = s; rq[t >> 6] = s2; }
    __syncthreads();
    float S    = rs[0] + rs[1] + rs[2] + rs[3];
    float S2   = rq[0] + rq[1] + rq[2] + rq[3];
    float mean = S * (1.0f / 768.0f);
    float var  = S2 * (1.0f / 768.0f) - mean * mean;
    float inv  = rsqrtf(var + 1e-5f);
    #pragma unroll
    for (int i = 0; i < 3; i++) {
        int c   = t + i * 256;
        float y = gain[c] * (v[i] - mean) * inv + beta[c];
        if (outF) outF[off + c] = y;
        if (outB) outB[off + c] = f2b(y);
    }
}

// ---------------------------------------------------------------------------
extern "C" void kernel_launch(void* const* d_in, const int* in_sizes, int n_in,
                              void* d_out, int out_size, void* d_ws, size_t ws_size,
                              hipStream_t stream) {
    const float* x    = (const float*)d_in[0];
    const float* Wqkv = (const float*)d_in[1];
    const float* Wout = (const float*)d_in[2];
    const float* bout = (const float*)d_in[3];
    const float* W1   = (const float*)d_in[4];
    const float* b1   = (const float*)d_in[5];
    const float* W2   = (const float*)d_in[6];
    const float* b2   = (const float*)d_in[7];
    const float* g1   = (const float*)d_in[8];
    const float* be1  = (const float*)d_in[9];
    const float* g2   = (const float*)d_in[10];
    const float* be2  = (const float*)d_in[11];
    float* out = (float*)d_out;

    // workspace layout (bytes), liveness-aliased; peak 83,361,792
    char* ws = (char*)d_ws;
    unsigned short* wqkvT  = (unsigned short*)(ws + 0);         // 3.5M  ->QKV
    unsigned short* woutT  = (unsigned short*)(ws + 3538944);   // 1.2M  ->Wout
    unsigned short* w1T    = (unsigned short*)(ws + 4718592);   // 4.7M  ->W1
    unsigned short* w2T    = (unsigned short*)(ws + 9437184);   // 4.7M  ->W2
    unsigned short* xb     = (unsigned short*)(ws + 14155776);  // 6.3M  ->QKV
    unsigned short* qkvG   = (unsigned short*)(ws + 20447232);  // 18.9M ->attn_part
    unsigned short* Qg     = qkvG;
    unsigned short* Kg     = qkvG + 3145728;
    unsigned short* Vg     = qkvG + 6291456;
    unsigned short* pO     = (unsigned short*)(ws + 39321600);  // 28.3M ->combine
    float*          pL     = (float*)(ws + 67633152);           // 0.9M  ->combine
    unsigned short* ctxb   = (unsigned short*)(ws + 14155776);  // 6.3M  combine->Wout (xb dead)
    float*          WoutP  = (float*)(ws + 39321600);           // 3x12.6M Wout->LN1; ends 77,070,336
    float*          h      = (float*)(ws + 20447232);           // 12.6M LN1->LN2 (qkvG dead)
    unsigned short* hb     = (unsigned short*)(ws + 77070336);  // 6.3M  LN1->W1; ends 83,361,792
    unsigned short* ffb    = (unsigned short*)(ws + 39321600);  // 25.2M W1->W2 (WoutP dead)
    float*          W2P    = (float*)(ws + 64487424);           // 2x12.6M W2->LN2; ends 77,070,336

    // 1) fused prepass
    prep_all<<<9984, 256, 0, stream>>>(x, xb, Wqkv, wqkvT, Wout, woutT, W1, w1T, W2, w2T);
    // 2) QKV projection -> Q/K/V [bh][s][64] bf16 (Q pre-scaled by QSC)
    gemm_bf16<<<dim3(18, 32), 256, 0, stream>>>(xb, wqkvT, nullptr, nullptr, qkvG,
                                                4096, 2304, 768, 0, 1, 768);
    // 3) kv-split flash attention + combine -> ctx bf16
    attn_part<<<dim3(72, 24), 256, 0, stream>>>(Qg, Kg, Vg, pO, pL);
    attn_combine<<<dim3(16, 24), 256, 0, stream>>>(pO, pL, ctxb);
    // 4) out projection, split-K=3 -> fp32 partials
    gemm_bf16<<<dim3(6, 32, 3), 256, 0, stream>>>(ctxb, woutT, nullptr, WoutP, nullptr,
                                                  4096, 768, 768, 0, 2, 256);
    // 5) h = LN(x + sum(WoutP) + bout) -> fp32 + bf16
    resid_ln2<<<4096, 256, 0, stream>>>(x, WoutP, 3, bout, g1, be1, h, hb);
    // 6) ff = relu(h @ W1 + b1) -> bf16
    gemm_bf16<<<dim3(24, 32), 256, 0, stream>>>(hb, w1T, b1, nullptr, ffb,
                                                4096, 3072, 768, 1, 0, 768);
    // 7) ff2 partials = ff @ W2 (split-K=2)
    gemm_bf16<<<dim3(6, 32, 2), 256, 0, stream>>>(ffb, w2T, nullptr, W2P, nullptr,
                                                  4096, 768, 3072, 0, 2, 1536);
    // 8) out = LN(h + sum(W2P) + b2) -> fp32
    resid_ln2<<<4096, 256, 0, stream>>>(h, W2P, 2, b2, g2, be2, out, nullptr);
}

// Round 7
// 332.433 us; speedup vs baseline: 8.0900x; 1.0295x over previous
//
#include <hip/hip_runtime.h>

// ---------------------------------------------------------------------------
// TransformerBlock: B=2,S=2048,D=768,H=12,DH=64,DFF=3072, causal attn, 2x LN
// Round 6: GEMM BK 32->64 (32 MFMAs + 32KB staging per barrier-pair instead
// of 16/16KB) -- halves barrier-drain count in the short-K GEMM chain.
// Attention (fixed-base softmax kv-split) + split-K plumbing unchanged.
// ---------------------------------------------------------------------------

typedef __attribute__((ext_vector_type(8))) short  short8;   // 8 x bf16 (4 VGPR)
typedef __attribute__((ext_vector_type(4))) float  floatx4;  // 4 x f32 acc

#define QSC 0.18033688f   // 0.125 * log2(e): folded into Q at scatter
#define C2  24.0f         // fixed base-2 softmax offset

__device__ __forceinline__ float b2f(unsigned short u) {
    return __uint_as_float(((unsigned)u) << 16);
}
__device__ __forceinline__ unsigned short f2b(float f) {  // RNE
    unsigned x = __float_as_uint(f);
    return (unsigned short)((x + 0x7fffu + ((x >> 16) & 1u)) >> 16);
}
__device__ __forceinline__ void async_cp16(const void* g, void* l) {
    __builtin_amdgcn_global_load_lds((const __attribute__((address_space(1))) void*)g,
                                     (__attribute__((address_space(3))) void*)l,
                                     16, 0, 0);
}
__device__ __forceinline__ int chunk_ofs(int qb) {
    int t = qb >> 1;
    return (qb & 1) ? (t + 1) * (t + 1) : t * (t + 1);
}

// ---------------- fused prepass: x->bf16 + 4 weight transposes --------------
__global__ __launch_bounds__(256) void prep_all(
    const float* __restrict__ x,    unsigned short* __restrict__ xb,
    const float* __restrict__ Wqkv, unsigned short* __restrict__ wqkvT,
    const float* __restrict__ Wout, unsigned short* __restrict__ woutT,
    const float* __restrict__ W1,   unsigned short* __restrict__ w1T,
    const float* __restrict__ W2,   unsigned short* __restrict__ w2T)
{
    __shared__ float tile[32][33];
    int idx = blockIdx.x;
    int tx = threadIdx.x & 31, ty = threadIdx.x >> 5;
    if (idx >= 6912) {  // cvt x
        int i = (idx - 6912) * 256 + threadIdx.x;
        float4 v = ((const float4*)x)[i];
        ushort4 u;
        u.x = f2b(v.x); u.y = f2b(v.y); u.z = f2b(v.z); u.w = f2b(v.w);
        ((ushort4*)xb)[i] = u;
        return;
    }
    const float* W; unsigned short* Wt; int K, N, bx, by;
    if (idx < 1728)      { W = Wqkv; Wt = wqkvT; K = 768;  N = 2304; bx = idx % 72;        by = idx / 72; }
    else if (idx < 2304) { W = Wout; Wt = woutT; K = 768;  N = 768;  bx = (idx-1728) % 24; by = (idx-1728) / 24; }
    else if (idx < 4608) { W = W1;   Wt = w1T;   K = 768;  N = 3072; bx = (idx-2304) % 96; by = (idx-2304) / 96; }
    else                 { W = W2;   Wt = w2T;   K = 3072; N = 768;  bx = (idx-4608) % 24; by = (idx-4608) / 24; }
    int n0 = bx * 32, k0 = by * 32;
    for (int i = ty; i < 32; i += 8)
        tile[i][tx] = W[(size_t)(k0 + i) * N + n0 + tx];
    __syncthreads();
    for (int i = ty; i < 32; i += 8)
        Wt[(size_t)(n0 + i) * K + k0 + tx] = f2b(tile[tx][i]);
}

// ---------------- bf16 MFMA GEMM (BK=64) -------------------------------------
// mode 0: row-major outF/outB (+bias, relu)
// mode 1: qkv scatter -> outB = Q|K|V each [24][2048][64]; Q scaled by QSC
// mode 2: split-K fp32 partial -> outF + blockIdx.z*M*N
__global__ __launch_bounds__(256) void gemm_bf16(
    const unsigned short* __restrict__ A,
    const unsigned short* __restrict__ Bt,
    const float* __restrict__ bias,
    float* __restrict__ outF,
    unsigned short* __restrict__ outB,
    int M, int N, int K, int relu, int mode, int kslab)
{
    __shared__ unsigned short As[128][64];
    __shared__ unsigned short Bs[128][64];
    const int tid  = threadIdx.x;
    const int m0   = blockIdx.y * 128;
    const int n0   = blockIdx.x * 128;
    const int kz   = blockIdx.z;
    const int kbeg = kz * kslab;
    const int kend = kbeg + kslab;
    const int lane = tid & 63;
    const int wave = tid >> 6;
    const int wm   = (wave >> 1) * 64;
    const int wn   = (wave & 1) * 64;
    const int fr   = lane & 15;
    const int fq   = lane >> 4;

    floatx4 acc[4][4];
    for (int i = 0; i < 4; i++)
        for (int j = 0; j < 4; j++)
            for (int e = 0; e < 4; e++) acc[i][j][e] = 0.f;

    for (int kk = kbeg; kk < kend; kk += 64) {
        __syncthreads();  // previous iter's LDS reads done
        #pragma unroll
        for (int r = 0; r < 4; ++r) {
            int c    = r * 256 + tid;      // 1024 16B-chunks per array
            int row  = c >> 3;
            int colb = (c & 7) * 8;
            async_cp16(A  + (size_t)(m0 + row) * K + kk + colb, &As[row][colb]);
            async_cp16(Bt + (size_t)(n0 + row) * K + kk + colb, &Bs[row][colb]);
        }
        __syncthreads();  // drains vmcnt(0) before barrier (compiler-emitted)

        #pragma unroll
        for (int kc = 0; kc < 2; ++kc) {
            short8 a[4], b[4];
            #pragma unroll
            for (int t = 0; t < 4; t++) a[t] = *(const short8*)&As[wm + t * 16 + fr][kc * 32 + fq * 8];
            #pragma unroll
            for (int t = 0; t < 4; t++) b[t] = *(const short8*)&Bs[wn + t * 16 + fr][kc * 32 + fq * 8];
            #pragma unroll
            for (int i = 0; i < 4; i++)
                #pragma unroll
                for (int j = 0; j < 4; j++)
                    acc[i][j] = __builtin_amdgcn_mfma_f32_16x16x32_bf16(a[i], b[j], acc[i][j], 0, 0, 0);
        }
    }

    if (mode == 2) {
        float* dst = outF + (size_t)kz * M * N;
        #pragma unroll
        for (int j = 0; j < 4; j++) {
            int col = n0 + wn + j * 16 + fr;
            #pragma unroll
            for (int i = 0; i < 4; i++) {
                int rbase = m0 + wm + i * 16 + fq * 4;
                #pragma unroll
                for (int e = 0; e < 4; e++)
                    dst[(size_t)(rbase + e) * N + col] = acc[i][j][e];
            }
        }
        return;
    }
    if (mode == 1) {
        #pragma unroll
        for (int j = 0; j < 4; j++) {
            int col   = n0 + wn + j * 16 + fr;
            int which = (col >= 1536) ? 2 : (col >= 768 ? 1 : 0);
            float sc  = (which == 0) ? QSC : 1.0f;   // fold 0.125*log2e into Q
            int rem   = col - which * 768;
            int hh    = rem >> 6, d = rem & 63;
            #pragma unroll
            for (int i = 0; i < 4; i++) {
                int rbase = m0 + wm + i * 16 + fq * 4;
                #pragma unroll
                for (int e = 0; e < 4; e++) {
                    int row = rbase + e;
                    int b_  = row >> 11, srow = row & 2047;
                    size_t idx = (size_t)which * 3145728 +
                                 ((size_t)(b_ * 12 + hh) * 2048 + srow) * 64 + d;
                    outB[idx] = f2b(acc[i][j][e] * sc);
                }
            }
        }
        return;
    }
    #pragma unroll
    for (int j = 0; j < 4; j++) {
        int col  = n0 + wn + j * 16 + fr;
        float bv = bias ? bias[col] : 0.f;
        #pragma unroll
        for (int i = 0; i < 4; i++) {
            int rbase = m0 + wm + i * 16 + fq * 4;
            #pragma unroll
            for (int e = 0; e < 4; e++) {
                float v = acc[i][j][e] + bv;
                if (relu) v = fmaxf(v, 0.f);
                size_t idx = (size_t)(rbase + e) * N + col;
                if (outF) outF[idx] = v;
                if (outB) outB[idx] = f2b(v);
            }
        }
    }
}

// ---------------- attention partial (kv-split, fixed-base softmax) ----------
__global__ __launch_bounds__(256) void attn_part(const unsigned short* __restrict__ Qg,
                                                 const unsigned short* __restrict__ Kg,
                                                 const unsigned short* __restrict__ Vg,
                                                 unsigned short* __restrict__ pO,
                                                 float* __restrict__ pL) {
    __shared__ unsigned short Ks[2][64][72];
    __shared__ unsigned short Vt[2][64][72];
    __shared__ unsigned short Ps[128][72];
    const int tid  = threadIdx.x;
    const int lane = tid & 63;
    const int wave = tid >> 6;
    const int fr   = lane & 15;
    const int fq   = lane >> 4;
    const int wm   = wave * 32;
    const int r    = blockIdx.x;
    const int bh   = blockIdx.y;
    int qb = 0;
    for (int q_ = 15; q_ >= 0; --q_) if (r >= chunk_ofs(q_)) { qb = q_; break; }
    const int c     = r - chunk_ofs(qb);
    const int q0    = qb * 128;
    const int tile0 = 4 * c;
    const int ntk   = min(4, 2 * (qb + 1) - 4 * c);
    const int slot  = bh * 72 + r;
    const unsigned short* Qb = Qg + (size_t)bh * 2048 * 64;
    const unsigned short* Kb = Kg + (size_t)bh * 2048 * 64;
    const unsigned short* Vb = Vg + (size_t)bh * 2048 * 64;

    short8 qf[2][2];
    #pragma unroll
    for (int rf = 0; rf < 2; ++rf) {
        const unsigned short* qr = Qb + (size_t)(q0 + wm + rf * 16 + fr) * 64;
        qf[rf][0] = *(const short8*)(qr + fq * 8);
        qf[rf][1] = *(const short8*)(qr + 32 + fq * 8);
    }

    floatx4 o[2][4];
    float l_s[2][4];
    #pragma unroll
    for (int rf = 0; rf < 2; ++rf)
        #pragma unroll
        for (int nt = 0; nt < 4; ++nt)
            #pragma unroll
            for (int e = 0; e < 4; ++e) o[rf][nt][e] = 0.f;
    #pragma unroll
    for (int rf = 0; rf < 2; ++rf)
        #pragma unroll
        for (int e = 0; e < 4; ++e) l_s[rf][e] = 0.f;

    const int c0 = tid, c1 = tid + 256;
    uint4 kr0, kr1, vr0, vr1;

#define LOADT(TG)                                                              \
    {                                                                          \
        int base = (TG) * 64;                                                  \
        kr0 = *(const uint4*)(Kb + (size_t)(base + (c0 >> 3)) * 64 + (c0 & 7) * 8); \
        kr1 = *(const uint4*)(Kb + (size_t)(base + (c1 >> 3)) * 64 + (c1 & 7) * 8); \
        vr0 = *(const uint4*)(Vb + (size_t)(base + (c0 & 63)) * 64 + (c0 >> 6) * 8); \
        vr1 = *(const uint4*)(Vb + (size_t)(base + (c1 & 63)) * 64 + (c1 >> 6) * 8); \
    }
#define WRITET(BUF)                                                            \
    {                                                                          \
        *(uint4*)&Ks[BUF][c0 >> 3][(c0 & 7) * 8] = kr0;                        \
        *(uint4*)&Ks[BUF][c1 >> 3][(c1 & 7) * 8] = kr1;                        \
        unsigned short t0[8]; *(uint4*)t0 = vr0;                               \
        _Pragma("unroll") for (int i_ = 0; i_ < 8; ++i_)                       \
            Vt[BUF][(c0 >> 6) * 8 + i_][c0 & 63] = t0[i_];                     \
        unsigned short t1[8]; *(uint4*)t1 = vr1;                               \
        _Pragma("unroll") for (int i_ = 0; i_ < 8; ++i_)                       \
            Vt[BUF][(c1 >> 6) * 8 + i_][c1 & 63] = t1[i_];                     \
    }

    LOADT(tile0);
    WRITET(0);
    __syncthreads();

    for (int kt = 0; kt < ntk; ++kt) {
        const int  tg   = tile0 + kt;
        const int  cur  = kt & 1;
        const bool more = (kt + 1 < ntk);
        if (more) LOADT(tg + 1);

        short8 kf[2][4];
        #pragma unroll
        for (int kc = 0; kc < 2; ++kc)
            #pragma unroll
            for (int nt = 0; nt < 4; ++nt)
                kf[kc][nt] = *(const short8*)&Ks[cur][nt * 16 + fr][kc * 32 + fq * 8];

        floatx4 s[2][4];
        #pragma unroll
        for (int rf = 0; rf < 2; ++rf)
            #pragma unroll
            for (int nt = 0; nt < 4; ++nt)
                #pragma unroll
                for (int e = 0; e < 4; ++e) s[rf][nt][e] = 0.f;
        #pragma unroll
        for (int rf = 0; rf < 2; ++rf)
            #pragma unroll
            for (int kc = 0; kc < 2; ++kc)
                #pragma unroll
                for (int nt = 0; nt < 4; ++nt)
                    s[rf][nt] = __builtin_amdgcn_mfma_f32_16x16x32_bf16(qf[rf][kc], kf[kc][nt], s[rf][nt], 0, 0, 0);

        // fixed-base softmax: p = 2^(s-C2); masked -> 0. No max, no rescale.
        const bool need_mask = (tg * 64 + 63) > (q0 + wm);
        #pragma unroll
        for (int rf = 0; rf < 2; ++rf)
            #pragma unroll
            for (int e = 0; e < 4; ++e) {
                const int qrow = q0 + wm + rf * 16 + fq * 4 + e;
                float rs = 0.f;
                #pragma unroll
                for (int nt = 0; nt < 4; ++nt) {
                    float v = s[rf][nt][e] - C2;
                    if (need_mask && (tg * 64 + nt * 16 + fr) > qrow) v = -1e30f;
                    float pv = __builtin_amdgcn_exp2f(v);
                    rs += pv;
                    Ps[wm + rf * 16 + fq * 4 + e][nt * 16 + fr] =
                        (unsigned short)(__float_as_uint(pv) >> 16);  // trunc pack
                }
                rs += __shfl_xor(rs, 1);
                rs += __shfl_xor(rs, 2);
                rs += __shfl_xor(rs, 4);
                rs += __shfl_xor(rs, 8);
                l_s[rf][e] += rs;
            }
        __asm__ volatile("s_waitcnt lgkmcnt(0)" ::: "memory");  // own-wave P RAW

        short8 pf[2][2], vf[2][4];
        #pragma unroll
        for (int rf = 0; rf < 2; ++rf)
            #pragma unroll
            for (int kc = 0; kc < 2; ++kc)
                pf[rf][kc] = *(const short8*)&Ps[wm + rf * 16 + fr][kc * 32 + fq * 8];
        #pragma unroll
        for (int kc = 0; kc < 2; ++kc)
            #pragma unroll
            for (int nt = 0; nt < 4; ++nt)
                vf[kc][nt] = *(const short8*)&Vt[cur][nt * 16 + fr][kc * 32 + fq * 8];
        #pragma unroll
        for (int rf = 0; rf < 2; ++rf)
            #pragma unroll
            for (int kc = 0; kc < 2; ++kc)
                #pragma unroll
                for (int nt = 0; nt < 4; ++nt)
                    o[rf][nt] = __builtin_amdgcn_mfma_f32_16x16x32_bf16(pf[rf][kc], vf[kc][nt], o[rf][nt], 0, 0, 0);

        if (more) {
            WRITET(cur ^ 1);
            __syncthreads();
        }
    }
#undef LOADT
#undef WRITET

    #pragma unroll
    for (int rf = 0; rf < 2; ++rf)
        #pragma unroll
        for (int e = 0; e < 4; ++e) {
            int row = wm + rf * 16 + fq * 4 + e;
            unsigned short* orow = pO + ((size_t)slot * 128 + row) * 64;
            #pragma unroll
            for (int nt = 0; nt < 4; ++nt)
                orow[nt * 16 + fr] = f2b(o[rf][nt][e]);
            if (fr == 0)
                pL[(size_t)slot * 128 + row] = l_s[rf][e];
        }
}

// ---------------- attention combine (fixed base: plain sums) ----------------
__global__ __launch_bounds__(256) void attn_combine(const unsigned short* __restrict__ pO,
                                                    const float* __restrict__ pL,
                                                    unsigned short* __restrict__ ctx) {
    const int qb  = blockIdx.x;
    const int bh  = blockIdx.y;
    const int b   = bh / 12, h = bh % 12;
    const int nch = (qb + 2) >> 1;
    const int slot0 = bh * 72 + chunk_ofs(qb);
    const int tid = threadIdx.x;
    const int row = tid >> 1;
    const int col0 = (tid & 1) * 32;

    float L = 0.f;
    for (int i = 0; i < nch; ++i)
        L += pL[(size_t)(slot0 + i) * 128 + row];

    float acc[32];
    #pragma unroll
    for (int j = 0; j < 32; ++j) acc[j] = 0.f;
    for (int i = 0; i < nch; ++i) {
        const unsigned short* p = pO + ((size_t)(slot0 + i) * 128 + row) * 64 + col0;
        #pragma unroll
        for (int v4 = 0; v4 < 4; ++v4) {
            uint4 u = *(const uint4*)(p + v4 * 8);
            unsigned short t[8]; *(uint4*)t = u;
            #pragma unroll
            for (int j = 0; j < 8; ++j) acc[v4 * 8 + j] += b2f(t[j]);
        }
    }
    float inv = 1.f / L;
    unsigned short* orow = ctx + ((size_t)(b * 2048 + qb * 128 + row)) * 768 + h * 64 + col0;
    #pragma unroll
    for (int v4 = 0; v4 < 4; ++v4) {
        unsigned short t[8];
        #pragma unroll
        for (int j = 0; j < 8; ++j) t[j] = f2b(acc[v4 * 8 + j] * inv);
        *(uint4*)(orow + v4 * 8) = *(uint4*)t;
    }
}

// ---------------- fused split-K reduce + bias + residual + LayerNorm --------
__global__ __launch_bounds__(256) void resid_ln2(const float* __restrict__ X,
                                                 const float* __restrict__ P,
                                                 int nsplit,
                                                 const float* __restrict__ bv,
                                                 const float* __restrict__ gain,
                                                 const float* __restrict__ beta,
                                                 float* __restrict__ outF,
                                                 unsigned short* __restrict__ outB) {
    const int row = blockIdx.x;
    const int t   = threadIdx.x;
    const size_t off = (size_t)row * 768;
    float v[3];
    #pragma unroll
    for (int i = 0; i < 3; i++) {
        size_t c = off + t + i * 256;
        float r = X[c] + bv[t + i * 256];
        for (int p = 0; p < nsplit; ++p) r += P[(size_t)p * 3145728 + c];
        v[i] = r;
    }
    float s  = v[0] + v[1] + v[2];
    float s2 = v[0] * v[0] + v[1] * v[1] + v[2] * v[2];
    #pragma unroll
    for (int o2 = 32; o2 > 0; o2 >>= 1) {
        s  += __shfl_down(s,  o2);
        s2 += __shfl_down(s2, o2);
    }
    __shared__ float rs[4], rq[4];
    if ((t & 63) == 0) { rs[t >> 6] = s; rq[t >> 6] = s2; }
    __syncthreads();
    float S    = rs[0] + rs[1] + rs[2] + rs[3];
    float S2   = rq[0] + rq[1] + rq[2] + rq[3];
    float mean = S * (1.0f / 768.0f);
    float var  = S2 * (1.0f / 768.0f) - mean * mean;
    float inv  = rsqrtf(var + 1e-5f);
    #pragma unroll
    for (int i = 0; i < 3; i++) {
        int c   = t + i * 256;
        float y = gain[c] * (v[i] - mean) * inv + beta[c];
        if (outF) outF[off + c] = y;
        if (outB) outB[off + c] = f2b(y);
    }
}

// ---------------------------------------------------------------------------
extern "C" void kernel_launch(void* const* d_in, const int* in_sizes, int n_in,
                              void* d_out, int out_size, void* d_ws, size_t ws_size,
                              hipStream_t stream) {
    const float* x    = (const float*)d_in[0];
    const float* Wqkv = (const float*)d_in[1];
    const float* Wout = (const float*)d_in[2];
    const float* bout = (const float*)d_in[3];
    const float* W1   = (const float*)d_in[4];
    const float* b1   = (const float*)d_in[5];
    const float* W2   = (const float*)d_in[6];
    const float* b2   = (const float*)d_in[7];
    const float* g1   = (const float*)d_in[8];
    const float* be1  = (const float*)d_in[9];
    const float* g2   = (const float*)d_in[10];
    const float* be2  = (const float*)d_in[11];
    float* out = (float*)d_out;

    // workspace layout (bytes), liveness-aliased; peak 83,361,792
    char* ws = (char*)d_ws;
    unsigned short* wqkvT  = (unsigned short*)(ws + 0);         // 3.5M  ->QKV
    unsigned short* woutT  = (unsigned short*)(ws + 3538944);   // 1.2M  ->Wout
    unsigned short* w1T    = (unsigned short*)(ws + 4718592);   // 4.7M  ->W1
    unsigned short* w2T    = (unsigned short*)(ws + 9437184);   // 4.7M  ->W2
    unsigned short* xb     = (unsigned short*)(ws + 14155776);  // 6.3M  ->QKV
    unsigned short* qkvG   = (unsigned short*)(ws + 20447232);  // 18.9M ->attn_part
    unsigned short* Qg     = qkvG;
    unsigned short* Kg     = qkvG + 3145728;
    unsigned short* Vg     = qkvG + 6291456;
    unsigned short* pO     = (unsigned short*)(ws + 39321600);  // 28.3M ->combine
    float*          pL     = (float*)(ws + 67633152);           // 0.9M  ->combine
    unsigned short* ctxb   = (unsigned short*)(ws + 14155776);  // 6.3M  combine->Wout (xb dead)
    float*          WoutP  = (float*)(ws + 39321600);           // 3x12.6M Wout->LN1; ends 77,070,336
    float*          h      = (float*)(ws + 20447232);           // 12.6M LN1->LN2 (qkvG dead)
    unsigned short* hb     = (unsigned short*)(ws + 77070336);  // 6.3M  LN1->W1; ends 83,361,792
    unsigned short* ffb    = (unsigned short*)(ws + 39321600);  // 25.2M W1->W2 (WoutP dead)
    float*          W2P    = (float*)(ws + 64487424);           // 2x12.6M W2->LN2; ends 77,070,336

    // 1) fused prepass
    prep_all<<<9984, 256, 0, stream>>>(x, xb, Wqkv, wqkvT, Wout, woutT, W1, w1T, W2, w2T);
    // 2) QKV projection -> Q/K/V [bh][s][64] bf16 (Q pre-scaled by QSC)
    gemm_bf16<<<dim3(18, 32), 256, 0, stream>>>(xb, wqkvT, nullptr, nullptr, qkvG,
                                                4096, 2304, 768, 0, 1, 768);
    // 3) kv-split flash attention + combine -> ctx bf16
    attn_part<<<dim3(72, 24), 256, 0, stream>>>(Qg, Kg, Vg, pO, pL);
    attn_combine<<<dim3(16, 24), 256, 0, stream>>>(pO, pL, ctxb);
    // 4) out projection, split-K=3 -> fp32 partials
    gemm_bf16<<<dim3(6, 32, 3), 256, 0, stream>>>(ctxb, woutT, nullptr, WoutP, nullptr,
                                                  4096, 768, 768, 0, 2, 256);
    // 5) h = LN(x + sum(WoutP) + bout) -> fp32 + bf16
    resid_ln2<<<4096, 256, 0, stream>>>(x, WoutP, 3, bout, g1, be1, h, hb);
    // 6) ff = relu(h @ W1 + b1) -> bf16
    gemm_bf16<<<dim3(24, 32), 256, 0, stream>>>(hb, w1T, b1, nullptr, ffb,
                                                4096, 3072, 768, 1, 0, 768);
    // 7) ff2 partials = ff @ W2 (split-K=2)
    gemm_bf16<<<dim3(6, 32, 2), 256, 0, stream>>>(ffb, w2T, nullptr, W2P, nullptr,
                                                  4096, 768, 3072, 0, 2, 1536);
    // 8) out = LN(h + sum(W2P) + b2) -> fp32
    resid_ln2<<<4096, 256, 0, stream>>>(h, W2P, 2, b2, g2, be2, out, nullptr);
}

// Round 8
// 329.576 us; speedup vs baseline: 8.1601x; 1.0087x over previous
//
#include <hip/hip_runtime.h>

// ---------------------------------------------------------------------------
// TransformerBlock: B=2,S=2048,D=768,H=12,DH=64,DFF=3072, causal attn, 2x LN
// Round 7: attn_part LDS 55.3KB -> 48KB via XOR-swizzled tiles (no padding)
// => 3 blocks/CU residency (was 2). Longest-chunks-first dispatch. GEMM BK=64,
// fixed-base softmax, split-K plumbing unchanged.
// ---------------------------------------------------------------------------

typedef __attribute__((ext_vector_type(8))) short  short8;   // 8 x bf16 (4 VGPR)
typedef __attribute__((ext_vector_type(4))) float  floatx4;  // 4 x f32 acc

#define QSC 0.18033688f   // 0.125 * log2(e): folded into Q at scatter
#define C2  24.0f         // fixed base-2 softmax offset

__device__ __forceinline__ float b2f(unsigned short u) {
    return __uint_as_float(((unsigned)u) << 16);
}
__device__ __forceinline__ unsigned short f2b(float f) {  // RNE
    unsigned x = __float_as_uint(f);
    return (unsigned short)((x + 0x7fffu + ((x >> 16) & 1u)) >> 16);
}
__device__ __forceinline__ void async_cp16(const void* g, void* l) {
    __builtin_amdgcn_global_load_lds((const __attribute__((address_space(1))) void*)g,
                                     (__attribute__((address_space(3))) void*)l,
                                     16, 0, 0);
}
__device__ __forceinline__ int chunk_ofs(int qb) {
    int t = qb >> 1;
    return (qb & 1) ? (t + 1) * (t + 1) : t * (t + 1);
}
// XOR-swizzled [R][64] bf16 tile: elem offset of 16B chunk `chunk` in row `row`
__device__ __forceinline__ int swz16(int row, int chunk) {
    return row * 64 + (((chunk ^ (row & 7)) & 7) << 3);
}

// ---------------- fused prepass: x->bf16 + 4 weight transposes --------------
__global__ __launch_bounds__(256) void prep_all(
    const float* __restrict__ x,    unsigned short* __restrict__ xb,
    const float* __restrict__ Wqkv, unsigned short* __restrict__ wqkvT,
    const float* __restrict__ Wout, unsigned short* __restrict__ woutT,
    const float* __restrict__ W1,   unsigned short* __restrict__ w1T,
    const float* __restrict__ W2,   unsigned short* __restrict__ w2T)
{
    __shared__ float tile[32][33];
    int idx = blockIdx.x;
    int tx = threadIdx.x & 31, ty = threadIdx.x >> 5;
    if (idx >= 6912) {  // cvt x
        int i = (idx - 6912) * 256 + threadIdx.x;
        float4 v = ((const float4*)x)[i];
        ushort4 u;
        u.x = f2b(v.x); u.y = f2b(v.y); u.z = f2b(v.z); u.w = f2b(v.w);
        ((ushort4*)xb)[i] = u;
        return;
    }
    const float* W; unsigned short* Wt; int K, N, bx, by;
    if (idx < 1728)      { W = Wqkv; Wt = wqkvT; K = 768;  N = 2304; bx = idx % 72;        by = idx / 72; }
    else if (idx < 2304) { W = Wout; Wt = woutT; K = 768;  N = 768;  bx = (idx-1728) % 24; by = (idx-1728) / 24; }
    else if (idx < 4608) { W = W1;   Wt = w1T;   K = 768;  N = 3072; bx = (idx-2304) % 96; by = (idx-2304) / 96; }
    else                 { W = W2;   Wt = w2T;   K = 3072; N = 768;  bx = (idx-4608) % 24; by = (idx-4608) / 24; }
    int n0 = bx * 32, k0 = by * 32;
    for (int i = ty; i < 32; i += 8)
        tile[i][tx] = W[(size_t)(k0 + i) * N + n0 + tx];
    __syncthreads();
    for (int i = ty; i < 32; i += 8)
        Wt[(size_t)(n0 + i) * K + k0 + tx] = f2b(tile[tx][i]);
}

// ---------------- bf16 MFMA GEMM (BK=64) -------------------------------------
// mode 0: row-major outF/outB (+bias, relu)
// mode 1: qkv scatter -> outB = Q|K|V each [24][2048][64]; Q scaled by QSC
// mode 2: split-K fp32 partial -> outF + blockIdx.z*M*N
__global__ __launch_bounds__(256) void gemm_bf16(
    const unsigned short* __restrict__ A,
    const unsigned short* __restrict__ Bt,
    const float* __restrict__ bias,
    float* __restrict__ outF,
    unsigned short* __restrict__ outB,
    int M, int N, int K, int relu, int mode, int kslab)
{
    __shared__ unsigned short As[128][64];
    __shared__ unsigned short Bs[128][64];
    const int tid  = threadIdx.x;
    const int m0   = blockIdx.y * 128;
    const int n0   = blockIdx.x * 128;
    const int kz   = blockIdx.z;
    const int kbeg = kz * kslab;
    const int kend = kbeg + kslab;
    const int lane = tid & 63;
    const int wave = tid >> 6;
    const int wm   = (wave >> 1) * 64;
    const int wn   = (wave & 1) * 64;
    const int fr   = lane & 15;
    const int fq   = lane >> 4;

    floatx4 acc[4][4];
    for (int i = 0; i < 4; i++)
        for (int j = 0; j < 4; j++)
            for (int e = 0; e < 4; e++) acc[i][j][e] = 0.f;

    for (int kk = kbeg; kk < kend; kk += 64) {
        __syncthreads();
        #pragma unroll
        for (int r = 0; r < 4; ++r) {
            int c    = r * 256 + tid;
            int row  = c >> 3;
            int colb = (c & 7) * 8;
            async_cp16(A  + (size_t)(m0 + row) * K + kk + colb, &As[row][colb]);
            async_cp16(Bt + (size_t)(n0 + row) * K + kk + colb, &Bs[row][colb]);
        }
        __syncthreads();

        #pragma unroll
        for (int kc = 0; kc < 2; ++kc) {
            short8 a[4], b[4];
            #pragma unroll
            for (int t = 0; t < 4; t++) a[t] = *(const short8*)&As[wm + t * 16 + fr][kc * 32 + fq * 8];
            #pragma unroll
            for (int t = 0; t < 4; t++) b[t] = *(const short8*)&Bs[wn + t * 16 + fr][kc * 32 + fq * 8];
            #pragma unroll
            for (int i = 0; i < 4; i++)
                #pragma unroll
                for (int j = 0; j < 4; j++)
                    acc[i][j] = __builtin_amdgcn_mfma_f32_16x16x32_bf16(a[i], b[j], acc[i][j], 0, 0, 0);
        }
    }

    if (mode == 2) {
        float* dst = outF + (size_t)kz * M * N;
        #pragma unroll
        for (int j = 0; j < 4; j++) {
            int col = n0 + wn + j * 16 + fr;
            #pragma unroll
            for (int i = 0; i < 4; i++) {
                int rbase = m0 + wm + i * 16 + fq * 4;
                #pragma unroll
                for (int e = 0; e < 4; e++)
                    dst[(size_t)(rbase + e) * N + col] = acc[i][j][e];
            }
        }
        return;
    }
    if (mode == 1) {
        #pragma unroll
        for (int j = 0; j < 4; j++) {
            int col   = n0 + wn + j * 16 + fr;
            int which = (col >= 1536) ? 2 : (col >= 768 ? 1 : 0);
            float sc  = (which == 0) ? QSC : 1.0f;   // fold 0.125*log2e into Q
            int rem   = col - which * 768;
            int hh    = rem >> 6, d = rem & 63;
            #pragma unroll
            for (int i = 0; i < 4; i++) {
                int rbase = m0 + wm + i * 16 + fq * 4;
                #pragma unroll
                for (int e = 0; e < 4; e++) {
                    int row = rbase + e;
                    int b_  = row >> 11, srow = row & 2047;
                    size_t idx = (size_t)which * 3145728 +
                                 ((size_t)(b_ * 12 + hh) * 2048 + srow) * 64 + d;
                    outB[idx] = f2b(acc[i][j][e] * sc);
                }
            }
        }
        return;
    }
    #pragma unroll
    for (int j = 0; j < 4; j++) {
        int col  = n0 + wn + j * 16 + fr;
        float bv = bias ? bias[col] : 0.f;
        #pragma unroll
        for (int i = 0; i < 4; i++) {
            int rbase = m0 + wm + i * 16 + fq * 4;
            #pragma unroll
            for (int e = 0; e < 4; e++) {
                float v = acc[i][j][e] + bv;
                if (relu) v = fmaxf(v, 0.f);
                size_t idx = (size_t)(rbase + e) * N + col;
                if (outF) outF[idx] = v;
                if (outB) outB[idx] = f2b(v);
            }
        }
    }
}

// ---------------- attention partial (kv-split, swizzled LDS) ----------------
// LDS 48KB -> 3 blocks/CU. XOR swizzle: 16B chunk c of row r lives at
// swz16(r,c); scalar elem (r,col) at r*64 + ((col>>3 ^ r&7)<<3 | col&7).
__global__ __launch_bounds__(256) void attn_part(const unsigned short* __restrict__ Qg,
                                                 const unsigned short* __restrict__ Kg,
                                                 const unsigned short* __restrict__ Vg,
                                                 unsigned short* __restrict__ pO,
                                                 float* __restrict__ pL) {
    __shared__ unsigned short Ks[2][4096];
    __shared__ unsigned short Vt[2][4096];
    __shared__ unsigned short Ps[8192];
    const int tid  = threadIdx.x;
    const int lane = tid & 63;
    const int wave = tid >> 6;
    const int fr   = lane & 15;
    const int fq   = lane >> 4;
    const int wm   = wave * 32;
    const int r    = 71 - blockIdx.x;          // longest chunks first
    const int bh   = blockIdx.y;
    int qb = 0;
    for (int q_ = 15; q_ >= 0; --q_) if (r >= chunk_ofs(q_)) { qb = q_; break; }
    const int c     = r - chunk_ofs(qb);
    const int q0    = qb * 128;
    const int tile0 = 4 * c;
    const int ntk   = min(4, 2 * (qb + 1) - 4 * c);
    const int slot  = bh * 72 + r;
    const unsigned short* Qb = Qg + (size_t)bh * 2048 * 64;
    const unsigned short* Kb = Kg + (size_t)bh * 2048 * 64;
    const unsigned short* Vb = Vg + (size_t)bh * 2048 * 64;

    short8 qf[2][2];
    #pragma unroll
    for (int rf = 0; rf < 2; ++rf) {
        const unsigned short* qr = Qb + (size_t)(q0 + wm + rf * 16 + fr) * 64;
        qf[rf][0] = *(const short8*)(qr + fq * 8);
        qf[rf][1] = *(const short8*)(qr + 32 + fq * 8);
    }

    floatx4 o[2][4];
    float l_s[2][4];
    #pragma unroll
    for (int rf = 0; rf < 2; ++rf)
        #pragma unroll
        for (int nt = 0; nt < 4; ++nt)
            #pragma unroll
            for (int e = 0; e < 4; ++e) o[rf][nt][e] = 0.f;
    #pragma unroll
    for (int rf = 0; rf < 2; ++rf)
        #pragma unroll
        for (int e = 0; e < 4; ++e) l_s[rf][e] = 0.f;

    const int c0 = tid, c1 = tid + 256;
    uint4 kr0, kr1, vr0, vr1;

#define LOADT(TG)                                                              \
    {                                                                          \
        int base = (TG) * 64;                                                  \
        kr0 = *(const uint4*)(Kb + (size_t)(base + (c0 >> 3)) * 64 + (c0 & 7) * 8); \
        kr1 = *(const uint4*)(Kb + (size_t)(base + (c1 >> 3)) * 64 + (c1 & 7) * 8); \
        vr0 = *(const uint4*)(Vb + (size_t)(base + (c0 & 63)) * 64 + (c0 >> 6) * 8); \
        vr1 = *(const uint4*)(Vb + (size_t)(base + (c1 & 63)) * 64 + (c1 >> 6) * 8); \
    }
// Vt transposed write: row = (c>>6)*8 + i (so row&7 == i), col = c&63
#define WRITET(BUF)                                                            \
    {                                                                          \
        *(uint4*)&Ks[BUF][swz16(c0 >> 3, c0 & 7)] = kr0;                       \
        *(uint4*)&Ks[BUF][swz16(c1 >> 3, c1 & 7)] = kr1;                       \
        unsigned short t0[8]; *(uint4*)t0 = vr0;                               \
        _Pragma("unroll") for (int i_ = 0; i_ < 8; ++i_)                       \
            Vt[BUF][((c0 >> 6) * 8 + i_) * 64 +                                \
                    (((((c0 >> 3) & 7) ^ i_) << 3) | (c0 & 7))] = t0[i_];      \
        unsigned short t1[8]; *(uint4*)t1 = vr1;                               \
        _Pragma("unroll") for (int i_ = 0; i_ < 8; ++i_)                       \
            Vt[BUF][((c1 >> 6) * 8 + i_) * 64 +                                \
                    (((((c1 >> 3) & 7) ^ i_) << 3) | (c1 & 7))] = t1[i_];      \
    }

    LOADT(tile0);
    WRITET(0);
    __syncthreads();

    for (int kt = 0; kt < ntk; ++kt) {
        const int  tg   = tile0 + kt;
        const int  cur  = kt & 1;
        const bool more = (kt + 1 < ntk);
        if (more) LOADT(tg + 1);

        short8 kf[2][4];
        #pragma unroll
        for (int kc = 0; kc < 2; ++kc)
            #pragma unroll
            for (int nt = 0; nt < 4; ++nt)
                kf[kc][nt] = *(const short8*)&Ks[cur][swz16(nt * 16 + fr, kc * 4 + fq)];

        floatx4 s[2][4];
        #pragma unroll
        for (int rf = 0; rf < 2; ++rf)
            #pragma unroll
            for (int nt = 0; nt < 4; ++nt)
                #pragma unroll
                for (int e = 0; e < 4; ++e) s[rf][nt][e] = 0.f;
        #pragma unroll
        for (int rf = 0; rf < 2; ++rf)
            #pragma unroll
            for (int kc = 0; kc < 2; ++kc)
                #pragma unroll
                for (int nt = 0; nt < 4; ++nt)
                    s[rf][nt] = __builtin_amdgcn_mfma_f32_16x16x32_bf16(qf[rf][kc], kf[kc][nt], s[rf][nt], 0, 0, 0);

        // fixed-base softmax: p = 2^(s-C2); masked -> 0. No max, no rescale.
        const bool need_mask = (tg * 64 + 63) > (q0 + wm);
        #pragma unroll
        for (int rf = 0; rf < 2; ++rf)
            #pragma unroll
            for (int e = 0; e < 4; ++e) {
                const int qrow = q0 + wm + rf * 16 + fq * 4 + e;
                const int prow = wm + rf * 16 + fq * 4 + e;   // LDS row
                float rs = 0.f;
                #pragma unroll
                for (int nt = 0; nt < 4; ++nt) {
                    float v = s[rf][nt][e] - C2;
                    if (need_mask && (tg * 64 + nt * 16 + fr) > qrow) v = -1e30f;
                    float pv = __builtin_amdgcn_exp2f(v);
                    rs += pv;
                    Ps[prow * 64 + (((((nt * 2 + (fr >> 3)) ^ (prow & 7)) & 7) << 3) | (fr & 7))] =
                        (unsigned short)(__float_as_uint(pv) >> 16);  // trunc pack
                }
                rs += __shfl_xor(rs, 1);
                rs += __shfl_xor(rs, 2);
                rs += __shfl_xor(rs, 4);
                rs += __shfl_xor(rs, 8);
                l_s[rf][e] += rs;
            }
        __asm__ volatile("s_waitcnt lgkmcnt(0)" ::: "memory");  // own-wave P RAW

        short8 pf[2][2], vf[2][4];
        #pragma unroll
        for (int rf = 0; rf < 2; ++rf)
            #pragma unroll
            for (int kc = 0; kc < 2; ++kc)
                pf[rf][kc] = *(const short8*)&Ps[swz16(wm + rf * 16 + fr, kc * 4 + fq)];
        #pragma unroll
        for (int kc = 0; kc < 2; ++kc)
            #pragma unroll
            for (int nt = 0; nt < 4; ++nt)
                vf[kc][nt] = *(const short8*)&Vt[cur][swz16(nt * 16 + fr, kc * 4 + fq)];
        #pragma unroll
        for (int rf = 0; rf < 2; ++rf)
            #pragma unroll
            for (int kc = 0; kc < 2; ++kc)
                #pragma unroll
                for (int nt = 0; nt < 4; ++nt)
                    o[rf][nt] = __builtin_amdgcn_mfma_f32_16x16x32_bf16(pf[rf][kc], vf[kc][nt], o[rf][nt], 0, 0, 0);

        if (more) {
            WRITET(cur ^ 1);
            __syncthreads();
        }
    }
#undef LOADT
#undef WRITET

    #pragma unroll
    for (int rf = 0; rf < 2; ++rf)
        #pragma unroll
        for (int e = 0; e < 4; ++e) {
            int row = wm + rf * 16 + fq * 4 + e;
            unsigned short* orow = pO + ((size_t)slot * 128 + row) * 64;
            #pragma unroll
            for (int nt = 0; nt < 4; ++nt)
                orow[nt * 16 + fr] = f2b(o[rf][nt][e]);
            if (fr == 0)
                pL[(size_t)slot * 128 + row] = l_s[rf][e];
        }
}

// ---------------- attention combine (fixed base: plain sums) ----------------
__global__ __launch_bounds__(256) void attn_combine(const unsigned short* __restrict__ pO,
                                                    const float* __restrict__ pL,
                                                    unsigned short* __restrict__ ctx) {
    const int qb  = blockIdx.x;
    const int bh  = blockIdx.y;
    const int b   = bh / 12, h = bh % 12;
    const int nch = (qb + 2) >> 1;
    const int slot0 = bh * 72 + chunk_ofs(qb);
    const int tid = threadIdx.x;
    const int row = tid >> 1;
    const int col0 = (tid & 1) * 32;

    float L = 0.f;
    for (int i = 0; i < nch; ++i)
        L += pL[(size_t)(slot0 + i) * 128 + row];

    float acc[32];
    #pragma unroll
    for (int j = 0; j < 32; ++j) acc[j] = 0.f;
    for (int i = 0; i < nch; ++i) {
        const unsigned short* p = pO + ((size_t)(slot0 + i) * 128 + row) * 64 + col0;
        #pragma unroll
        for (int v4 = 0; v4 < 4; ++v4) {
            uint4 u = *(const uint4*)(p + v4 * 8);
            unsigned short t[8]; *(uint4*)t = u;
            #pragma unroll
            for (int j = 0; j < 8; ++j) acc[v4 * 8 + j] += b2f(t[j]);
        }
    }
    float inv = 1.f / L;
    unsigned short* orow = ctx + ((size_t)(b * 2048 + qb * 128 + row)) * 768 + h * 64 + col0;
    #pragma unroll
    for (int v4 = 0; v4 < 4; ++v4) {
        unsigned short t[8];
        #pragma unroll
        for (int j = 0; j < 8; ++j) t[j] = f2b(acc[v4 * 8 + j] * inv);
        *(uint4*)(orow + v4 * 8) = *(uint4*)t;
    }
}

// ---------------- fused split-K reduce + bias + residual + LayerNorm --------
__global__ __launch_bounds__(256) void resid_ln2(const float* __restrict__ X,
                                                 const float* __restrict__ P,
                                                 int nsplit,
                                                 const float* __restrict__ bv,
                                                 const float* __restrict__ gain,
                                                 const float* __restrict__ beta,
                                                 float* __restrict__ outF,
                                                 unsigned short* __restrict__ outB) {
    const int row = blockIdx.x;
    const int t   = threadIdx.x;
    const size_t off = (size_t)row * 768;
    float v[3];
    #pragma unroll
    for (int i = 0; i < 3; i++) {
        size_t c = off + t + i * 256;
        float r = X[c] + bv[t + i * 256];
        for (int p = 0; p < nsplit; ++p) r += P[(size_t)p * 3145728 + c];
        v[i] = r;
    }
    float s  = v[0] + v[1] + v[2];
    float s2 = v[0] * v[0] + v[1] * v[1] + v[2] * v[2];
    #pragma unroll
    for (int o2 = 32; o2 > 0; o2 >>= 1) {
        s  += __shfl_down(s,  o2);
        s2 += __shfl_down(s2, o2);
    }
    __shared__ float rs[4], rq[4];
    if ((t & 63) == 0) { rs[t >> 6] = s; rq[t >> 6] = s2; }
    __syncthreads();
    float S    = rs[0] + rs[1] + rs[2] + rs[3];
    float S2   = rq[0] + rq[1] + rq[2] + rq[3];
    float mean = S * (1.0f / 768.0f);
    float var  = S2 * (1.0f / 768.0f) - mean * mean;
    float inv  = rsqrtf(var + 1e-5f);
    #pragma unroll
    for (int i = 0; i < 3; i++) {
        int c   = t + i * 256;
        float y = gain[c] * (v[i] - mean) * inv + beta[c];
        if (outF) outF[off + c] = y;
        if (outB) outB[off + c] = f2b(y);
    }
}

// ---------------------------------------------------------------------------
extern "C" void kernel_launch(void* const* d_in, const int* in_sizes, int n_in,
                              void* d_out, int out_size, void* d_ws, size_t ws_size,
                              hipStream_t stream) {
    const float* x    = (const float*)d_in[0];
    const float* Wqkv = (const float*)d_in[1];
    const float* Wout = (const float*)d_in[2];
    const float* bout = (const float*)d_in[3];
    const float* W1   = (const float*)d_in[4];
    const float* b1   = (const float*)d_in[5];
    const float* W2   = (const float*)d_in[6];
    const float* b2   = (const float*)d_in[7];
    const float* g1   = (const float*)d_in[8];
    const float* be1  = (const float*)d_in[9];
    const float* g2   = (const float*)d_in[10];
    const float* be2  = (const float*)d_in[11];
    float* out = (float*)d_out;

    // workspace layout (bytes), liveness-aliased; peak 83,361,792
    char* ws = (char*)d_ws;
    unsigned short* wqkvT  = (unsigned short*)(ws + 0);         // 3.5M  ->QKV
    unsigned short* woutT  = (unsigned short*)(ws + 3538944);   // 1.2M  ->Wout
    unsigned short* w1T    = (unsigned short*)(ws + 4718592);   // 4.7M  ->W1
    unsigned short* w2T    = (unsigned short*)(ws + 9437184);   // 4.7M  ->W2
    unsigned short* xb     = (unsigned short*)(ws + 14155776);  // 6.3M  ->QKV
    unsigned short* qkvG   = (unsigned short*)(ws + 20447232);  // 18.9M ->attn_part
    unsigned short* Qg     = qkvG;
    unsigned short* Kg     = qkvG + 3145728;
    unsigned short* Vg     = qkvG + 6291456;
    unsigned short* pO     = (unsigned short*)(ws + 39321600);  // 28.3M ->combine
    float*          pL     = (float*)(ws + 67633152);           // 0.9M  ->combine
    unsigned short* ctxb   = (unsigned short*)(ws + 14155776);  // 6.3M  combine->Wout (xb dead)
    float*          WoutP  = (float*)(ws + 39321600);           // 3x12.6M Wout->LN1; ends 77,070,336
    float*          h      = (float*)(ws + 20447232);           // 12.6M LN1->LN2 (qkvG dead)
    unsigned short* hb     = (unsigned short*)(ws + 77070336);  // 6.3M  LN1->W1; ends 83,361,792
    unsigned short* ffb    = (unsigned short*)(ws + 39321600);  // 25.2M W1->W2 (WoutP dead)
    float*          W2P    = (float*)(ws + 64487424);           // 2x12.6M W2->LN2; ends 77,070,336

    // 1) fused prepass
    prep_all<<<9984, 256, 0, stream>>>(x, xb, Wqkv, wqkvT, Wout, woutT, W1, w1T, W2, w2T);
    // 2) QKV projection -> Q/K/V [bh][s][64] bf16 (Q pre-scaled by QSC)
    gemm_bf16<<<dim3(18, 32), 256, 0, stream>>>(xb, wqkvT, nullptr, nullptr, qkvG,
                                                4096, 2304, 768, 0, 1, 768);
    // 3) kv-split flash attention + combine -> ctx bf16
    attn_part<<<dim3(72, 24), 256, 0, stream>>>(Qg, Kg, Vg, pO, pL);
    attn_combine<<<dim3(16, 24), 256, 0, stream>>>(pO, pL, ctxb);
    // 4) out projection, split-K=3 -> fp32 partials
    gemm_bf16<<<dim3(6, 32, 3), 256, 0, stream>>>(ctxb, woutT, nullptr, WoutP, nullptr,
                                                  4096, 768, 768, 0, 2, 256);
    // 5) h = LN(x + sum(WoutP) + bout) -> fp32 + bf16
    resid_ln2<<<4096, 256, 0, stream>>>(x, WoutP, 3, bout, g1, be1, h, hb);
    // 6) ff = relu(h @ W1 + b1) -> bf16
    gemm_bf16<<<dim3(24, 32), 256, 0, stream>>>(hb, w1T, b1, nullptr, ffb,
                                                4096, 3072, 768, 1, 0, 768);
    // 7) ff2 partials = ff @ W2 (split-K=2)
    gemm_bf16<<<dim3(6, 32, 2), 256, 0, stream>>>(ffb, w2T, nullptr, W2P, nullptr,
                                                  4096, 768, 3072, 0, 2, 1536);
    // 8) out = LN(h + sum(W2P) + b2) -> fp32
    resid_ln2<<<4096, 256, 0, stream>>>(h, W2P, 2, b2, g2, be2, out, nullptr);
}

// Round 9
// 322.445 us; speedup vs baseline: 8.3406x; 1.0221x over previous
//
#include <hip/hip_runtime.h>

// ---------------------------------------------------------------------------
// TransformerBlock: B=2,S=2048,D=768,H=12,DH=64,DFF=3072, causal attn, 2x LN
// Round 9: attn_part VALU-stream diet: (1) row-sum l via MFMA-with-ones
// (replaces 32 shfl + 64 add per tile), (2) Ps back to affine stride-72
// addressing (XOR swizzle only on Ks/Vt where it measured 0 conflicts),
// (3) wave-uniform mask-tile test skips cndmask on fully-visible fragments.
// GEMM BK=64, fixed-base softmax, split-K plumbing unchanged.
// ---------------------------------------------------------------------------

typedef __attribute__((ext_vector_type(8))) short  short8;   // 8 x bf16 (4 VGPR)
typedef __attribute__((ext_vector_type(4))) float  floatx4;  // 4 x f32 acc

#define QSC 0.18033688f   // 0.125 * log2(e): folded into Q at scatter
#define C2  24.0f         // fixed base-2 softmax offset

__device__ __forceinline__ float b2f(unsigned short u) {
    return __uint_as_float(((unsigned)u) << 16);
}
__device__ __forceinline__ unsigned short f2b(float f) {  // RNE
    unsigned x = __float_as_uint(f);
    return (unsigned short)((x + 0x7fffu + ((x >> 16) & 1u)) >> 16);
}
__device__ __forceinline__ void async_cp16(const void* g, void* l) {
    __builtin_amdgcn_global_load_lds((const __attribute__((address_space(1))) void*)g,
                                     (__attribute__((address_space(3))) void*)l,
                                     16, 0, 0);
}
__device__ __forceinline__ int chunk_ofs(int qb) {
    int t = qb >> 1;
    return (qb & 1) ? (t + 1) * (t + 1) : t * (t + 1);
}
// XOR-swizzled [R][64] bf16 tile: elem offset of 16B chunk `chunk` in row `row`
__device__ __forceinline__ int swz16(int row, int chunk) {
    return row * 64 + (((chunk ^ (row & 7)) & 7) << 3);
}

// ---------------- fused prepass: x->bf16 + 4 weight transposes --------------
__global__ __launch_bounds__(256) void prep_all(
    const float* __restrict__ x,    unsigned short* __restrict__ xb,
    const float* __restrict__ Wqkv, unsigned short* __restrict__ wqkvT,
    const float* __restrict__ Wout, unsigned short* __restrict__ woutT,
    const float* __restrict__ W1,   unsigned short* __restrict__ w1T,
    const float* __restrict__ W2,   unsigned short* __restrict__ w2T)
{
    __shared__ float tile[32][33];
    int idx = blockIdx.x;
    int tx = threadIdx.x & 31, ty = threadIdx.x >> 5;
    if (idx >= 6912) {  // cvt x
        int i = (idx - 6912) * 256 + threadIdx.x;
        float4 v = ((const float4*)x)[i];
        ushort4 u;
        u.x = f2b(v.x); u.y = f2b(v.y); u.z = f2b(v.z); u.w = f2b(v.w);
        ((ushort4*)xb)[i] = u;
        return;
    }
    const float* W; unsigned short* Wt; int K, N, bx, by;
    if (idx < 1728)      { W = Wqkv; Wt = wqkvT; K = 768;  N = 2304; bx = idx % 72;        by = idx / 72; }
    else if (idx < 2304) { W = Wout; Wt = woutT; K = 768;  N = 768;  bx = (idx-1728) % 24; by = (idx-1728) / 24; }
    else if (idx < 4608) { W = W1;   Wt = w1T;   K = 768;  N = 3072; bx = (idx-2304) % 96; by = (idx-2304) / 96; }
    else                 { W = W2;   Wt = w2T;   K = 3072; N = 768;  bx = (idx-4608) % 24; by = (idx-4608) / 24; }
    int n0 = bx * 32, k0 = by * 32;
    for (int i = ty; i < 32; i += 8)
        tile[i][tx] = W[(size_t)(k0 + i) * N + n0 + tx];
    __syncthreads();
    for (int i = ty; i < 32; i += 8)
        Wt[(size_t)(n0 + i) * K + k0 + tx] = f2b(tile[tx][i]);
}

// ---------------- bf16 MFMA GEMM (BK=64) -------------------------------------
// mode 0: row-major outF/outB (+bias, relu)
// mode 1: qkv scatter -> outB = Q|K|V each [24][2048][64]; Q scaled by QSC
// mode 2: split-K fp32 partial -> outF + blockIdx.z*M*N
__global__ __launch_bounds__(256) void gemm_bf16(
    const unsigned short* __restrict__ A,
    const unsigned short* __restrict__ Bt,
    const float* __restrict__ bias,
    float* __restrict__ outF,
    unsigned short* __restrict__ outB,
    int M, int N, int K, int relu, int mode, int kslab)
{
    __shared__ unsigned short As[128][64];
    __shared__ unsigned short Bs[128][64];
    const int tid  = threadIdx.x;
    const int m0   = blockIdx.y * 128;
    const int n0   = blockIdx.x * 128;
    const int kz   = blockIdx.z;
    const int kbeg = kz * kslab;
    const int kend = kbeg + kslab;
    const int lane = tid & 63;
    const int wave = tid >> 6;
    const int wm   = (wave >> 1) * 64;
    const int wn   = (wave & 1) * 64;
    const int fr   = lane & 15;
    const int fq   = lane >> 4;

    floatx4 acc[4][4];
    for (int i = 0; i < 4; i++)
        for (int j = 0; j < 4; j++)
            for (int e = 0; e < 4; e++) acc[i][j][e] = 0.f;

    for (int kk = kbeg; kk < kend; kk += 64) {
        __syncthreads();
        #pragma unroll
        for (int r = 0; r < 4; ++r) {
            int c    = r * 256 + tid;
            int row  = c >> 3;
            int colb = (c & 7) * 8;
            async_cp16(A  + (size_t)(m0 + row) * K + kk + colb, &As[row][colb]);
            async_cp16(Bt + (size_t)(n0 + row) * K + kk + colb, &Bs[row][colb]);
        }
        __syncthreads();

        #pragma unroll
        for (int kc = 0; kc < 2; ++kc) {
            short8 a[4], b[4];
            #pragma unroll
            for (int t = 0; t < 4; t++) a[t] = *(const short8*)&As[wm + t * 16 + fr][kc * 32 + fq * 8];
            #pragma unroll
            for (int t = 0; t < 4; t++) b[t] = *(const short8*)&Bs[wn + t * 16 + fr][kc * 32 + fq * 8];
            #pragma unroll
            for (int i = 0; i < 4; i++)
                #pragma unroll
                for (int j = 0; j < 4; j++)
                    acc[i][j] = __builtin_amdgcn_mfma_f32_16x16x32_bf16(a[i], b[j], acc[i][j], 0, 0, 0);
        }
    }

    if (mode == 2) {
        float* dst = outF + (size_t)kz * M * N;
        #pragma unroll
        for (int j = 0; j < 4; j++) {
            int col = n0 + wn + j * 16 + fr;
            #pragma unroll
            for (int i = 0; i < 4; i++) {
                int rbase = m0 + wm + i * 16 + fq * 4;
                #pragma unroll
                for (int e = 0; e < 4; e++)
                    dst[(size_t)(rbase + e) * N + col] = acc[i][j][e];
            }
        }
        return;
    }
    if (mode == 1) {
        #pragma unroll
        for (int j = 0; j < 4; j++) {
            int col   = n0 + wn + j * 16 + fr;
            int which = (col >= 1536) ? 2 : (col >= 768 ? 1 : 0);
            float sc  = (which == 0) ? QSC : 1.0f;   // fold 0.125*log2e into Q
            int rem   = col - which * 768;
            int hh    = rem >> 6, d = rem & 63;
            #pragma unroll
            for (int i = 0; i < 4; i++) {
                int rbase = m0 + wm + i * 16 + fq * 4;
                #pragma unroll
                for (int e = 0; e < 4; e++) {
                    int row = rbase + e;
                    int b_  = row >> 11, srow = row & 2047;
                    size_t idx = (size_t)which * 3145728 +
                                 ((size_t)(b_ * 12 + hh) * 2048 + srow) * 64 + d;
                    outB[idx] = f2b(acc[i][j][e] * sc);
                }
            }
        }
        return;
    }
    #pragma unroll
    for (int j = 0; j < 4; j++) {
        int col  = n0 + wn + j * 16 + fr;
        float bv = bias ? bias[col] : 0.f;
        #pragma unroll
        for (int i = 0; i < 4; i++) {
            int rbase = m0 + wm + i * 16 + fq * 4;
            #pragma unroll
            for (int e = 0; e < 4; e++) {
                float v = acc[i][j][e] + bv;
                if (relu) v = fmaxf(v, 0.f);
                size_t idx = (size_t)(rbase + e) * N + col;
                if (outF) outF[idx] = v;
                if (outB) outB[idx] = f2b(v);
            }
        }
    }
}

// ---------------- attention partial (kv-split, lean softmax) ----------------
// Ks/Vt XOR-swizzled (0 conflicts, R8-verified); Ps padded stride-72 (affine
// addresses). l computed by MFMA with all-ones B fragment. LDS 51.2KB.
__global__ __launch_bounds__(256) void attn_part(const unsigned short* __restrict__ Qg,
                                                 const unsigned short* __restrict__ Kg,
                                                 const unsigned short* __restrict__ Vg,
                                                 unsigned short* __restrict__ pO,
                                                 float* __restrict__ pL) {
    __shared__ unsigned short Ks[2][4096];
    __shared__ unsigned short Vt[2][4096];
    __shared__ unsigned short Ps[128 * 72];
    const int tid  = threadIdx.x;
    const int lane = tid & 63;
    const int wave = tid >> 6;
    const int fr   = lane & 15;
    const int fq   = lane >> 4;
    const int wm   = wave * 32;
    const int r    = 71 - blockIdx.x;          // longest chunks first
    const int bh   = blockIdx.y;
    int qb = 0;
    for (int q_ = 15; q_ >= 0; --q_) if (r >= chunk_ofs(q_)) { qb = q_; break; }
    const int c     = r - chunk_ofs(qb);
    const int q0    = qb * 128;
    const int tile0 = 4 * c;
    const int ntk   = min(4, 2 * (qb + 1) - 4 * c);
    const int slot  = bh * 72 + r;
    const unsigned short* Qb = Qg + (size_t)bh * 2048 * 64;
    const unsigned short* Kb = Kg + (size_t)bh * 2048 * 64;
    const unsigned short* Vb = Vg + (size_t)bh * 2048 * 64;

    short8 qf[2][2];
    #pragma unroll
    for (int rf = 0; rf < 2; ++rf) {
        const unsigned short* qr = Qb + (size_t)(q0 + wm + rf * 16 + fr) * 64;
        qf[rf][0] = *(const short8*)(qr + fq * 8);
        qf[rf][1] = *(const short8*)(qr + 32 + fq * 8);
    }

    // all-ones bf16 B fragment for row-sum MFMA
    short8 onesf;
    #pragma unroll
    for (int i = 0; i < 8; ++i) onesf[i] = (short)0x3F80;

    floatx4 o[2][4];
    floatx4 lacc[2];
    #pragma unroll
    for (int rf = 0; rf < 2; ++rf) {
        #pragma unroll
        for (int nt = 0; nt < 4; ++nt)
            #pragma unroll
            for (int e = 0; e < 4; ++e) o[rf][nt][e] = 0.f;
        #pragma unroll
        for (int e = 0; e < 4; ++e) lacc[rf][e] = 0.f;
    }

    const int c0 = tid, c1 = tid + 256;
    uint4 kr0, kr1, vr0, vr1;

#define LOADT(TG)                                                              \
    {                                                                          \
        int base = (TG) * 64;                                                  \
        kr0 = *(const uint4*)(Kb + (size_t)(base + (c0 >> 3)) * 64 + (c0 & 7) * 8); \
        kr1 = *(const uint4*)(Kb + (size_t)(base + (c1 >> 3)) * 64 + (c1 & 7) * 8); \
        vr0 = *(const uint4*)(Vb + (size_t)(base + (c0 & 63)) * 64 + (c0 >> 6) * 8); \
        vr1 = *(const uint4*)(Vb + (size_t)(base + (c1 & 63)) * 64 + (c1 >> 6) * 8); \
    }
// Vt transposed write: row = (c>>6)*8 + i (so row&7 == i), col = c&63
#define WRITET(BUF)                                                            \
    {                                                                          \
        *(uint4*)&Ks[BUF][swz16(c0 >> 3, c0 & 7)] = kr0;                       \
        *(uint4*)&Ks[BUF][swz16(c1 >> 3, c1 & 7)] = kr1;                       \
        unsigned short t0[8]; *(uint4*)t0 = vr0;                               \
        _Pragma("unroll") for (int i_ = 0; i_ < 8; ++i_)                       \
            Vt[BUF][((c0 >> 6) * 8 + i_) * 64 +                                \
                    (((((c0 >> 3) & 7) ^ i_) << 3) | (c0 & 7))] = t0[i_];      \
        unsigned short t1[8]; *(uint4*)t1 = vr1;                               \
        _Pragma("unroll") for (int i_ = 0; i_ < 8; ++i_)                       \
            Vt[BUF][((c1 >> 6) * 8 + i_) * 64 +                                \
                    (((((c1 >> 3) & 7) ^ i_) << 3) | (c1 & 7))] = t1[i_];      \
    }

    LOADT(tile0);
    WRITET(0);
    __syncthreads();

    for (int kt = 0; kt < ntk; ++kt) {
        const int  tg   = tile0 + kt;
        const int  cur  = kt & 1;
        const bool more = (kt + 1 < ntk);
        if (more) LOADT(tg + 1);

        short8 kf[2][4];
        #pragma unroll
        for (int kc = 0; kc < 2; ++kc)
            #pragma unroll
            for (int nt = 0; nt < 4; ++nt)
                kf[kc][nt] = *(const short8*)&Ks[cur][swz16(nt * 16 + fr, kc * 4 + fq)];

        floatx4 s[2][4];
        #pragma unroll
        for (int rf = 0; rf < 2; ++rf)
            #pragma unroll
            for (int nt = 0; nt < 4; ++nt)
                #pragma unroll
                for (int e = 0; e < 4; ++e) s[rf][nt][e] = 0.f;
        #pragma unroll
        for (int rf = 0; rf < 2; ++rf)
            #pragma unroll
            for (int kc = 0; kc < 2; ++kc)
                #pragma unroll
                for (int nt = 0; nt < 4; ++nt)
                    s[rf][nt] = __builtin_amdgcn_mfma_f32_16x16x32_bf16(qf[rf][kc], kf[kc][nt], s[rf][nt], 0, 0, 0);

        // fixed-base softmax: p = 2^(s-C2); masked -> 0. No max, no rescale,
        // no row-sum here (l comes from MFMA-with-ones below).
        const bool need_mask = (tg * 64 + 63) > (q0 + wm);
        #pragma unroll
        for (int rf = 0; rf < 2; ++rf) {
            const int rmin  = q0 + wm + rf * 16;           // min q-row of frag
            const int pbase = (wm + rf * 16 + fq * 4) * 72 + fr;
            #pragma unroll
            for (int nt = 0; nt < 4; ++nt) {
                const bool tmask = need_mask && (tg * 64 + nt * 16 + 15 > rmin);
                const int  kvc   = tg * 64 + nt * 16 + fr;  // this lane's kv col
                #pragma unroll
                for (int e = 0; e < 4; ++e) {
                    float v = s[rf][nt][e] - C2;
                    if (tmask && kvc > rmin + fq * 4 + e) v = -1e30f;
                    float pv = __builtin_amdgcn_exp2f(v);
                    Ps[pbase + e * 72 + nt * 16] =
                        (unsigned short)(__float_as_uint(pv) >> 16);  // trunc
                }
            }
        }
        __asm__ volatile("s_waitcnt lgkmcnt(0)" ::: "memory");  // own-wave P RAW

        short8 pf[2][2], vf[2][4];
        #pragma unroll
        for (int rf = 0; rf < 2; ++rf)
            #pragma unroll
            for (int kc = 0; kc < 2; ++kc)
                pf[rf][kc] = *(const short8*)&Ps[(wm + rf * 16 + fr) * 72 + kc * 32 + fq * 8];
        #pragma unroll
        for (int kc = 0; kc < 2; ++kc)
            #pragma unroll
            for (int nt = 0; nt < 4; ++nt)
                vf[kc][nt] = *(const short8*)&Vt[cur][swz16(nt * 16 + fr, kc * 4 + fq)];
        #pragma unroll
        for (int rf = 0; rf < 2; ++rf)
            #pragma unroll
            for (int kc = 0; kc < 2; ++kc) {
                lacc[rf] = __builtin_amdgcn_mfma_f32_16x16x32_bf16(pf[rf][kc], onesf, lacc[rf], 0, 0, 0);
                #pragma unroll
                for (int nt = 0; nt < 4; ++nt)
                    o[rf][nt] = __builtin_amdgcn_mfma_f32_16x16x32_bf16(pf[rf][kc], vf[kc][nt], o[rf][nt], 0, 0, 0);
            }

        if (more) {
            WRITET(cur ^ 1);
            __syncthreads();
        }
    }
#undef LOADT
#undef WRITET

    #pragma unroll
    for (int rf = 0; rf < 2; ++rf)
        #pragma unroll
        for (int e = 0; e < 4; ++e) {
            int row = wm + rf * 16 + fq * 4 + e;
            unsigned short* orow = pO + ((size_t)slot * 128 + row) * 64;
            #pragma unroll
            for (int nt = 0; nt < 4; ++nt)
                orow[nt * 16 + fr] = f2b(o[rf][nt][e]);
            if (fr == 0)
                pL[(size_t)slot * 128 + row] = lacc[rf][e];
        }
}

// ---------------- attention combine (fixed base: plain sums) ----------------
__global__ __launch_bounds__(256) void attn_combine(const unsigned short* __restrict__ pO,
                                                    const float* __restrict__ pL,
                                                    unsigned short* __restrict__ ctx) {
    const int qb  = blockIdx.x;
    const int bh  = blockIdx.y;
    const int b   = bh / 12, h = bh % 12;
    const int nch = (qb + 2) >> 1;
    const int slot0 = bh * 72 + chunk_ofs(qb);
    const int tid = threadIdx.x;
    const int row = tid >> 1;
    const int col0 = (tid & 1) * 32;

    float L = 0.f;
    for (int i = 0; i < nch; ++i)
        L += pL[(size_t)(slot0 + i) * 128 + row];

    float acc[32];
    #pragma unroll
    for (int j = 0; j < 32; ++j) acc[j] = 0.f;
    for (int i = 0; i < nch; ++i) {
        const unsigned short* p = pO + ((size_t)(slot0 + i) * 128 + row) * 64 + col0;
        #pragma unroll
        for (int v4 = 0; v4 < 4; ++v4) {
            uint4 u = *(const uint4*)(p + v4 * 8);
            unsigned short t[8]; *(uint4*)t = u;
            #pragma unroll
            for (int j = 0; j < 8; ++j) acc[v4 * 8 + j] += b2f(t[j]);
        }
    }
    float inv = 1.f / L;
    unsigned short* orow = ctx + ((size_t)(b * 2048 + qb * 128 + row)) * 768 + h * 64 + col0;
    #pragma unroll
    for (int v4 = 0; v4 < 4; ++v4) {
        unsigned short t[8];
        #pragma unroll
        for (int j = 0; j < 8; ++j) t[j] = f2b(acc[v4 * 8 + j] * inv);
        *(uint4*)(orow + v4 * 8) = *(uint4*)t;
    }
}

// ---------------- fused split-K reduce + bias + residual + LayerNorm --------
__global__ __launch_bounds__(256) void resid_ln2(const float* __restrict__ X,
                                                 const float* __restrict__ P,
                                                 int nsplit,
                                                 const float* __restrict__ bv,
                                                 const float* __restrict__ gain,
                                                 const float* __restrict__ beta,
                                                 float* __restrict__ outF,
                                                 unsigned short* __restrict__ outB) {
    const int row = blockIdx.x;
    const int t   = threadIdx.x;
    const size_t off = (size_t)row * 768;
    float v[3];
    #pragma unroll
    for (int i = 0; i < 3; i++) {
        size_t c = off + t + i * 256;
        float r = X[c] + bv[t + i * 256];
        for (int p = 0; p < nsplit; ++p) r += P[(size_t)p * 3145728 + c];
        v[i] = r;
    }
    float s  = v[0] + v[1] + v[2];
    float s2 = v[0] * v[0] + v[1] * v[1] + v[2] * v[2];
    #pragma unroll
    for (int o2 = 32; o2 > 0; o2 >>= 1) {
        s  += __shfl_down(s,  o2);
        s2 += __shfl_down(s2, o2);
    }
    __shared__ float rs[4], rq[4];
    if ((t & 63) == 0) { rs[t >> 6] = s; rq[t >> 6] = s2; }
    __syncthreads();
    float S    = rs[0] + rs[1] + rs[2] + rs[3];
    float S2   = rq[0] + rq[1] + rq[2] + rq[3];
    float mean = S * (1.0f / 768.0f);
    float var  = S2 * (1.0f / 768.0f) - mean * mean;
    float inv  = rsqrtf(var + 1e-5f);
    #pragma unroll
    for (int i = 0; i < 3; i++) {
        int c   = t + i * 256;
        float y = gain[c] * (v[i] - mean) * inv + beta[c];
        if (outF) outF[off + c] = y;
        if (outB) outB[off + c] = f2b(y);
    }
}

// ---------------------------------------------------------------------------
extern "C" void kernel_launch(void* const* d_in, const int* in_sizes, int n_in,
                              void* d_out, int out_size, void* d_ws, size_t ws_size,
                              hipStream_t stream) {
    const float* x    = (const float*)d_in[0];
    const float* Wqkv = (const float*)d_in[1];
    const float* Wout = (const float*)d_in[2];
    const float* bout = (const float*)d_in[3];
    const float* W1   = (const float*)d_in[4];
    const float* b1   = (const float*)d_in[5];
    const float* W2   = (const float*)d_in[6];
    const float* b2   = (const float*)d_in[7];
    const float* g1   = (const float*)d_in[8];
    const float* be1  = (const float*)d_in[9];
    const float* g2   = (const float*)d_in[10];
    const float* be2  = (const float*)d_in[11];
    float* out = (float*)d_out;

    // workspace layout (bytes), liveness-aliased; peak 83,361,792
    char* ws = (char*)d_ws;
    unsigned short* wqkvT  = (unsigned short*)(ws + 0);         // 3.5M  ->QKV
    unsigned short* woutT  = (unsigned short*)(ws + 3538944);   // 1.2M  ->Wout
    unsigned short* w1T    = (unsigned short*)(ws + 4718592);   // 4.7M  ->W1
    unsigned short* w2T    = (unsigned short*)(ws + 9437184);   // 4.7M  ->W2
    unsigned short* xb     = (unsigned short*)(ws + 14155776);  // 6.3M  ->QKV
    unsigned short* qkvG   = (unsigned short*)(ws + 20447232);  // 18.9M ->attn_part
    unsigned short* Qg     = qkvG;
    unsigned short* Kg     = qkvG + 3145728;
    unsigned short* Vg     = qkvG + 6291456;
    unsigned short* pO     = (unsigned short*)(ws + 39321600);  // 28.3M ->combine
    float*          pL     = (float*)(ws + 67633152);           // 0.9M  ->combine
    unsigned short* ctxb   = (unsigned short*)(ws + 14155776);  // 6.3M  combine->Wout (xb dead)
    float*          WoutP  = (float*)(ws + 39321600);           // 3x12.6M Wout->LN1; ends 77,070,336
    float*          h      = (float*)(ws + 20447232);           // 12.6M LN1->LN2 (qkvG dead)
    unsigned short* hb     = (unsigned short*)(ws + 77070336);  // 6.3M  LN1->W1; ends 83,361,792
    unsigned short* ffb    = (unsigned short*)(ws + 39321600);  // 25.2M W1->W2 (WoutP dead)
    float*          W2P    = (float*)(ws + 64487424);           // 2x12.6M W2->LN2; ends 77,070,336

    // 1) fused prepass
    prep_all<<<9984, 256, 0, stream>>>(x, xb, Wqkv, wqkvT, Wout, woutT, W1, w1T, W2, w2T);
    // 2) QKV projection -> Q/K/V [bh][s][64] bf16 (Q pre-scaled by QSC)
    gemm_bf16<<<dim3(18, 32), 256, 0, stream>>>(xb, wqkvT, nullptr, nullptr, qkvG,
                                                4096, 2304, 768, 0, 1, 768);
    // 3) kv-split flash attention + combine -> ctx bf16
    attn_part<<<dim3(72, 24), 256, 0, stream>>>(Qg, Kg, Vg, pO, pL);
    attn_combine<<<dim3(16, 24), 256, 0, stream>>>(pO, pL, ctxb);
    // 4) out projection, split-K=3 -> fp32 partials
    gemm_bf16<<<dim3(6, 32, 3), 256, 0, stream>>>(ctxb, woutT, nullptr, WoutP, nullptr,
                                                  4096, 768, 768, 0, 2, 256);
    // 5) h = LN(x + sum(WoutP) + bout) -> fp32 + bf16
    resid_ln2<<<4096, 256, 0, stream>>>(x, WoutP, 3, bout, g1, be1, h, hb);
    // 6) ff = relu(h @ W1 + b1) -> bf16
    gemm_bf16<<<dim3(24, 32), 256, 0, stream>>>(hb, w1T, b1, nullptr, ffb,
                                                4096, 3072, 768, 1, 0, 768);
    // 7) ff2 partials = ff @ W2 (split-K=2)
    gemm_bf16<<<dim3(6, 32, 2), 256, 0, stream>>>(ffb, w2T, nullptr, W2P, nullptr,
                                                  4096, 768, 3072, 0, 2, 1536);
    // 8) out = LN(h + sum(W2P) + b2) -> fp32
    resid_ln2<<<4096, 256, 0, stream>>>(h, W2P, 2, b2, g2, be2, out, nullptr);
}

// Round 10
// 308.087 us; speedup vs baseline: 8.7293x; 1.0466x over previous
//
#include <hip/hip_runtime.h>

// ---------------------------------------------------------------------------
// TransformerBlock: B=2,S=2048,D=768,H=12,DH=64,DFF=3072, causal attn, 2x LN
// Round 10: GEMM LDS bank-conflict fix. BK=64 tile [128][64] has 128B row
// stride -> every row on identical banks -> 16-way conflict on b128 fragment
// reads (SQ_LDS_BANK_CONFLICT 7.08M). Fix: XOR-swizzle via staging SOURCE
// permutation (global_load_lds dest must stay lane-contiguous), fragment
// reads via swz16 (R8-verified 0 conflicts in attn). Attention unchanged.
// ---------------------------------------------------------------------------

typedef __attribute__((ext_vector_type(8))) short  short8;   // 8 x bf16 (4 VGPR)
typedef __attribute__((ext_vector_type(4))) float  floatx4;  // 4 x f32 acc

#define QSC 0.18033688f   // 0.125 * log2(e): folded into Q at scatter
#define C2  24.0f         // fixed base-2 softmax offset

__device__ __forceinline__ float b2f(unsigned short u) {
    return __uint_as_float(((unsigned)u) << 16);
}
__device__ __forceinline__ unsigned short f2b(float f) {  // RNE
    unsigned x = __float_as_uint(f);
    return (unsigned short)((x + 0x7fffu + ((x >> 16) & 1u)) >> 16);
}
__device__ __forceinline__ void async_cp16(const void* g, void* l) {
    __builtin_amdgcn_global_load_lds((const __attribute__((address_space(1))) void*)g,
                                     (__attribute__((address_space(3))) void*)l,
                                     16, 0, 0);
}
__device__ __forceinline__ int chunk_ofs(int qb) {
    int t = qb >> 1;
    return (qb & 1) ? (t + 1) * (t + 1) : t * (t + 1);
}
// XOR-swizzled [R][64] bf16 tile: elem offset of logical 16B chunk `chunk`
__device__ __forceinline__ int swz16(int row, int chunk) {
    return row * 64 + (((chunk ^ (row & 7)) & 7) << 3);
}

// ---------------- fused prepass: x->bf16 + 4 weight transposes --------------
__global__ __launch_bounds__(256) void prep_all(
    const float* __restrict__ x,    unsigned short* __restrict__ xb,
    const float* __restrict__ Wqkv, unsigned short* __restrict__ wqkvT,
    const float* __restrict__ Wout, unsigned short* __restrict__ woutT,
    const float* __restrict__ W1,   unsigned short* __restrict__ w1T,
    const float* __restrict__ W2,   unsigned short* __restrict__ w2T)
{
    __shared__ float tile[32][33];
    int idx = blockIdx.x;
    int tx = threadIdx.x & 31, ty = threadIdx.x >> 5;
    if (idx >= 6912) {  // cvt x
        int i = (idx - 6912) * 256 + threadIdx.x;
        float4 v = ((const float4*)x)[i];
        ushort4 u;
        u.x = f2b(v.x); u.y = f2b(v.y); u.z = f2b(v.z); u.w = f2b(v.w);
        ((ushort4*)xb)[i] = u;
        return;
    }
    const float* W; unsigned short* Wt; int K, N, bx, by;
    if (idx < 1728)      { W = Wqkv; Wt = wqkvT; K = 768;  N = 2304; bx = idx % 72;        by = idx / 72; }
    else if (idx < 2304) { W = Wout; Wt = woutT; K = 768;  N = 768;  bx = (idx-1728) % 24; by = (idx-1728) / 24; }
    else if (idx < 4608) { W = W1;   Wt = w1T;   K = 768;  N = 3072; bx = (idx-2304) % 96; by = (idx-2304) / 96; }
    else                 { W = W2;   Wt = w2T;   K = 3072; N = 768;  bx = (idx-4608) % 24; by = (idx-4608) / 24; }
    int n0 = bx * 32, k0 = by * 32;
    for (int i = ty; i < 32; i += 8)
        tile[i][tx] = W[(size_t)(k0 + i) * N + n0 + tx];
    __syncthreads();
    for (int i = ty; i < 32; i += 8)
        Wt[(size_t)(n0 + i) * K + k0 + tx] = f2b(tile[tx][i]);
}

// ---------------- bf16 MFMA GEMM (BK=64, swizzled LDS) -----------------------
// mode 0: row-major outF/outB (+bias, relu)
// mode 1: qkv scatter -> outB = Q|K|V each [24][2048][64]; Q scaled by QSC
// mode 2: split-K fp32 partial -> outF + blockIdx.z*M*N
__global__ __launch_bounds__(256) void gemm_bf16(
    const unsigned short* __restrict__ A,
    const unsigned short* __restrict__ Bt,
    const float* __restrict__ bias,
    float* __restrict__ outF,
    unsigned short* __restrict__ outB,
    int M, int N, int K, int relu, int mode, int kslab)
{
    __shared__ unsigned short As[8192];   // swizzled [128][64]
    __shared__ unsigned short Bs[8192];
    const int tid  = threadIdx.x;
    const int m0   = blockIdx.y * 128;
    const int n0   = blockIdx.x * 128;
    const int kz   = blockIdx.z;
    const int kbeg = kz * kslab;
    const int kend = kbeg + kslab;
    const int lane = tid & 63;
    const int wave = tid >> 6;
    const int wm   = (wave >> 1) * 64;
    const int wn   = (wave & 1) * 64;
    const int fr   = lane & 15;
    const int fq   = lane >> 4;

    floatx4 acc[4][4];
    for (int i = 0; i < 4; i++)
        for (int j = 0; j < 4; j++)
            for (int e = 0; e < 4; e++) acc[i][j][e] = 0.f;

    for (int kk = kbeg; kk < kend; kk += 64) {
        __syncthreads();
        #pragma unroll
        for (int r = 0; r < 4; ++r) {
            int c   = r * 256 + tid;          // LDS dest chunk (lane-contig)
            int row = c >> 3;
            int jj  = ((c & 7) ^ (row & 7)) * 8;  // swizzled global source col
            async_cp16(A  + (size_t)(m0 + row) * K + kk + jj, &As[c * 8]);
            async_cp16(Bt + (size_t)(n0 + row) * K + kk + jj, &Bs[c * 8]);
        }
        __syncthreads();

        #pragma unroll
        for (int kc = 0; kc < 2; ++kc) {
            short8 a[4], b[4];
            #pragma unroll
            for (int t = 0; t < 4; t++) a[t] = *(const short8*)&As[swz16(wm + t * 16 + fr, kc * 4 + fq)];
            #pragma unroll
            for (int t = 0; t < 4; t++) b[t] = *(const short8*)&Bs[swz16(wn + t * 16 + fr, kc * 4 + fq)];
            #pragma unroll
            for (int i = 0; i < 4; i++)
                #pragma unroll
                for (int j = 0; j < 4; j++)
                    acc[i][j] = __builtin_amdgcn_mfma_f32_16x16x32_bf16(a[i], b[j], acc[i][j], 0, 0, 0);
        }
    }

    if (mode == 2) {
        float* dst = outF + (size_t)kz * M * N;
        #pragma unroll
        for (int j = 0; j < 4; j++) {
            int col = n0 + wn + j * 16 + fr;
            #pragma unroll
            for (int i = 0; i < 4; i++) {
                int rbase = m0 + wm + i * 16 + fq * 4;
                #pragma unroll
                for (int e = 0; e < 4; e++)
                    dst[(size_t)(rbase + e) * N + col] = acc[i][j][e];
            }
        }
        return;
    }
    if (mode == 1) {
        #pragma unroll
        for (int j = 0; j < 4; j++) {
            int col   = n0 + wn + j * 16 + fr;
            int which = (col >= 1536) ? 2 : (col >= 768 ? 1 : 0);
            float sc  = (which == 0) ? QSC : 1.0f;   // fold 0.125*log2e into Q
            int rem   = col - which * 768;
            int hh    = rem >> 6, d = rem & 63;
            #pragma unroll
            for (int i = 0; i < 4; i++) {
                int rbase = m0 + wm + i * 16 + fq * 4;
                #pragma unroll
                for (int e = 0; e < 4; e++) {
                    int row = rbase + e;
                    int b_  = row >> 11, srow = row & 2047;
                    size_t idx = (size_t)which * 3145728 +
                                 ((size_t)(b_ * 12 + hh) * 2048 + srow) * 64 + d;
                    outB[idx] = f2b(acc[i][j][e] * sc);
                }
            }
        }
        return;
    }
    #pragma unroll
    for (int j = 0; j < 4; j++) {
        int col  = n0 + wn + j * 16 + fr;
        float bv = bias ? bias[col] : 0.f;
        #pragma unroll
        for (int i = 0; i < 4; i++) {
            int rbase = m0 + wm + i * 16 + fq * 4;
            #pragma unroll
            for (int e = 0; e < 4; e++) {
                float v = acc[i][j][e] + bv;
                if (relu) v = fmaxf(v, 0.f);
                size_t idx = (size_t)(rbase + e) * N + col;
                if (outF) outF[idx] = v;
                if (outB) outB[idx] = f2b(v);
            }
        }
    }
}

// ---------------- attention partial (kv-split, lean softmax) ----------------
// Ks/Vt XOR-swizzled (0 conflicts, R8-verified); Ps padded stride-72 (affine
// addresses). l computed by MFMA with all-ones B fragment. LDS 51.2KB.
__global__ __launch_bounds__(256) void attn_part(const unsigned short* __restrict__ Qg,
                                                 const unsigned short* __restrict__ Kg,
                                                 const unsigned short* __restrict__ Vg,
                                                 unsigned short* __restrict__ pO,
                                                 float* __restrict__ pL) {
    __shared__ unsigned short Ks[2][4096];
    __shared__ unsigned short Vt[2][4096];
    __shared__ unsigned short Ps[128 * 72];
    const int tid  = threadIdx.x;
    const int lane = tid & 63;
    const int wave = tid >> 6;
    const int fr   = lane & 15;
    const int fq   = lane >> 4;
    const int wm   = wave * 32;
    const int r    = 71 - blockIdx.x;          // longest chunks first
    const int bh   = blockIdx.y;
    int qb = 0;
    for (int q_ = 15; q_ >= 0; --q_) if (r >= chunk_ofs(q_)) { qb = q_; break; }
    const int c     = r - chunk_ofs(qb);
    const int q0    = qb * 128;
    const int tile0 = 4 * c;
    const int ntk   = min(4, 2 * (qb + 1) - 4 * c);
    const int slot  = bh * 72 + r;
    const unsigned short* Qb = Qg + (size_t)bh * 2048 * 64;
    const unsigned short* Kb = Kg + (size_t)bh * 2048 * 64;
    const unsigned short* Vb = Vg + (size_t)bh * 2048 * 64;

    short8 qf[2][2];
    #pragma unroll
    for (int rf = 0; rf < 2; ++rf) {
        const unsigned short* qr = Qb + (size_t)(q0 + wm + rf * 16 + fr) * 64;
        qf[rf][0] = *(const short8*)(qr + fq * 8);
        qf[rf][1] = *(const short8*)(qr + 32 + fq * 8);
    }

    // all-ones bf16 B fragment for row-sum MFMA
    short8 onesf;
    #pragma unroll
    for (int i = 0; i < 8; ++i) onesf[i] = (short)0x3F80;

    floatx4 o[2][4];
    floatx4 lacc[2];
    #pragma unroll
    for (int rf = 0; rf < 2; ++rf) {
        #pragma unroll
        for (int nt = 0; nt < 4; ++nt)
            #pragma unroll
            for (int e = 0; e < 4; ++e) o[rf][nt][e] = 0.f;
        #pragma unroll
        for (int e = 0; e < 4; ++e) lacc[rf][e] = 0.f;
    }

    const int c0 = tid, c1 = tid + 256;
    uint4 kr0, kr1, vr0, vr1;

#define LOADT(TG)                                                              \
    {                                                                          \
        int base = (TG) * 64;                                                  \
        kr0 = *(const uint4*)(Kb + (size_t)(base + (c0 >> 3)) * 64 + (c0 & 7) * 8); \
        kr1 = *(const uint4*)(Kb + (size_t)(base + (c1 >> 3)) * 64 + (c1 & 7) * 8); \
        vr0 = *(const uint4*)(Vb + (size_t)(base + (c0 & 63)) * 64 + (c0 >> 6) * 8); \
        vr1 = *(const uint4*)(Vb + (size_t)(base + (c1 & 63)) * 64 + (c1 >> 6) * 8); \
    }
// Vt transposed write: row = (c>>6)*8 + i (so row&7 == i), col = c&63
#define WRITET(BUF)                                                            \
    {                                                                          \
        *(uint4*)&Ks[BUF][swz16(c0 >> 3, c0 & 7)] = kr0;                       \
        *(uint4*)&Ks[BUF][swz16(c1 >> 3, c1 & 7)] = kr1;                       \
        unsigned short t0[8]; *(uint4*)t0 = vr0;                               \
        _Pragma("unroll") for (int i_ = 0; i_ < 8; ++i_)                       \
            Vt[BUF][((c0 >> 6) * 8 + i_) * 64 +                                \
                    (((((c0 >> 3) & 7) ^ i_) << 3) | (c0 & 7))] = t0[i_];      \
        unsigned short t1[8]; *(uint4*)t1 = vr1;                               \
        _Pragma("unroll") for (int i_ = 0; i_ < 8; ++i_)                       \
            Vt[BUF][((c1 >> 6) * 8 + i_) * 64 +                                \
                    (((((c1 >> 3) & 7) ^ i_) << 3) | (c1 & 7))] = t1[i_];      \
    }

    LOADT(tile0);
    WRITET(0);
    __syncthreads();

    for (int kt = 0; kt < ntk; ++kt) {
        const int  tg   = tile0 + kt;
        const int  cur  = kt & 1;
        const bool more = (kt + 1 < ntk);
        if (more) LOADT(tg + 1);

        short8 kf[2][4];
        #pragma unroll
        for (int kc = 0; kc < 2; ++kc)
            #pragma unroll
            for (int nt = 0; nt < 4; ++nt)
                kf[kc][nt] = *(const short8*)&Ks[cur][swz16(nt * 16 + fr, kc * 4 + fq)];

        floatx4 s[2][4];
        #pragma unroll
        for (int rf = 0; rf < 2; ++rf)
            #pragma unroll
            for (int nt = 0; nt < 4; ++nt)
                #pragma unroll
                for (int e = 0; e < 4; ++e) s[rf][nt][e] = 0.f;
        #pragma unroll
        for (int rf = 0; rf < 2; ++rf)
            #pragma unroll
            for (int kc = 0; kc < 2; ++kc)
                #pragma unroll
                for (int nt = 0; nt < 4; ++nt)
                    s[rf][nt] = __builtin_amdgcn_mfma_f32_16x16x32_bf16(qf[rf][kc], kf[kc][nt], s[rf][nt], 0, 0, 0);

        // fixed-base softmax: p = 2^(s-C2); masked -> 0. No max, no rescale,
        // no row-sum here (l comes from MFMA-with-ones below).
        const bool need_mask = (tg * 64 + 63) > (q0 + wm);
        #pragma unroll
        for (int rf = 0; rf < 2; ++rf) {
            const int rmin  = q0 + wm + rf * 16;           // min q-row of frag
            const int pbase = (wm + rf * 16 + fq * 4) * 72 + fr;
            #pragma unroll
            for (int nt = 0; nt < 4; ++nt) {
                const bool tmask = need_mask && (tg * 64 + nt * 16 + 15 > rmin);
                const int  kvc   = tg * 64 + nt * 16 + fr;  // this lane's kv col
                #pragma unroll
                for (int e = 0; e < 4; ++e) {
                    float v = s[rf][nt][e] - C2;
                    if (tmask && kvc > rmin + fq * 4 + e) v = -1e30f;
                    float pv = __builtin_amdgcn_exp2f(v);
                    Ps[pbase + e * 72 + nt * 16] =
                        (unsigned short)(__float_as_uint(pv) >> 16);  // trunc
                }
            }
        }
        __asm__ volatile("s_waitcnt lgkmcnt(0)" ::: "memory");  // own-wave P RAW

        short8 pf[2][2], vf[2][4];
        #pragma unroll
        for (int rf = 0; rf < 2; ++rf)
            #pragma unroll
            for (int kc = 0; kc < 2; ++kc)
                pf[rf][kc] = *(const short8*)&Ps[(wm + rf * 16 + fr) * 72 + kc * 32 + fq * 8];
        #pragma unroll
        for (int kc = 0; kc < 2; ++kc)
            #pragma unroll
            for (int nt = 0; nt < 4; ++nt)
                vf[kc][nt] = *(const short8*)&Vt[cur][swz16(nt * 16 + fr, kc * 4 + fq)];
        #pragma unroll
        for (int rf = 0; rf < 2; ++rf)
            #pragma unroll
            for (int kc = 0; kc < 2; ++kc) {
                lacc[rf] = __builtin_amdgcn_mfma_f32_16x16x32_bf16(pf[rf][kc], onesf, lacc[rf], 0, 0, 0);
                #pragma unroll
                for (int nt = 0; nt < 4; ++nt)
                    o[rf][nt] = __builtin_amdgcn_mfma_f32_16x16x32_bf16(pf[rf][kc], vf[kc][nt], o[rf][nt], 0, 0, 0);
            }

        if (more) {
            WRITET(cur ^ 1);
            __syncthreads();
        }
    }
#undef LOADT
#undef WRITET

    #pragma unroll
    for (int rf = 0; rf < 2; ++rf)
        #pragma unroll
        for (int e = 0; e < 4; ++e) {
            int row = wm + rf * 16 + fq * 4 + e;
            unsigned short* orow = pO + ((size_t)slot * 128 + row) * 64;
            #pragma unroll
            for (int nt = 0; nt < 4; ++nt)
                orow[nt * 16 + fr] = f2b(o[rf][nt][e]);
            if (fr == 0)
                pL[(size_t)slot * 128 + row] = lacc[rf][e];
        }
}

// ---------------- attention combine (fixed base: plain sums) ----------------
__global__ __launch_bounds__(256) void attn_combine(const unsigned short* __restrict__ pO,
                                                    const float* __restrict__ pL,
                                                    unsigned short* __restrict__ ctx) {
    const int qb  = blockIdx.x;
    const int bh  = blockIdx.y;
    const int b   = bh / 12, h = bh % 12;
    const int nch = (qb + 2) >> 1;
    const int slot0 = bh * 72 + chunk_ofs(qb);
    const int tid = threadIdx.x;
    const int row = tid >> 1;
    const int col0 = (tid & 1) * 32;

    float L = 0.f;
    for (int i = 0; i < nch; ++i)
        L += pL[(size_t)(slot0 + i) * 128 + row];

    float acc[32];
    #pragma unroll
    for (int j = 0; j < 32; ++j) acc[j] = 0.f;
    for (int i = 0; i < nch; ++i) {
        const unsigned short* p = pO + ((size_t)(slot0 + i) * 128 + row) * 64 + col0;
        #pragma unroll
        for (int v4 = 0; v4 < 4; ++v4) {
            uint4 u = *(const uint4*)(p + v4 * 8);
            unsigned short t[8]; *(uint4*)t = u;
            #pragma unroll
            for (int j = 0; j < 8; ++j) acc[v4 * 8 + j] += b2f(t[j]);
        }
    }
    float inv = 1.f / L;
    unsigned short* orow = ctx + ((size_t)(b * 2048 + qb * 128 + row)) * 768 + h * 64 + col0;
    #pragma unroll
    for (int v4 = 0; v4 < 4; ++v4) {
        unsigned short t[8];
        #pragma unroll
        for (int j = 0; j < 8; ++j) t[j] = f2b(acc[v4 * 8 + j] * inv);
        *(uint4*)(orow + v4 * 8) = *(uint4*)t;
    }
}

// ---------------- fused split-K reduce + bias + residual + LayerNorm --------
__global__ __launch_bounds__(256) void resid_ln2(const float* __restrict__ X,
                                                 const float* __restrict__ P,
                                                 int nsplit,
                                                 const float* __restrict__ bv,
                                                 const float* __restrict__ gain,
                                                 const float* __restrict__ beta,
                                                 float* __restrict__ outF,
                                                 unsigned short* __restrict__ outB) {
    const int row = blockIdx.x;
    const int t   = threadIdx.x;
    const size_t off = (size_t)row * 768;
    float v[3];
    #pragma unroll
    for (int i = 0; i < 3; i++) {
        size_t c = off + t + i * 256;
        float r = X[c] + bv[t + i * 256];
        for (int p = 0; p < nsplit; ++p) r += P[(size_t)p * 3145728 + c];
        v[i] = r;
    }
    float s  = v[0] + v[1] + v[2];
    float s2 = v[0] * v[0] + v[1] * v[1] + v[2] * v[2];
    #pragma unroll
    for (int o2 = 32; o2 > 0; o2 >>= 1) {
        s  += __shfl_down(s,  o2);
        s2 += __shfl_down(s2, o2);
    }
    __shared__ float rs[4], rq[4];
    if ((t & 63) == 0) { rs[t >> 6] = s; rq[t >> 6] = s2; }
    __syncthreads();
    float S    = rs[0] + rs[1] + rs[2] + rs[3];
    float S2   = rq[0] + rq[1] + rq[2] + rq[3];
    float mean = S * (1.0f / 768.0f);
    float var  = S2 * (1.0f / 768.0f) - mean * mean;
    float inv  = rsqrtf(var + 1e-5f);
    #pragma unroll
    for (int i = 0; i < 3; i++) {
        int c   = t + i * 256;
        float y = gain[c] * (v[i] - mean) * inv + beta[c];
        if (outF) outF[off + c] = y;
        if (outB) outB[off + c] = f2b(y);
    }
}

// ---------------------------------------------------------------------------
extern "C" void kernel_launch(void* const* d_in, const int* in_sizes, int n_in,
                              void* d_out, int out_size, void* d_ws, size_t ws_size,
                              hipStream_t stream) {
    const float* x    = (const float*)d_in[0];
    const float* Wqkv = (const float*)d_in[1];
    const float* Wout = (const float*)d_in[2];
    const float* bout = (const float*)d_in[3];
    const float* W1   = (const float*)d_in[4];
    const float* b1   = (const float*)d_in[5];
    const float* W2   = (const float*)d_in[6];
    const float* b2   = (const float*)d_in[7];
    const float* g1   = (const float*)d_in[8];
    const float* be1  = (const float*)d_in[9];
    const float* g2   = (const float*)d_in[10];
    const float* be2  = (const float*)d_in[11];
    float* out = (float*)d_out;

    // workspace layout (bytes), liveness-aliased; peak 83,361,792
    char* ws = (char*)d_ws;
    unsigned short* wqkvT  = (unsigned short*)(ws + 0);         // 3.5M  ->QKV
    unsigned short* woutT  = (unsigned short*)(ws + 3538944);   // 1.2M  ->Wout
    unsigned short* w1T    = (unsigned short*)(ws + 4718592);   // 4.7M  ->W1
    unsigned short* w2T    = (unsigned short*)(ws + 9437184);   // 4.7M  ->W2
    unsigned short* xb     = (unsigned short*)(ws + 14155776);  // 6.3M  ->QKV
    unsigned short* qkvG   = (unsigned short*)(ws + 20447232);  // 18.9M ->attn_part
    unsigned short* Qg     = qkvG;
    unsigned short* Kg     = qkvG + 3145728;
    unsigned short* Vg     = qkvG + 6291456;
    unsigned short* pO     = (unsigned short*)(ws + 39321600);  // 28.3M ->combine
    float*          pL     = (float*)(ws + 67633152);           // 0.9M  ->combine
    unsigned short* ctxb   = (unsigned short*)(ws + 14155776);  // 6.3M  combine->Wout (xb dead)
    float*          WoutP  = (float*)(ws + 39321600);           // 3x12.6M Wout->LN1; ends 77,070,336
    float*          h      = (float*)(ws + 20447232);           // 12.6M LN1->LN2 (qkvG dead)
    unsigned short* hb     = (unsigned short*)(ws + 77070336);  // 6.3M  LN1->W1; ends 83,361,792
    unsigned short* ffb    = (unsigned short*)(ws + 39321600);  // 25.2M W1->W2 (WoutP dead)
    float*          W2P    = (float*)(ws + 64487424);           // 2x12.6M W2->LN2; ends 77,070,336

    // 1) fused prepass
    prep_all<<<9984, 256, 0, stream>>>(x, xb, Wqkv, wqkvT, Wout, woutT, W1, w1T, W2, w2T);
    // 2) QKV projection -> Q/K/V [bh][s][64] bf16 (Q pre-scaled by QSC)
    gemm_bf16<<<dim3(18, 32), 256, 0, stream>>>(xb, wqkvT, nullptr, nullptr, qkvG,
                                                4096, 2304, 768, 0, 1, 768);
    // 3) kv-split flash attention + combine -> ctx bf16
    attn_part<<<dim3(72, 24), 256, 0, stream>>>(Qg, Kg, Vg, pO, pL);
    attn_combine<<<dim3(16, 24), 256, 0, stream>>>(pO, pL, ctxb);
    // 4) out projection, split-K=3 -> fp32 partials
    gemm_bf16<<<dim3(6, 32, 3), 256, 0, stream>>>(ctxb, woutT, nullptr, WoutP, nullptr,
                                                  4096, 768, 768, 0, 2, 256);
    // 5) h = LN(x + sum(WoutP) + bout) -> fp32 + bf16
    resid_ln2<<<4096, 256, 0, stream>>>(x, WoutP, 3, bout, g1, be1, h, hb);
    // 6) ff = relu(h @ W1 + b1) -> bf16
    gemm_bf16<<<dim3(24, 32), 256, 0, stream>>>(hb, w1T, b1, nullptr, ffb,
                                                4096, 3072, 768, 1, 0, 768);
    // 7) ff2 partials = ff @ W2 (split-K=2)
    gemm_bf16<<<dim3(6, 32, 2), 256, 0, stream>>>(ffb, w2T, nullptr, W2P, nullptr,
                                                  4096, 768, 3072, 0, 2, 1536);
    // 8) out = LN(h + sum(W2P) + b2) -> fp32
    resid_ln2<<<4096, 256, 0, stream>>>(h, W2P, 2, b2, g2, be2, out, nullptr);
}